// Round 15
// baseline (1163.258 us; speedup 1.0000x reference)
//
#include <hip/hip_runtime.h>

#define Bb 64
#define Nn 128
#define Ee 2048
#define Hh 256
#define Ll 6
#define TN 8192
#define TE 131072
#define EDGE 50
#define EKPAD 64
#define TABN 512
#define TSCALE ((float)(TABN - 2) / 5.0f)

typedef __attribute__((ext_vector_type(4))) float f32x4;
typedef __attribute__((ext_vector_type(8))) __bf16 bf16x8;
typedef __attribute__((ext_vector_type(8))) unsigned short ushort8;

__device__ inline float b2f(unsigned short u) {
    union { unsigned u; float f; } v; v.u = ((unsigned)u) << 16; return v.f;
}
__device__ inline unsigned short f2b(float f) {
    union { float f; unsigned u; } v; v.f = f;
    unsigned r = v.u + 0x7fffu + ((v.u >> 16) & 1u);
    return (unsigned short)(r >> 16);
}
__device__ inline float spf(float x) {
    return fmaxf(x, 0.f) + __logf(1.f + __expf(-fabsf(x)));
}
__device__ inline float sspf(float x) {
    return spf(x) - 0.69314718055994530942f;
}

// ---------------- GEMM (R4-verified) + z-batch strides (table build) ----------------
template <int ACT, int OUTMODE, int TM>
__global__ __launch_bounds__(256)
void gemm_k(const unsigned short* __restrict__ A,
            const unsigned short* __restrict__ WT,
            const float* __restrict__ bias,
            unsigned short* __restrict__ Cb,
            float* __restrict__ Xf,
            unsigned short* __restrict__ Xb,
            int M, int K,
            long Az, long Wz, long bz, long Cz)
{
    constexpr int BK  = 64;
    constexpr int TNc = 128;
    constexpr int MR  = TM / 32;
    constexpr int NR  = 4;
    constexpr int SMEM_B = (TM + TNc) * BK * 2;

    __shared__ __align__(16) unsigned char smem[SMEM_B];
    unsigned short* As = (unsigned short*)smem;
    unsigned short* Bs = As + TM * BK;

    const int z = blockIdx.z;
    A += z * Az; WT += z * Wz; bias += z * bz;
    if (Cb) Cb += z * Cz;

    const int tid  = threadIdx.x;
    const int lane = tid & 63;
    const int w    = tid >> 6;
    const int wr   = w >> 1, wc = w & 1;
    const int r16  = lane & 15;
    const int kg   = lane >> 4;

    const long brow = (long)blockIdx.y * TM;
    const int  bcol = blockIdx.x * TNc;

    constexpr int ACH = TM / 8;
    constexpr int NCH = ACH + TNc / 8;
    constexpr int IPW = NCH / 4;
    const int lrow  = lane >> 3;
    const int lslot = lane & 7;

    f32x4 acc[MR][NR];
#pragma unroll
    for (int m = 0; m < MR; ++m)
#pragma unroll
        for (int n = 0; n < NR; ++n) acc[m][n] = f32x4{0.f, 0.f, 0.f, 0.f};

    for (int k0 = 0; k0 < K; k0 += BK) {
        __syncthreads();
#pragma unroll
        for (int i = 0; i < IPW; ++i) {
            const int c    = w * IPW + i;
            const bool isA = c < ACH;
            const int cc   = isA ? c : c - ACH;
            const int srow = cc * 8 + lrow;
            const int kch  = lslot ^ (srow & 7);
            const unsigned short* gp = isA
                ? A  + (brow + srow) * (long)K + k0 + kch * 8
                : WT + (bcol + srow) * (long)K + k0 + kch * 8;
            unsigned short* lp = (isA ? As : Bs) + cc * 512;
            __builtin_amdgcn_global_load_lds(
                (const __attribute__((address_space(1))) void*)gp,
                (__attribute__((address_space(3))) void*)lp, 16, 0, 0);
        }
        __syncthreads();

        bf16x8 a[MR][2], b[NR][2];
#pragma unroll
        for (int m = 0; m < MR; ++m) {
            const int row = wr * (MR * 16) + m * 16 + r16;
            const unsigned short* base = As + row * BK;
#pragma unroll
            for (int kk = 0; kk < 2; ++kk) {
                const int slot = (kk * 4 + kg) ^ (row & 7);
                a[m][kk] = *(const bf16x8*)(base + slot * 8);
            }
        }
#pragma unroll
        for (int n = 0; n < NR; ++n) {
            const int row = wc * 64 + n * 16 + r16;
            const unsigned short* base = Bs + row * BK;
#pragma unroll
            for (int kk = 0; kk < 2; ++kk) {
                const int slot = (kk * 4 + kg) ^ (row & 7);
                b[n][kk] = *(const bf16x8*)(base + slot * 8);
            }
        }
#pragma unroll
        for (int kk = 0; kk < 2; ++kk)
#pragma unroll
            for (int m = 0; m < MR; ++m)
#pragma unroll
                for (int n = 0; n < NR; ++n)
                    acc[m][n] = __builtin_amdgcn_mfma_f32_16x16x32_bf16(
                        b[n][kk], a[m][kk], acc[m][n], 0, 0, 0);
    }

    __syncthreads();

    {
#pragma unroll
        for (int m = 0; m < MR; ++m) {
            const int row = wr * (MR * 16) + m * 16 + r16;
#pragma unroll
            for (int n = 0; n < NR; ++n) {
                const int colL = wc * 64 + n * 16 + kg * 4;
                const f32x4 bv = *(const f32x4*)(bias + bcol + colL);
                float v0 = acc[m][n][0] + bv[0];
                float v1 = acc[m][n][1] + bv[1];
                float v2 = acc[m][n][2] + bv[2];
                float v3 = acc[m][n][3] + bv[3];
                if (ACT) { v0 = sspf(v0); v1 = sspf(v1); v2 = sspf(v2); v3 = sspf(v3); }
                uint2 p;
                p.x = (unsigned)f2b(v0) | ((unsigned)f2b(v1) << 16);
                p.y = (unsigned)f2b(v2) | ((unsigned)f2b(v3) << 16);
                const int off = (row * 256 + colL * 2) ^ ((row & 7) << 4);
                *(uint2*)(smem + off) = p;
            }
        }
        __syncthreads();
        constexpr int ITER = TM / 16;
#pragma unroll
        for (int q = 0; q < ITER; ++q) {
            const int flat = q * 4096 + tid * 16;
            const int row = flat >> 8, cbyte = flat & 255;
            uint4 d = *(const uint4*)(smem + ((row * 256 + cbyte) ^ ((row & 7) << 4)));
            *(uint4*)((unsigned char*)Cb + (brow + row) * 512 + bcol * 2 + cbyte) = d;
        }
    }
}

// ================= MEGA: one block = one graph; full layer loop + readout =================
__global__ __launch_bounds__(1024)
void mega(const unsigned short* __restrict__ xb0,
          float* __restrict__ xf,
          const unsigned short* __restrict__ mn1T, const float* __restrict__ mn_b1,
          const unsigned short* __restrict__ mn2T, const float* __restrict__ mn_b2,
          const unsigned short* __restrict__ st1T, const float* __restrict__ st_b1,
          const unsigned short* __restrict__ st2T, const float* __restrict__ st_b2,
          const unsigned short* __restrict__ gtab,
          const float* __restrict__ dcsr, const int* __restrict__ gsrcs,
          const int* __restrict__ cofl,
          const unsigned short* __restrict__ ro1T, const float* __restrict__ ro_b1,
          const float* __restrict__ ro_w2, const float* __restrict__ ro_b2,
          const int* __restrict__ num_nodes,
          const float* __restrict__ evw, const float* __restrict__ evb,
          float* __restrict__ out)
{
    __shared__ __align__(16) unsigned char bufs[2][65536];   // 128 rows x 512B, swizzled
    __shared__ float  dcsr_l[Ee];
    __shared__ short  src_l[Ee];
    __shared__ int    coff_l[129];

    const int tid  = threadIdx.x;
    const int lane = tid & 63;
    const int w    = tid >> 6;
    const int r16  = lane & 15;
    const int kg   = lane >> 4;
    const int wr   = w & 7;
    const int wc   = w >> 3;
    const int g    = blockIdx.x;
    const int gn0  = g * Nn;
    const long eb  = (long)g * Ee;

    const int arow = wr * 16 + r16;
    const int swz  = (arow & 7) << 4;

    // ---- one-time staging ----
    {
        const int lrow  = lane >> 5;
        const int lslot = lane & 31;
#pragma unroll
        for (int i = 0; i < 4; ++i) {
            const int cc   = w * 4 + i;
            const int srow = cc * 2 + lrow;
            const int kch  = lslot ^ (srow & 7);
            const unsigned short* gp = xb0 + (long)(gn0 + srow) * 256 + kch * 8;
            __builtin_amdgcn_global_load_lds(
                (const __attribute__((address_space(1))) void*)gp,
                (__attribute__((address_space(3))) void*)((unsigned short*)bufs[0] + cc * 512),
                16, 0, 0);
        }
#pragma unroll
        for (int j = 0; j < 2; ++j) {
            const int e = tid * 2 + j;
            src_l[e]  = (short)(gsrcs[eb + e] - gn0);
            dcsr_l[e] = dcsr[eb + e];
        }
        if (tid < 129) coff_l[tid] = cofl[g * 129 + tid];
    }
    __syncthreads();

    // ---- layer loop ----
    for (int L = 0; L < Ll; ++L) {
        const int cp = L & 1;
        unsigned char* cur = bufs[cp];
        unsigned char* oth = bufs[cp ^ 1];
        const unsigned short* W1 = mn1T + L * 65536;
        const unsigned short* W2 = mn2T + L * 65536;
        const unsigned short* S1 = st1T + L * 65536;
        const unsigned short* S2 = st2T + L * 65536;
        const float* B1 = mn_b1 + L * 256;
        const float* B2 = mn_b2 + L * 256;
        const float* C1 = st_b1 + L * 256;
        const float* C2 = st_b2 + L * 256;
        const unsigned short* tab = gtab + (size_t)L * TABN * 256;

        // mn GEMM1: cur(xb) -> oth(t), ssp
        {
            f32x4 acc[8];
#pragma unroll
            for (int n = 0; n < 8; ++n) acc[n] = f32x4{0.f, 0.f, 0.f, 0.f};
#pragma unroll
            for (int kk = 0; kk < 8; ++kk) {
                const int slot = (kk * 4 + kg) ^ (arow & 7);
                bf16x8 af = *(const bf16x8*)((unsigned short*)cur + arow * 256 + slot * 8);
#pragma unroll
                for (int n = 0; n < 8; ++n) {
                    const int col = wc * 128 + n * 16 + r16;
                    bf16x8 wf = *(const bf16x8*)(W1 + col * 256 + kk * 32 + kg * 8);
                    acc[n] = __builtin_amdgcn_mfma_f32_16x16x32_bf16(wf, af, acc[n], 0, 0, 0);
                }
            }
#pragma unroll
            for (int n = 0; n < 8; ++n) {
                const int c0 = wc * 128 + n * 16 + kg * 4;
                const f32x4 bv = *(const f32x4*)(B1 + c0);
                uint2 p;
                p.x = (unsigned)f2b(sspf(acc[n][0] + bv[0])) |
                      ((unsigned)f2b(sspf(acc[n][1] + bv[1])) << 16);
                p.y = (unsigned)f2b(sspf(acc[n][2] + bv[2])) |
                      ((unsigned)f2b(sspf(acc[n][3] + bv[3])) << 16);
                *(uint2*)(oth + ((arow * 512 + c0 * 2) ^ swz)) = p;
            }
        }
        __syncthreads();

        // mn GEMM2: oth(t) -> cur(nmsg)
        {
            f32x4 acc[8];
#pragma unroll
            for (int n = 0; n < 8; ++n) acc[n] = f32x4{0.f, 0.f, 0.f, 0.f};
#pragma unroll
            for (int kk = 0; kk < 8; ++kk) {
                bf16x8 af = *(const bf16x8*)(oth + ((arow * 512 + (kk * 4 + kg) * 16) ^ swz));
#pragma unroll
                for (int n = 0; n < 8; ++n) {
                    const int col = wc * 128 + n * 16 + r16;
                    bf16x8 wf = *(const bf16x8*)(W2 + col * 256 + kk * 32 + kg * 8);
                    acc[n] = __builtin_amdgcn_mfma_f32_16x16x32_bf16(wf, af, acc[n], 0, 0, 0);
                }
            }
            __syncthreads();   // all waves done reading cur(xb) (phase1) -> safe overwrite
#pragma unroll
            for (int n = 0; n < 8; ++n) {
                const int c0 = wc * 128 + n * 16 + kg * 4;
                const f32x4 bv = *(const f32x4*)(B2 + c0);
                uint2 p;
                p.x = (unsigned)f2b(acc[n][0] + bv[0]) | ((unsigned)f2b(acc[n][1] + bv[1]) << 16);
                p.y = (unsigned)f2b(acc[n][2] + bv[2]) | ((unsigned)f2b(acc[n][3] + bv[3]) << 16);
                *(uint2*)(cur + ((arow * 512 + c0 * 2) ^ swz)) = p;
            }
        }
        __syncthreads();

        // aggregation: cur(nmsg) -> oth(msum)
        {
            const int node = tid >> 3;
            const int c0a  = (tid & 7) * 32;
            float s[32];
#pragma unroll
            for (int j = 0; j < 32; ++j) s[j] = 0.f;
            const int beg = coff_l[node], end = coff_l[node + 1];
            for (int i = beg; i < end; ++i) {
                const float d  = dcsr_l[i];
                const int   sr = src_l[i];
                const float xx = d * TSCALE;
                const int   i0 = (int)xx;
                const float f  = xx - (float)i0;
                const unsigned short* t0 = tab + (long)i0 * 256 + c0a;
                const int nswz = (sr & 7) << 4;
#pragma unroll
                for (int q = 0; q < 4; ++q) {
                    ushort8 g0 = *(const ushort8*)(t0 + q * 8);
                    ushort8 g1 = *(const ushort8*)(t0 + 256 + q * 8);
                    ushort8 nm = *(const ushort8*)(cur + ((sr * 512 + (c0a + q * 8) * 2) ^ nswz));
#pragma unroll
                    for (int j = 0; j < 8; ++j) {
                        float a = b2f(g0[j]);
                        s[q * 8 + j] += (a + (b2f(g1[j]) - a) * f) * b2f(nm[j]);
                    }
                }
            }
            const int mswz = ((node & 7) << 4);
#pragma unroll
            for (int p8 = 0; p8 < 8; ++p8) {
                uint2 p;
                p.x = (unsigned)f2b(s[p8 * 4 + 0]) | ((unsigned)f2b(s[p8 * 4 + 1]) << 16);
                p.y = (unsigned)f2b(s[p8 * 4 + 2]) | ((unsigned)f2b(s[p8 * 4 + 3]) << 16);
                const int c = c0a + p8 * 4;
                *(uint2*)(oth + ((node * 512 + c * 2) ^ mswz)) = p;
            }
        }
        __syncthreads();

        // st GEMM1: oth(msum) -> cur(t2), ssp
        {
            f32x4 acc[8];
#pragma unroll
            for (int n = 0; n < 8; ++n) acc[n] = f32x4{0.f, 0.f, 0.f, 0.f};
#pragma unroll
            for (int kk = 0; kk < 8; ++kk) {
                bf16x8 af = *(const bf16x8*)(oth + ((arow * 512 + (kk * 4 + kg) * 16) ^ swz));
#pragma unroll
                for (int n = 0; n < 8; ++n) {
                    const int col = wc * 128 + n * 16 + r16;
                    bf16x8 wf = *(const bf16x8*)(S1 + col * 256 + kk * 32 + kg * 8);
                    acc[n] = __builtin_amdgcn_mfma_f32_16x16x32_bf16(wf, af, acc[n], 0, 0, 0);
                }
            }
            __syncthreads();   // agg reads of cur(nmsg) complete -> safe overwrite
#pragma unroll
            for (int n = 0; n < 8; ++n) {
                const int c0 = wc * 128 + n * 16 + kg * 4;
                const f32x4 bv = *(const f32x4*)(C1 + c0);
                uint2 p;
                p.x = (unsigned)f2b(sspf(acc[n][0] + bv[0])) |
                      ((unsigned)f2b(sspf(acc[n][1] + bv[1])) << 16);
                p.y = (unsigned)f2b(sspf(acc[n][2] + bv[2])) |
                      ((unsigned)f2b(sspf(acc[n][3] + bv[3])) << 16);
                *(uint2*)(cur + ((arow * 512 + c0 * 2) ^ swz)) = p;
            }
        }
        __syncthreads();

        // st GEMM2: cur(t2) -> xf update (global) + oth(xb_new)
        {
            f32x4 acc[8];
#pragma unroll
            for (int n = 0; n < 8; ++n) acc[n] = f32x4{0.f, 0.f, 0.f, 0.f};
#pragma unroll
            for (int kk = 0; kk < 8; ++kk) {
                bf16x8 af = *(const bf16x8*)(cur + ((arow * 512 + (kk * 4 + kg) * 16) ^ swz));
#pragma unroll
                for (int n = 0; n < 8; ++n) {
                    const int col = wc * 128 + n * 16 + r16;
                    bf16x8 wf = *(const bf16x8*)(S2 + col * 256 + kk * 32 + kg * 8);
                    acc[n] = __builtin_amdgcn_mfma_f32_16x16x32_bf16(wf, af, acc[n], 0, 0, 0);
                }
            }
            __syncthreads();   // st GEMM1 reads of oth(msum) complete -> safe overwrite
#pragma unroll
            for (int n = 0; n < 8; ++n) {
                const int c0 = wc * 128 + n * 16 + kg * 4;
                const f32x4 bv = *(const f32x4*)(C2 + c0);
                f32x4 v = acc[n] + bv;
                const long base = (long)(gn0 + arow) * 256 + c0;
                f32x4 xo = *(const f32x4*)(xf + base);
                f32x4 nx = xo + v;
                *(f32x4*)(xf + base) = nx;
                uint2 p;
                p.x = (unsigned)f2b(nx[0]) | ((unsigned)f2b(nx[1]) << 16);
                p.y = (unsigned)f2b(nx[2]) | ((unsigned)f2b(nx[3]) << 16);
                *(uint2*)(oth + ((arow * 512 + c0 * 2) ^ swz)) = p;
            }
        }
        __syncthreads();
    }

    // ---- readout ----
    {
        unsigned char* cur = bufs[Ll & 1];
        unsigned char* oth = bufs[(Ll & 1) ^ 1];
        f32x4 acc[8];
#pragma unroll
        for (int n = 0; n < 8; ++n) acc[n] = f32x4{0.f, 0.f, 0.f, 0.f};
#pragma unroll
        for (int kk = 0; kk < 8; ++kk) {
            const int slot = (kk * 4 + kg) ^ (arow & 7);
            bf16x8 af = *(const bf16x8*)((unsigned short*)cur + arow * 256 + slot * 8);
#pragma unroll
            for (int n = 0; n < 8; ++n) {
                const int col = wc * 128 + n * 16 + r16;
                bf16x8 wf = *(const bf16x8*)(ro1T + col * 256 + kk * 32 + kg * 8);
                acc[n] = __builtin_amdgcn_mfma_f32_16x16x32_bf16(wf, af, acc[n], 0, 0, 0);
            }
        }
        __syncthreads();
#pragma unroll
        for (int n = 0; n < 8; ++n) {
            const int c0 = wc * 128 + n * 16 + kg * 4;
            const f32x4 bv = *(const f32x4*)(ro_b1 + c0);
            uint2 p;
            p.x = (unsigned)f2b(sspf(acc[n][0] + bv[0])) |
                  ((unsigned)f2b(sspf(acc[n][1] + bv[1])) << 16);
            p.y = (unsigned)f2b(sspf(acc[n][2] + bv[2])) |
                  ((unsigned)f2b(sspf(acc[n][3] + bv[3])) << 16);
            *(uint2*)(oth + ((arow * 512 + c0 * 2) ^ swz)) = p;
        }
        __syncthreads();

        float part = 0.f;
#pragma unroll
        for (int j = 0; j < 32; ++j) {
            const int flat = tid * 32 + j;
            const int row = flat >> 8, c = flat & 255;
            const unsigned short u =
                *(const unsigned short*)(oth + ((row * 512 + c * 2) ^ ((row & 7) << 4)));
            part += b2f(u) * ro_w2[c];
        }
        float* red = (float*)cur;
        red[tid] = part;
        __syncthreads();
        for (int d = 512; d > 0; d >>= 1) {
            if (tid < d) red[tid] += red[tid + d];
            __syncthreads();
        }
        if (tid == 0) {
            float gg = red[0] + (float)Nn * ro_b2[0];
            gg = gg * 2.0f + (-1.5f) * (float)num_nodes[g];
            out[g * 4 + 0] = gg * evw[0] + evb[0];
            out[g * 4 + 1] = spf(gg * evw[1] + evb[1]);
            out[g * 4 + 2] = spf(gg * evw[2] + evb[2]) + 1.f;
            out[g * 4 + 3] = spf(gg * evw[3] + evb[3]);
        }
    }
}

// ---------------- small kernels ----------------
__global__ void k_offsets(const int* __restrict__ num_nodes, int* __restrict__ off) {
    __shared__ int s[Bb];
    int t = threadIdx.x;
    s[t] = num_nodes[t];
    __syncthreads();
    for (int d = 1; d < Bb; d <<= 1) {
        int v = (t >= d) ? s[t - d] : 0;
        __syncthreads();
        s[t] += v;
        __syncthreads();
    }
    off[t + 1] = s[t];
    if (t == 0) off[0] = 0;
}

__global__ void k_edgeprep(const int* __restrict__ edges, const int* __restrict__ off,
                           int* __restrict__ gsrc, int* __restrict__ gdst, int* __restrict__ cnt) {
    int ge = blockIdx.x * 256 + threadIdx.x;
    if (ge >= TE) return;
    int b = ge >> 11;
    int o = off[b];
    gsrc[ge] = edges[ge * 2 + 0] + o;
    int d = edges[ge * 2 + 1] + o;
    gdst[ge] = d;
    atomicAdd(&cnt[d], 1);
}

__global__ void k_scan(const int* __restrict__ cnt, int* __restrict__ coff, int* __restrict__ pos) {
    __shared__ int part[1024];
    int t = threadIdx.x;
    int loc[8];
    int s = 0;
#pragma unroll
    for (int j = 0; j < 8; ++j) { loc[j] = cnt[t * 8 + j]; s += loc[j]; }
    part[t] = s;
    __syncthreads();
    for (int d = 1; d < 1024; d <<= 1) {
        int v = (t >= d) ? part[t - d] : 0;
        __syncthreads();
        part[t] += v;
        __syncthreads();
    }
    int base = part[t] - s;
#pragma unroll
    for (int j = 0; j < 8; ++j) {
        int idx = t * 8 + j;
        coff[idx] = base;
        pos[idx]  = base;
        base += loc[j];
    }
    if (t == 1023) coff[TN] = part[1023];
}

__global__ void k_fill(const int* __restrict__ gdst, const int* __restrict__ gsrc,
                       const float* __restrict__ ef,
                       int* __restrict__ pos, int* __restrict__ gsrcs,
                       float* __restrict__ dcsr) {
    int ge = blockIdx.x * 256 + threadIdx.x;
    if (ge >= TE) return;
    int d = gdst[ge];
    int p = atomicAdd(&pos[d], 1);
    gsrcs[p] = gsrc[ge];
    dcsr[p]  = ef[ge];
}

__global__ void k_cofflocal(const int* __restrict__ coff, int* __restrict__ cofl) {
    int gid = blockIdx.x * 256 + threadIdx.x;
    if (gid >= Bb * 129) return;
    int g = gid / 129, t = gid % 129;
    // coff[g*128 + 128] == coff[(g+1)*128] == (g+1)*2048 (uniform E per graph)
    cofl[gid] = coff[g * Nn + t] - g * Ee;
}

__global__ void k_rbfgrid(unsigned short* __restrict__ rbfg) {
    int gid = blockIdx.x * 256 + threadIdx.x;   // TABN * 64
    int i = gid >> 6, k = gid & 63;
    float v = 0.f;
    if (k < EDGE) {
        float d = (float)i / TSCALE;
        float t = d - 0.1f * (float)k;
        v = __expf(-50.f * t * t);
    }
    rbfg[gid] = f2b(v);
}

__global__ void k_embed(const int* __restrict__ nodes, const float* __restrict__ embed,
                        float* __restrict__ x, unsigned short* __restrict__ xb) {
    int gid = blockIdx.x * 256 + threadIdx.x;
    int i = gid >> 8, c = gid & 255;
    float v = embed[(nodes[i] << 8) + c];
    x[gid] = v;
    xb[gid] = f2b(v);
}

__global__ void k_wprep(const float* __restrict__ me_w1, const float* __restrict__ me_w2,
                        const float* __restrict__ mn_w1, const float* __restrict__ mn_w2,
                        const float* __restrict__ st_w1, const float* __restrict__ st_w2,
                        const float* __restrict__ ro_w1,
                        unsigned short* __restrict__ me1T, unsigned short* __restrict__ me2T,
                        unsigned short* __restrict__ mn1T, unsigned short* __restrict__ mn2T,
                        unsigned short* __restrict__ st1T, unsigned short* __restrict__ st2T,
                        unsigned short* __restrict__ ro1T) {
    int gid = blockIdx.x * 256 + threadIdx.x;
    const int S1 = Ll * 256 * EKPAD;
    if (gid < S1) {
        int i = gid / (256 * EKPAD);
        int r = gid % (256 * EKPAD);
        int n = r / EKPAD, k = r % EKPAD;
        float v = (k < EDGE) ? me_w1[(i * EDGE + k) * 256 + n] : 0.f;
        me1T[gid] = f2b(v);
        return;
    }
    gid -= S1;
    const int S2 = Ll * 256 * 256;
    const float* srcs[5] = { me_w2, mn_w1, mn_w2, st_w1, st_w2 };
    unsigned short* dsts[5] = { me2T, mn1T, mn2T, st1T, st2T };
#pragma unroll
    for (int q = 0; q < 5; ++q) {
        if (gid < S2) {
            int i = gid >> 16;
            int r = gid & 65535;
            int n = r >> 8, k = r & 255;
            dsts[q][gid] = f2b(srcs[q][(i << 16) + k * 256 + n]);
            return;
        }
        gid -= S2;
    }
    int n = gid >> 8, k = gid & 255;
    ro1T[gid] = f2b(ro_w1[k * 256 + n]);
}

// ---------------- workspace layout ----------------
constexpr size_t al(size_t x) { return (x + 255) & ~(size_t)255; }
constexpr size_t O_OFF    = 0;
constexpr size_t O_GSRC   = al(O_OFF + 65 * 4);
constexpr size_t O_GDST   = al(O_GSRC + (size_t)TE * 4);
constexpr size_t O_CNT    = al(O_GDST + (size_t)TE * 4);
constexpr size_t O_COFF   = al(O_CNT + (size_t)TN * 4);
constexpr size_t O_POS    = al(O_COFF + (size_t)(TN + 1) * 4);
constexpr size_t O_COFL   = al(O_POS + (size_t)TN * 4);
constexpr size_t O_GSRCS  = al(O_COFL + (size_t)Bb * 129 * 4);
constexpr size_t O_DCSR   = al(O_GSRCS + (size_t)TE * 4);
constexpr size_t O_RBFG   = al(O_DCSR + (size_t)TE * 4);
constexpr size_t O_TTAB   = al(O_RBFG + (size_t)TABN * EKPAD * 2);
constexpr size_t O_GTAB   = al(O_TTAB + (size_t)Ll * TABN * 256 * 2);
constexpr size_t O_ME1T   = al(O_GTAB + (size_t)Ll * TABN * 256 * 2);
constexpr size_t O_ME2T   = al(O_ME1T + (size_t)Ll * 256 * EKPAD * 2);
constexpr size_t O_MN1T   = al(O_ME2T + (size_t)Ll * 256 * 256 * 2);
constexpr size_t O_MN2T   = al(O_MN1T + (size_t)Ll * 256 * 256 * 2);
constexpr size_t O_ST1T   = al(O_MN2T + (size_t)Ll * 256 * 256 * 2);
constexpr size_t O_ST2T   = al(O_ST1T + (size_t)Ll * 256 * 256 * 2);
constexpr size_t O_RO1T   = al(O_ST2T + (size_t)Ll * 256 * 256 * 2);
constexpr size_t O_X      = al(O_RO1T + (size_t)256 * 256 * 2);
constexpr size_t O_XB     = al(O_X + (size_t)TN * 256 * 4);
constexpr size_t WS_NEED  = al(O_XB + (size_t)TN * 256 * 2);

extern "C" void kernel_launch(void* const* d_in, const int* in_sizes, int n_in,
                              void* d_out, int out_size, void* d_ws, size_t ws_size,
                              hipStream_t stream) {
    if (ws_size < WS_NEED) return;

    const int*   nodes     = (const int*)d_in[0];
    const int*   num_nodes = (const int*)d_in[1];
    const int*   edges     = (const int*)d_in[2];
    const float* efeat     = (const float*)d_in[3];
    const float* embed     = (const float*)d_in[5];
    const float* me_w1 = (const float*)d_in[6],  *me_b1 = (const float*)d_in[7];
    const float* me_w2 = (const float*)d_in[8],  *me_b2 = (const float*)d_in[9];
    const float* mn_w1 = (const float*)d_in[10], *mn_b1 = (const float*)d_in[11];
    const float* mn_w2 = (const float*)d_in[12], *mn_b2 = (const float*)d_in[13];
    const float* st_w1 = (const float*)d_in[14], *st_b1 = (const float*)d_in[15];
    const float* st_w2 = (const float*)d_in[16], *st_b2 = (const float*)d_in[17];
    const float* ro_w1 = (const float*)d_in[18], *ro_b1 = (const float*)d_in[19];
    const float* ro_w2 = (const float*)d_in[20], *ro_b2 = (const float*)d_in[21];
    const float* ev_w  = (const float*)d_in[22], *ev_b  = (const float*)d_in[23];

    char* ws = (char*)d_ws;
    int* off   = (int*)(ws + O_OFF);
    int* gsrc  = (int*)(ws + O_GSRC);
    int* gdst  = (int*)(ws + O_GDST);
    int* cnt   = (int*)(ws + O_CNT);
    int* coff  = (int*)(ws + O_COFF);
    int* pos   = (int*)(ws + O_POS);
    int* cofl  = (int*)(ws + O_COFL);
    int* gsrcs = (int*)(ws + O_GSRCS);
    float* dcsr = (float*)(ws + O_DCSR);
    unsigned short* rbfg  = (unsigned short*)(ws + O_RBFG);
    unsigned short* ttab  = (unsigned short*)(ws + O_TTAB);
    unsigned short* gtab  = (unsigned short*)(ws + O_GTAB);
    unsigned short* me1T  = (unsigned short*)(ws + O_ME1T);
    unsigned short* me2T  = (unsigned short*)(ws + O_ME2T);
    unsigned short* mn1T  = (unsigned short*)(ws + O_MN1T);
    unsigned short* mn2T  = (unsigned short*)(ws + O_MN2T);
    unsigned short* st1T  = (unsigned short*)(ws + O_ST1T);
    unsigned short* st2T  = (unsigned short*)(ws + O_ST2T);
    unsigned short* ro1T  = (unsigned short*)(ws + O_RO1T);
    float*          x     = (float*)(ws + O_X);
    unsigned short* xb    = (unsigned short*)(ws + O_XB);
    float* out = (float*)d_out;

    hipMemsetAsync(cnt, 0, TN * 4, stream);
    k_offsets<<<1, Bb, 0, stream>>>(num_nodes, off);
    k_edgeprep<<<TE / 256, 256, 0, stream>>>(edges, off, gsrc, gdst, cnt);
    k_scan<<<1, 1024, 0, stream>>>(cnt, coff, pos);
    k_fill<<<TE / 256, 256, 0, stream>>>(gdst, gsrc, efeat, pos, gsrcs, dcsr);
    k_cofflocal<<<(Bb * 129 + 255) / 256, 256, 0, stream>>>(coff, cofl);
    k_rbfgrid<<<(TABN * EKPAD) / 256, 256, 0, stream>>>(rbfg);
    k_embed<<<TN, 256, 0, stream>>>(nodes, embed, x, xb);
    {
        const int total = Ll * 256 * EKPAD + 5 * Ll * 256 * 256 + 256 * 256;
        k_wprep<<<total / 256, 256, 0, stream>>>(me_w1, me_w2, mn_w1, mn_w2, st_w1, st_w2, ro_w1,
                                                 me1T, me2T, mn1T, mn2T, st1T, st2T, ro1T);
    }

    const dim3 gT(2, TABN / 128, Ll), blk(256);
    gemm_k<1, 0, 128><<<gT, blk, 0, stream>>>(rbfg, me1T, me_b1, ttab, nullptr, nullptr,
                                              TABN, EKPAD,
                                              0, 256 * EKPAD, 256, (long)TABN * 256);
    gemm_k<0, 0, 128><<<gT, blk, 0, stream>>>(ttab, me2T, me_b2, gtab, nullptr, nullptr,
                                              TABN, 256,
                                              (long)TABN * 256, 65536, 256, (long)TABN * 256);

    mega<<<Bb, 1024, 0, stream>>>(xb, x,
                                  mn1T, mn_b1, mn2T, mn_b2,
                                  st1T, st_b1, st2T, st_b2,
                                  gtab, dcsr, gsrcs, cofl,
                                  ro1T, ro_b1, ro_w2, ro_b2,
                                  num_nodes, ev_w, ev_b, out);
}

// Round 17
// 444.148 us; speedup vs baseline: 2.6191x; 2.6191x over previous
//
#include <hip/hip_runtime.h>

#define Bb 64
#define Nn 128
#define Ee 2048
#define Hh 256
#define Ll 6
#define TN 8192
#define TE 131072
#define EDGE 50
#define EKPAD 64
#define TABN 512
#define TSCALE ((float)(TABN - 2) / 5.0f)

typedef __attribute__((ext_vector_type(4))) float f32x4;
typedef __attribute__((ext_vector_type(8))) __bf16 bf16x8;
typedef __attribute__((ext_vector_type(8))) unsigned short ushort8;

__device__ inline float b2f(unsigned short u) {
    union { unsigned u; float f; } v; v.u = ((unsigned)u) << 16; return v.f;
}
__device__ inline unsigned short f2b(float f) {
    union { float f; unsigned u; } v; v.f = f;
    unsigned r = v.u + 0x7fffu + ((v.u >> 16) & 1u);
    return (unsigned short)(r >> 16);
}
__device__ inline float spf(float x) {
    return fmaxf(x, 0.f) + __logf(1.f + __expf(-fabsf(x)));
}
__device__ inline float sspf(float x) {
    return spf(x) - 0.69314718055994530942f;
}

// ---------------- GEMM (R4-verified) + z-batch strides ----------------
template <int ACT, int OUTMODE, int TM>
__global__ __launch_bounds__(256)
void gemm_k(const unsigned short* __restrict__ A,
            const unsigned short* __restrict__ WT,
            const float* __restrict__ bias,
            unsigned short* __restrict__ Cb,
            float* __restrict__ Xf,
            unsigned short* __restrict__ Xb,
            int M, int K,
            long Az, long Wz, long bz, long Cz)
{
    constexpr int BK  = 64;
    constexpr int TNc = 128;
    constexpr int MR  = TM / 32;
    constexpr int NR  = 4;
    constexpr int STAGE_B = (TM + TNc) * BK * 2;
    constexpr int EPI_B   = (OUTMODE == 2) ? TM * TNc * 4 : TM * TNc * 2;
    constexpr int SMEM_B  = STAGE_B > EPI_B ? STAGE_B : EPI_B;

    __shared__ __align__(16) unsigned char smem[SMEM_B];
    unsigned short* As = (unsigned short*)smem;
    unsigned short* Bs = As + TM * BK;

    const int z = blockIdx.z;
    A += z * Az; WT += z * Wz; bias += z * bz;
    if (Cb) Cb += z * Cz;

    const int tid  = threadIdx.x;
    const int lane = tid & 63;
    const int w    = tid >> 6;
    const int wr   = w >> 1, wc = w & 1;
    const int r16  = lane & 15;
    const int kg   = lane >> 4;

    const long brow = (long)blockIdx.y * TM;
    const int  bcol = blockIdx.x * TNc;

    constexpr int ACH = TM / 8;
    constexpr int NCH = ACH + TNc / 8;
    constexpr int IPW = NCH / 4;
    const int lrow  = lane >> 3;
    const int lslot = lane & 7;

    f32x4 acc[MR][NR];
#pragma unroll
    for (int m = 0; m < MR; ++m)
#pragma unroll
        for (int n = 0; n < NR; ++n) acc[m][n] = f32x4{0.f, 0.f, 0.f, 0.f};

    for (int k0 = 0; k0 < K; k0 += BK) {
        __syncthreads();
#pragma unroll
        for (int i = 0; i < IPW; ++i) {
            const int c    = w * IPW + i;
            const bool isA = c < ACH;
            const int cc   = isA ? c : c - ACH;
            const int srow = cc * 8 + lrow;
            const int kch  = lslot ^ (srow & 7);
            const unsigned short* gp = isA
                ? A  + (brow + srow) * (long)K + k0 + kch * 8
                : WT + (bcol + srow) * (long)K + k0 + kch * 8;
            unsigned short* lp = (isA ? As : Bs) + cc * 512;
            __builtin_amdgcn_global_load_lds(
                (const __attribute__((address_space(1))) void*)gp,
                (__attribute__((address_space(3))) void*)lp, 16, 0, 0);
        }
        __syncthreads();

        bf16x8 a[MR][2], b[NR][2];
#pragma unroll
        for (int m = 0; m < MR; ++m) {
            const int row = wr * (MR * 16) + m * 16 + r16;
            const unsigned short* base = As + row * BK;
#pragma unroll
            for (int kk = 0; kk < 2; ++kk) {
                const int slot = (kk * 4 + kg) ^ (row & 7);
                a[m][kk] = *(const bf16x8*)(base + slot * 8);
            }
        }
#pragma unroll
        for (int n = 0; n < NR; ++n) {
            const int row = wc * 64 + n * 16 + r16;
            const unsigned short* base = Bs + row * BK;
#pragma unroll
            for (int kk = 0; kk < 2; ++kk) {
                const int slot = (kk * 4 + kg) ^ (row & 7);
                b[n][kk] = *(const bf16x8*)(base + slot * 8);
            }
        }
#pragma unroll
        for (int kk = 0; kk < 2; ++kk)
#pragma unroll
            for (int m = 0; m < MR; ++m)
#pragma unroll
                for (int n = 0; n < NR; ++n)
                    acc[m][n] = __builtin_amdgcn_mfma_f32_16x16x32_bf16(
                        b[n][kk], a[m][kk], acc[m][n], 0, 0, 0);
    }

    __syncthreads();

    if (OUTMODE != 2) {
#pragma unroll
        for (int m = 0; m < MR; ++m) {
            const int row = wr * (MR * 16) + m * 16 + r16;
#pragma unroll
            for (int n = 0; n < NR; ++n) {
                const int colL = wc * 64 + n * 16 + kg * 4;
                const f32x4 bv = *(const f32x4*)(bias + bcol + colL);
                float v0 = acc[m][n][0] + bv[0];
                float v1 = acc[m][n][1] + bv[1];
                float v2 = acc[m][n][2] + bv[2];
                float v3 = acc[m][n][3] + bv[3];
                if (ACT) { v0 = sspf(v0); v1 = sspf(v1); v2 = sspf(v2); v3 = sspf(v3); }
                uint2 p;
                p.x = (unsigned)f2b(v0) | ((unsigned)f2b(v1) << 16);
                p.y = (unsigned)f2b(v2) | ((unsigned)f2b(v3) << 16);
                const int off = (row * 256 + colL * 2) ^ ((row & 7) << 4);
                *(uint2*)(smem + off) = p;
            }
        }
        __syncthreads();
        constexpr int ITER = TM / 16;
#pragma unroll
        for (int q = 0; q < ITER; ++q) {
            const int flat = q * 4096 + tid * 16;
            const int row = flat >> 8, cbyte = flat & 255;
            uint4 d = *(const uint4*)(smem + ((row * 256 + cbyte) ^ ((row & 7) << 4)));
            *(uint4*)((unsigned char*)Cb + (brow + row) * 512 + bcol * 2 + cbyte) = d;
        }
    } else {
#pragma unroll
        for (int m = 0; m < MR; ++m) {
            const int row = wr * (MR * 16) + m * 16 + r16;
#pragma unroll
            for (int n = 0; n < NR; ++n) {
                const int colL = wc * 64 + n * 16 + kg * 4;
                const f32x4 bv = *(const f32x4*)(bias + bcol + colL);
                f32x4 v = acc[m][n] + bv;
                const int off = (row * 512 + colL * 4) ^ ((row & 7) << 4);
                *(f32x4*)(smem + off) = v;
            }
        }
        __syncthreads();
        constexpr int ITER = TM / 8;
#pragma unroll
        for (int q = 0; q < ITER; ++q) {
            const int flat = q * 4096 + tid * 16;
            const int row = flat >> 9, cbyte = flat & 511;
            f32x4 v = *(const f32x4*)(smem + ((row * 512 + cbyte) ^ ((row & 7) << 4)));
            const long base = (brow + row) * 256 + bcol + (cbyte >> 2);
            f32x4 xo = *(const f32x4*)(Xf + base);
            f32x4 nx = xo + v;
            *(f32x4*)(Xf + base) = nx;
            uint2 p;
            p.x = (unsigned)f2b(nx[0]) | ((unsigned)f2b(nx[1]) << 16);
            p.y = (unsigned)f2b(nx[2]) | ((unsigned)f2b(nx[3]) << 16);
            *(uint2*)(Xb + base) = p;
        }
    }
}

// ======== fused node MLP, 16-row tiles, 8 waves (512 thr): 4 waves/SIMD ========
// out = [ssp(A @ W1T^T + b1)] @ W2T^T + b2 ; wave w owns cols [w*32, w*32+32).
// R16 bug fixed: staging dest is w*512 ELEMENTS (chunk = 1KB = 512 bf16), not w*1024.
template <int OUTMODE, int AGG>
__global__ __launch_bounds__(512, 2)
void fused_node16(const unsigned short* __restrict__ Ab,
                  const unsigned short* __restrict__ W1T,
                  const float* __restrict__ b1,
                  const unsigned short* __restrict__ W2T,
                  const float* __restrict__ b2,
                  unsigned short* __restrict__ Cb,
                  float* __restrict__ Xf,
                  unsigned short* __restrict__ Xb,
                  const float* __restrict__ dcsr,
                  const unsigned short* __restrict__ tab,
                  const unsigned short* __restrict__ nmsgb,
                  const int* __restrict__ coff,
                  const int* __restrict__ gsrcs)
{
    __shared__ __align__(16) unsigned char smem[16384];       // A(8K) + t(8K)
    unsigned short* A_lds = (unsigned short*)smem;            // 16 x 256 bf16
    unsigned char*  t_lds = smem + 8192;                      // 16 x 256 bf16

    const int tid  = threadIdx.x;
    const int lane = tid & 63;
    const int w    = tid >> 6;            // 8 waves; wave w: cols [w*32, w*32+32)
    const int r16  = lane & 15;
    const int kg   = lane >> 4;
    const long brow = (long)blockIdx.x * 16;

    if (!AGG) {
        // stage A: 8 chunks x 1KB (2 rows each), one per wave; dest = w*512 elems
        const int lrow  = lane >> 5;          // 0..1
        const int lslot = lane & 31;          // 16B slot in 512B row
        const int srow  = w * 2 + lrow;
        const int kch   = lslot ^ (srow & 7);
        const unsigned short* gp = Ab + (brow + srow) * 256 + kch * 8;
        __builtin_amdgcn_global_load_lds(
            (const __attribute__((address_space(1))) void*)gp,
            (__attribute__((address_space(3))) void*)(A_lds + w * 512), 16, 0, 0);
    } else {
        // in-kernel aggregation: node = tid>>5 (0..15), 8 channels per thread
        const int node = tid >> 5;
        const int c0   = (tid & 31) * 8;
        const int gn   = (int)brow + node;
        float s[8];
#pragma unroll
        for (int j = 0; j < 8; ++j) s[j] = 0.f;
        const int beg = coff[gn], end = coff[gn + 1];
        for (int i = beg; i < end; ++i) {
            const float d  = dcsr[i];
            const int   sr = gsrcs[i];
            const float xx = d * TSCALE;
            const int   i0 = (int)xx;
            const float f  = xx - (float)i0;
            const unsigned short* t0 = tab + (long)i0 * 256 + c0;
            ushort8 g0 = *(const ushort8*)t0;
            ushort8 g1 = *(const ushort8*)(t0 + 256);
            ushort8 nm = *(const ushort8*)(nmsgb + ((long)sr << 8) + c0);
#pragma unroll
            for (int j = 0; j < 8; ++j) {
                float a = b2f(g0[j]);
                s[j] += (a + (b2f(g1[j]) - a) * f) * b2f(nm[j]);
            }
        }
        const int swzn = (node & 7) << 4;
#pragma unroll
        for (int j = 0; j < 2; ++j) {
            uint2 p;
            p.x = (unsigned)f2b(s[j * 4 + 0]) | ((unsigned)f2b(s[j * 4 + 1]) << 16);
            p.y = (unsigned)f2b(s[j * 4 + 2]) | ((unsigned)f2b(s[j * 4 + 3]) << 16);
            const int c = c0 + j * 4;
            *(uint2*)((unsigned char*)A_lds + ((node * 512 + c * 2) ^ swzn)) = p;
        }
    }
    __syncthreads();

    const int arow = r16;                 // 16 rows, lane r16 <-> row
    const int swz  = (arow & 7) << 4;

    // ---- GEMM1: t[arow][w*32 + n*16 + kg*4 + j] ----
    f32x4 acc1[2];
#pragma unroll
    for (int n = 0; n < 2; ++n) acc1[n] = f32x4{0.f, 0.f, 0.f, 0.f};
#pragma unroll
    for (int kk = 0; kk < 8; ++kk) {
        const int slot = (kk * 4 + kg) ^ (arow & 7);
        bf16x8 af = *(const bf16x8*)(A_lds + arow * 256 + slot * 8);
#pragma unroll
        for (int n = 0; n < 2; ++n) {
            const int col = w * 32 + n * 16 + r16;
            bf16x8 wf = *(const bf16x8*)(W1T + col * 256 + kk * 32 + kg * 8);
            acc1[n] = __builtin_amdgcn_mfma_f32_16x16x32_bf16(wf, af, acc1[n], 0, 0, 0);
        }
    }
#pragma unroll
    for (int n = 0; n < 2; ++n) {
        const int c0 = w * 32 + n * 16 + kg * 4;
        const f32x4 bv = *(const f32x4*)(b1 + c0);
        uint2 p;
        p.x = (unsigned)f2b(sspf(acc1[n][0] + bv[0])) |
              ((unsigned)f2b(sspf(acc1[n][1] + bv[1])) << 16);
        p.y = (unsigned)f2b(sspf(acc1[n][2] + bv[2])) |
              ((unsigned)f2b(sspf(acc1[n][3] + bv[3])) << 16);
        *(uint2*)(t_lds + ((arow * 512 + c0 * 2) ^ swz)) = p;
    }
    __syncthreads();

    // ---- GEMM2 ----
    f32x4 acc2[2];
#pragma unroll
    for (int n = 0; n < 2; ++n) acc2[n] = f32x4{0.f, 0.f, 0.f, 0.f};
#pragma unroll
    for (int kk = 0; kk < 8; ++kk) {
        bf16x8 af = *(const bf16x8*)(t_lds + ((arow * 512 + (kk * 4 + kg) * 16) ^ swz));
#pragma unroll
        for (int n = 0; n < 2; ++n) {
            const int col = w * 32 + n * 16 + r16;
            bf16x8 wf = *(const bf16x8*)(W2T + col * 256 + kk * 32 + kg * 8);
            acc2[n] = __builtin_amdgcn_mfma_f32_16x16x32_bf16(wf, af, acc2[n], 0, 0, 0);
        }
    }
    __syncthreads();   // A,t dead -> epilogue tile

    if (OUTMODE == 0) {
        // bf16 tile 16x512B in first 8KB, then one linear 16B/lane store pass
#pragma unroll
        for (int n = 0; n < 2; ++n) {
            const int c0 = w * 32 + n * 16 + kg * 4;
            const f32x4 bv = *(const f32x4*)(b2 + c0);
            uint2 p;
            p.x = (unsigned)f2b(acc2[n][0] + bv[0]) | ((unsigned)f2b(acc2[n][1] + bv[1]) << 16);
            p.y = (unsigned)f2b(acc2[n][2] + bv[2]) | ((unsigned)f2b(acc2[n][3] + bv[3]) << 16);
            *(uint2*)(smem + ((arow * 512 + c0 * 2) ^ swz)) = p;
        }
        __syncthreads();
        {
            const int flat = tid * 16;            // 512 x 16B = 8KB = whole tile
            const int row = flat >> 9, cbyte = flat & 511;
            uint4 d = *(const uint4*)(smem + ((row * 512 + cbyte) ^ ((row & 7) << 4)));
            *(uint4*)((unsigned char*)Cb + (brow + row) * 512 + cbyte) = d;
        }
    } else {
        // f32 tile 16x1024B across full 16KB
#pragma unroll
        for (int n = 0; n < 2; ++n) {
            const int c0 = w * 32 + n * 16 + kg * 4;
            const f32x4 bv = *(const f32x4*)(b2 + c0);
            f32x4 v = acc2[n] + bv;
            *(f32x4*)(smem + ((arow * 1024 + c0 * 4) ^ swz)) = v;
        }
        __syncthreads();
#pragma unroll
        for (int q = 0; q < 2; ++q) {
            const int flat = q * 8192 + tid * 16;
            const int row = flat >> 10, cbyte = flat & 1023;
            f32x4 v = *(const f32x4*)(smem + ((row * 1024 + cbyte) ^ ((row & 7) << 4)));
            const long base = (brow + row) * 256 + (cbyte >> 2);
            f32x4 xo = *(const f32x4*)(Xf + base);
            f32x4 nx = xo + v;
            *(f32x4*)(Xf + base) = nx;
            uint2 p;
            p.x = (unsigned)f2b(nx[0]) | ((unsigned)f2b(nx[1]) << 16);
            p.y = (unsigned)f2b(nx[2]) | ((unsigned)f2b(nx[3]) << 16);
            *(uint2*)(Xb + base) = p;
        }
    }
}

// ---------------- small kernels ----------------
__global__ void k_offsets(const int* __restrict__ num_nodes, int* __restrict__ off) {
    __shared__ int s[Bb];
    int t = threadIdx.x;
    s[t] = num_nodes[t];
    __syncthreads();
    for (int d = 1; d < Bb; d <<= 1) {
        int v = (t >= d) ? s[t - d] : 0;
        __syncthreads();
        s[t] += v;
        __syncthreads();
    }
    off[t + 1] = s[t];
    if (t == 0) off[0] = 0;
}

__global__ void k_edgeprep(const int* __restrict__ edges, const int* __restrict__ off,
                           int* __restrict__ gsrc, int* __restrict__ gdst, int* __restrict__ cnt) {
    int ge = blockIdx.x * 256 + threadIdx.x;
    if (ge >= TE) return;
    int b = ge >> 11;
    int o = off[b];
    gsrc[ge] = edges[ge * 2 + 0] + o;
    int d = edges[ge * 2 + 1] + o;
    gdst[ge] = d;
    atomicAdd(&cnt[d], 1);
}

__global__ void k_scan(const int* __restrict__ cnt, int* __restrict__ coff, int* __restrict__ pos) {
    __shared__ int part[1024];
    int t = threadIdx.x;
    int loc[8];
    int s = 0;
#pragma unroll
    for (int j = 0; j < 8; ++j) { loc[j] = cnt[t * 8 + j]; s += loc[j]; }
    part[t] = s;
    __syncthreads();
    for (int d = 1; d < 1024; d <<= 1) {
        int v = (t >= d) ? part[t - d] : 0;
        __syncthreads();
        part[t] += v;
        __syncthreads();
    }
    int base = part[t] - s;
#pragma unroll
    for (int j = 0; j < 8; ++j) {
        int idx = t * 8 + j;
        coff[idx] = base;
        pos[idx]  = base;
        base += loc[j];
    }
    if (t == 1023) coff[TN] = part[1023];
}

__global__ void k_fill(const int* __restrict__ gdst, const int* __restrict__ gsrc,
                       const float* __restrict__ ef,
                       int* __restrict__ pos, int* __restrict__ gsrcs,
                       float* __restrict__ dcsr) {
    int ge = blockIdx.x * 256 + threadIdx.x;
    if (ge >= TE) return;
    int d = gdst[ge];
    int p = atomicAdd(&pos[d], 1);
    gsrcs[p] = gsrc[ge];
    dcsr[p]  = ef[ge];
}

__global__ void k_rbfgrid(unsigned short* __restrict__ rbfg) {
    int gid = blockIdx.x * 256 + threadIdx.x;   // TABN * 64
    int i = gid >> 6, k = gid & 63;
    float v = 0.f;
    if (k < EDGE) {
        float d = (float)i / TSCALE;
        float t = d - 0.1f * (float)k;
        v = __expf(-50.f * t * t);
    }
    rbfg[gid] = f2b(v);
}

__global__ void k_embed(const int* __restrict__ nodes, const float* __restrict__ embed,
                        float* __restrict__ x, unsigned short* __restrict__ xb) {
    int gid = blockIdx.x * 256 + threadIdx.x;
    int i = gid >> 8, c = gid & 255;
    float v = embed[(nodes[i] << 8) + c];
    x[gid] = v;
    xb[gid] = f2b(v);
}

__global__ void k_wprep(const float* __restrict__ me_w1, const float* __restrict__ me_w2,
                        const float* __restrict__ mn_w1, const float* __restrict__ mn_w2,
                        const float* __restrict__ st_w1, const float* __restrict__ st_w2,
                        const float* __restrict__ ro_w1,
                        unsigned short* __restrict__ me1T, unsigned short* __restrict__ me2T,
                        unsigned short* __restrict__ mn1T, unsigned short* __restrict__ mn2T,
                        unsigned short* __restrict__ st1T, unsigned short* __restrict__ st2T,
                        unsigned short* __restrict__ ro1T) {
    int gid = blockIdx.x * 256 + threadIdx.x;
    const int S1 = Ll * 256 * EKPAD;
    if (gid < S1) {
        int i = gid / (256 * EKPAD);
        int r = gid % (256 * EKPAD);
        int n = r / EKPAD, k = r % EKPAD;
        float v = (k < EDGE) ? me_w1[(i * EDGE + k) * 256 + n] : 0.f;
        me1T[gid] = f2b(v);
        return;
    }
    gid -= S1;
    const int S2 = Ll * 256 * 256;
    const float* srcs[5] = { me_w2, mn_w1, mn_w2, st_w1, st_w2 };
    unsigned short* dsts[5] = { me2T, mn1T, mn2T, st1T, st2T };
#pragma unroll
    for (int q = 0; q < 5; ++q) {
        if (gid < S2) {
            int i = gid >> 16;
            int r = gid & 65535;
            int n = r >> 8, k = r & 255;
            dsts[q][gid] = f2b(srcs[q][(i << 16) + k * 256 + n]);
            return;
        }
        gid -= S2;
    }
    int n = gid >> 8, k = gid & 255;
    ro1T[gid] = f2b(ro_w1[k * 256 + n]);
}

__global__ void k_readout(const unsigned short* __restrict__ t, const float* __restrict__ w2,
                          const float* __restrict__ b2, const int* __restrict__ num_nodes,
                          const float* __restrict__ evw, const float* __restrict__ evb,
                          float* __restrict__ out) {
    __shared__ float red[256];
    int b = blockIdx.x, tid = threadIdx.x;
    const unsigned short* tb = t + (long)b * Nn * 256;
    float part = 0.f;
    for (int i = tid; i < Nn * 256; i += 256)
        part += b2f(tb[i]) * w2[i & 255];
    red[tid] = part;
    __syncthreads();
    for (int d = 128; d > 0; d >>= 1) {
        if (tid < d) red[tid] += red[tid + d];
        __syncthreads();
    }
    if (tid == 0) {
        float g = red[0] + (float)Nn * b2[0];
        g = g * 2.0f + (-1.5f) * (float)num_nodes[b];
        out[b * 4 + 0] = g * evw[0] + evb[0];
        out[b * 4 + 1] = spf(g * evw[1] + evb[1]);
        out[b * 4 + 2] = spf(g * evw[2] + evb[2]) + 1.f;
        out[b * 4 + 3] = spf(g * evw[3] + evb[3]);
    }
}

// ---------------- workspace layout ----------------
constexpr size_t al(size_t x) { return (x + 255) & ~(size_t)255; }
constexpr size_t O_OFF    = 0;
constexpr size_t O_GSRC   = al(O_OFF + 65 * 4);
constexpr size_t O_GDST   = al(O_GSRC + (size_t)TE * 4);
constexpr size_t O_CNT    = al(O_GDST + (size_t)TE * 4);
constexpr size_t O_COFF   = al(O_CNT + (size_t)TN * 4);
constexpr size_t O_POS    = al(O_COFF + (size_t)(TN + 1) * 4);
constexpr size_t O_GSRCS  = al(O_POS + (size_t)TN * 4);
constexpr size_t O_DCSR   = al(O_GSRCS + (size_t)TE * 4);
constexpr size_t O_RBFG   = al(O_DCSR + (size_t)TE * 4);
constexpr size_t O_TTAB   = al(O_RBFG + (size_t)TABN * EKPAD * 2);
constexpr size_t O_GTAB   = al(O_TTAB + (size_t)Ll * TABN * 256 * 2);
constexpr size_t O_ME1T   = al(O_GTAB + (size_t)Ll * TABN * 256 * 2);
constexpr size_t O_ME2T   = al(O_ME1T + (size_t)Ll * 256 * EKPAD * 2);
constexpr size_t O_MN1T   = al(O_ME2T + (size_t)Ll * 256 * 256 * 2);
constexpr size_t O_MN2T   = al(O_MN1T + (size_t)Ll * 256 * 256 * 2);
constexpr size_t O_ST1T   = al(O_MN2T + (size_t)Ll * 256 * 256 * 2);
constexpr size_t O_ST2T   = al(O_ST1T + (size_t)Ll * 256 * 256 * 2);
constexpr size_t O_RO1T   = al(O_ST2T + (size_t)Ll * 256 * 256 * 2);
constexpr size_t O_X      = al(O_RO1T + (size_t)256 * 256 * 2);
constexpr size_t O_XB     = al(O_X + (size_t)TN * 256 * 4);
constexpr size_t O_TMPB   = al(O_XB + (size_t)TN * 256 * 2);
constexpr size_t O_NMSG   = al(O_TMPB + (size_t)TN * 256 * 2);
constexpr size_t WS_NEED  = al(O_NMSG + (size_t)TN * 256 * 2);

extern "C" void kernel_launch(void* const* d_in, const int* in_sizes, int n_in,
                              void* d_out, int out_size, void* d_ws, size_t ws_size,
                              hipStream_t stream) {
    if (ws_size < WS_NEED) return;

    const int*   nodes     = (const int*)d_in[0];
    const int*   num_nodes = (const int*)d_in[1];
    const int*   edges     = (const int*)d_in[2];
    const float* efeat     = (const float*)d_in[3];
    const float* embed     = (const float*)d_in[5];
    const float* me_w1 = (const float*)d_in[6],  *me_b1 = (const float*)d_in[7];
    const float* me_w2 = (const float*)d_in[8],  *me_b2 = (const float*)d_in[9];
    const float* mn_w1 = (const float*)d_in[10], *mn_b1 = (const float*)d_in[11];
    const float* mn_w2 = (const float*)d_in[12], *mn_b2 = (const float*)d_in[13];
    const float* st_w1 = (const float*)d_in[14], *st_b1 = (const float*)d_in[15];
    const float* st_w2 = (const float*)d_in[16], *st_b2 = (const float*)d_in[17];
    const float* ro_w1 = (const float*)d_in[18], *ro_b1 = (const float*)d_in[19];
    const float* ro_w2 = (const float*)d_in[20], *ro_b2 = (const float*)d_in[21];
    const float* ev_w  = (const float*)d_in[22], *ev_b  = (const float*)d_in[23];

    char* ws = (char*)d_ws;
    int* off   = (int*)(ws + O_OFF);
    int* gsrc  = (int*)(ws + O_GSRC);
    int* gdst  = (int*)(ws + O_GDST);
    int* cnt   = (int*)(ws + O_CNT);
    int* coff  = (int*)(ws + O_COFF);
    int* pos   = (int*)(ws + O_POS);
    int* gsrcs = (int*)(ws + O_GSRCS);
    float* dcsr = (float*)(ws + O_DCSR);
    unsigned short* rbfg  = (unsigned short*)(ws + O_RBFG);
    unsigned short* ttab  = (unsigned short*)(ws + O_TTAB);
    unsigned short* gtab  = (unsigned short*)(ws + O_GTAB);
    unsigned short* me1T  = (unsigned short*)(ws + O_ME1T);
    unsigned short* me2T  = (unsigned short*)(ws + O_ME2T);
    unsigned short* mn1T  = (unsigned short*)(ws + O_MN1T);
    unsigned short* mn2T  = (unsigned short*)(ws + O_MN2T);
    unsigned short* st1T  = (unsigned short*)(ws + O_ST1T);
    unsigned short* st2T  = (unsigned short*)(ws + O_ST2T);
    unsigned short* ro1T  = (unsigned short*)(ws + O_RO1T);
    float*          x     = (float*)(ws + O_X);
    unsigned short* xb    = (unsigned short*)(ws + O_XB);
    unsigned short* tmpb  = (unsigned short*)(ws + O_TMPB);
    unsigned short* nmsgb = (unsigned short*)(ws + O_NMSG);
    float* out = (float*)d_out;

    hipMemsetAsync(cnt, 0, TN * 4, stream);
    k_offsets<<<1, Bb, 0, stream>>>(num_nodes, off);
    k_edgeprep<<<TE / 256, 256, 0, stream>>>(edges, off, gsrc, gdst, cnt);
    k_scan<<<1, 1024, 0, stream>>>(cnt, coff, pos);
    k_fill<<<TE / 256, 256, 0, stream>>>(gdst, gsrc, efeat, pos, gsrcs, dcsr);
    k_rbfgrid<<<(TABN * EKPAD) / 256, 256, 0, stream>>>(rbfg);
    k_embed<<<TN, 256, 0, stream>>>(nodes, embed, x, xb);
    {
        const int total = Ll * 256 * EKPAD + 5 * Ll * 256 * 256 + 256 * 256;
        k_wprep<<<total / 256, 256, 0, stream>>>(me_w1, me_w2, mn_w1, mn_w2, st_w1, st_w2, ro_w1,
                                                 me1T, me2T, mn1T, mn2T, st1T, st2T, ro1T);
    }

    // ---- build all 6 layers' gate tables (z = layer) ----
    const dim3 gT(2, TABN / 128, Ll), gN(2, TN / 64, 1), blk(256);
    gemm_k<1, 0, 128><<<gT, blk, 0, stream>>>(rbfg, me1T, me_b1, ttab, nullptr, nullptr,
                                              TABN, EKPAD,
                                              0, 256 * EKPAD, 256, (long)TABN * 256);
    gemm_k<0, 0, 128><<<gT, blk, 0, stream>>>(ttab, me2T, me_b2, gtab, nullptr, nullptr,
                                              TABN, 256,
                                              (long)TABN * 256, 65536, 256, (long)TABN * 256);

    for (int i = 0; i < Ll; ++i) {
        fused_node16<0, 0><<<TN / 16, 512, 0, stream>>>(
            xb, mn1T + i * 65536, mn_b1 + i * 256,
            mn2T + i * 65536, mn_b2 + i * 256, nmsgb, nullptr, nullptr,
            nullptr, nullptr, nullptr, nullptr, nullptr);
        fused_node16<2, 1><<<TN / 16, 512, 0, stream>>>(
            nullptr, st1T + i * 65536, st_b1 + i * 256,
            st2T + i * 65536, st_b2 + i * 256, nullptr, x, xb,
            dcsr, gtab + (size_t)i * TABN * 256, nmsgb, coff, gsrcs);
    }

    gemm_k<1, 0, 64><<<gN, blk, 0, stream>>>(xb, ro1T, ro_b1, tmpb, nullptr, nullptr,
                                             TN, 256, 0, 0, 0, 0);
    k_readout<<<Bb, 256, 0, stream>>>(tmpb, ro_w2, ro_b2, num_nodes, ev_w, ev_b, out);
}

// Round 18
// 409.280 us; speedup vs baseline: 2.8422x; 1.0852x over previous
//
#include <hip/hip_runtime.h>

#define Bb 64
#define Nn 128
#define Ee 2048
#define Hh 256
#define Ll 6
#define TN 8192
#define TE 131072
#define EDGE 50
#define EKPAD 64
#define TABN 512
#define TSCALE ((float)(TABN - 2) / 5.0f)

typedef __attribute__((ext_vector_type(4))) float f32x4;
typedef __attribute__((ext_vector_type(8))) __bf16 bf16x8;
typedef __attribute__((ext_vector_type(8))) unsigned short ushort8;

__device__ inline float b2f(unsigned short u) {
    union { unsigned u; float f; } v; v.u = ((unsigned)u) << 16; return v.f;
}
__device__ inline unsigned short f2b(float f) {
    union { float f; unsigned u; } v; v.f = f;
    unsigned r = v.u + 0x7fffu + ((v.u >> 16) & 1u);
    return (unsigned short)(r >> 16);
}
__device__ inline float spf(float x) {
    return fmaxf(x, 0.f) + __logf(1.f + __expf(-fabsf(x)));
}
__device__ inline float sspf(float x) {
    return spf(x) - 0.69314718055994530942f;
}

// ---------------- GEMM (R4-verified) + z-batch strides (table build) ----------------
template <int ACT, int OUTMODE, int TM>
__global__ __launch_bounds__(256)
void gemm_k(const unsigned short* __restrict__ A,
            const unsigned short* __restrict__ WT,
            const float* __restrict__ bias,
            unsigned short* __restrict__ Cb,
            float* __restrict__ Xf,
            unsigned short* __restrict__ Xb,
            int M, int K,
            long Az, long Wz, long bz, long Cz)
{
    constexpr int BK  = 64;
    constexpr int TNc = 128;
    constexpr int MR  = TM / 32;
    constexpr int NR  = 4;
    constexpr int SMEM_B = (TM + TNc) * BK * 2;

    __shared__ __align__(16) unsigned char smem[SMEM_B];
    unsigned short* As = (unsigned short*)smem;
    unsigned short* Bs = As + TM * BK;

    const int z = blockIdx.z;
    A += z * Az; WT += z * Wz; bias += z * bz;
    if (Cb) Cb += z * Cz;

    const int tid  = threadIdx.x;
    const int lane = tid & 63;
    const int w    = tid >> 6;
    const int wr   = w >> 1, wc = w & 1;
    const int r16  = lane & 15;
    const int kg   = lane >> 4;

    const long brow = (long)blockIdx.y * TM;
    const int  bcol = blockIdx.x * TNc;

    constexpr int ACH = TM / 8;
    constexpr int NCH = ACH + TNc / 8;
    constexpr int IPW = NCH / 4;
    const int lrow  = lane >> 3;
    const int lslot = lane & 7;

    f32x4 acc[MR][NR];
#pragma unroll
    for (int m = 0; m < MR; ++m)
#pragma unroll
        for (int n = 0; n < NR; ++n) acc[m][n] = f32x4{0.f, 0.f, 0.f, 0.f};

    for (int k0 = 0; k0 < K; k0 += BK) {
        __syncthreads();
#pragma unroll
        for (int i = 0; i < IPW; ++i) {
            const int c    = w * IPW + i;
            const bool isA = c < ACH;
            const int cc   = isA ? c : c - ACH;
            const int srow = cc * 8 + lrow;
            const int kch  = lslot ^ (srow & 7);
            const unsigned short* gp = isA
                ? A  + (brow + srow) * (long)K + k0 + kch * 8
                : WT + (bcol + srow) * (long)K + k0 + kch * 8;
            unsigned short* lp = (isA ? As : Bs) + cc * 512;
            __builtin_amdgcn_global_load_lds(
                (const __attribute__((address_space(1))) void*)gp,
                (__attribute__((address_space(3))) void*)lp, 16, 0, 0);
        }
        __syncthreads();

        bf16x8 a[MR][2], b[NR][2];
#pragma unroll
        for (int m = 0; m < MR; ++m) {
            const int row = wr * (MR * 16) + m * 16 + r16;
            const unsigned short* base = As + row * BK;
#pragma unroll
            for (int kk = 0; kk < 2; ++kk) {
                const int slot = (kk * 4 + kg) ^ (row & 7);
                a[m][kk] = *(const bf16x8*)(base + slot * 8);
            }
        }
#pragma unroll
        for (int n = 0; n < NR; ++n) {
            const int row = wc * 64 + n * 16 + r16;
            const unsigned short* base = Bs + row * BK;
#pragma unroll
            for (int kk = 0; kk < 2; ++kk) {
                const int slot = (kk * 4 + kg) ^ (row & 7);
                b[n][kk] = *(const bf16x8*)(base + slot * 8);
            }
        }
#pragma unroll
        for (int kk = 0; kk < 2; ++kk)
#pragma unroll
            for (int m = 0; m < MR; ++m)
#pragma unroll
                for (int n = 0; n < NR; ++n)
                    acc[m][n] = __builtin_amdgcn_mfma_f32_16x16x32_bf16(
                        b[n][kk], a[m][kk], acc[m][n], 0, 0, 0);
    }

    __syncthreads();

    {
#pragma unroll
        for (int m = 0; m < MR; ++m) {
            const int row = wr * (MR * 16) + m * 16 + r16;
#pragma unroll
            for (int n = 0; n < NR; ++n) {
                const int colL = wc * 64 + n * 16 + kg * 4;
                const f32x4 bv = *(const f32x4*)(bias + bcol + colL);
                float v0 = acc[m][n][0] + bv[0];
                float v1 = acc[m][n][1] + bv[1];
                float v2 = acc[m][n][2] + bv[2];
                float v3 = acc[m][n][3] + bv[3];
                if (ACT) { v0 = sspf(v0); v1 = sspf(v1); v2 = sspf(v2); v3 = sspf(v3); }
                uint2 p;
                p.x = (unsigned)f2b(v0) | ((unsigned)f2b(v1) << 16);
                p.y = (unsigned)f2b(v2) | ((unsigned)f2b(v3) << 16);
                const int off = (row * 256 + colL * 2) ^ ((row & 7) << 4);
                *(uint2*)(smem + off) = p;
            }
        }
        __syncthreads();
        constexpr int ITER = TM / 16;
#pragma unroll
        for (int q = 0; q < ITER; ++q) {
            const int flat = q * 4096 + tid * 16;
            const int row = flat >> 8, cbyte = flat & 255;
            uint4 d = *(const uint4*)(smem + ((row * 256 + cbyte) ^ ((row & 7) << 4)));
            *(uint4*)((unsigned char*)Cb + (brow + row) * 512 + bcol * 2 + cbyte) = d;
        }
    }
}

// ======== mn_0: fused node MLP, 16-row tiles, 8 waves (R17-verified) ========
__global__ __launch_bounds__(512, 2)
void fused_mn0(const unsigned short* __restrict__ Ab,
               const unsigned short* __restrict__ W1T,
               const float* __restrict__ b1,
               const unsigned short* __restrict__ W2T,
               const float* __restrict__ b2,
               unsigned short* __restrict__ Cb)
{
    __shared__ __align__(16) unsigned char smem[16384];       // A(8K) + t(8K)
    unsigned short* A_lds = (unsigned short*)smem;
    unsigned char*  t_lds = smem + 8192;

    const int tid  = threadIdx.x;
    const int lane = tid & 63;
    const int w    = tid >> 6;
    const int r16  = lane & 15;
    const int kg   = lane >> 4;
    const long brow = (long)blockIdx.x * 16;

    {
        const int lrow  = lane >> 5;
        const int lslot = lane & 31;
        const int srow  = w * 2 + lrow;
        const int kch   = lslot ^ (srow & 7);
        const unsigned short* gp = Ab + (brow + srow) * 256 + kch * 8;
        __builtin_amdgcn_global_load_lds(
            (const __attribute__((address_space(1))) void*)gp,
            (__attribute__((address_space(3))) void*)(A_lds + w * 512), 16, 0, 0);
    }
    __syncthreads();

    const int arow = r16;
    const int swz  = (arow & 7) << 4;

    f32x4 acc1[2];
#pragma unroll
    for (int n = 0; n < 2; ++n) acc1[n] = f32x4{0.f, 0.f, 0.f, 0.f};
#pragma unroll
    for (int kk = 0; kk < 8; ++kk) {
        const int slot = (kk * 4 + kg) ^ (arow & 7);
        bf16x8 af = *(const bf16x8*)(A_lds + arow * 256 + slot * 8);
#pragma unroll
        for (int n = 0; n < 2; ++n) {
            const int col = w * 32 + n * 16 + r16;
            bf16x8 wf = *(const bf16x8*)(W1T + col * 256 + kk * 32 + kg * 8);
            acc1[n] = __builtin_amdgcn_mfma_f32_16x16x32_bf16(wf, af, acc1[n], 0, 0, 0);
        }
    }
#pragma unroll
    for (int n = 0; n < 2; ++n) {
        const int c0 = w * 32 + n * 16 + kg * 4;
        const f32x4 bv = *(const f32x4*)(b1 + c0);
        uint2 p;
        p.x = (unsigned)f2b(sspf(acc1[n][0] + bv[0])) |
              ((unsigned)f2b(sspf(acc1[n][1] + bv[1])) << 16);
        p.y = (unsigned)f2b(sspf(acc1[n][2] + bv[2])) |
              ((unsigned)f2b(sspf(acc1[n][3] + bv[3])) << 16);
        *(uint2*)(t_lds + ((arow * 512 + c0 * 2) ^ swz)) = p;
    }
    __syncthreads();

    f32x4 acc2[2];
#pragma unroll
    for (int n = 0; n < 2; ++n) acc2[n] = f32x4{0.f, 0.f, 0.f, 0.f};
#pragma unroll
    for (int kk = 0; kk < 8; ++kk) {
        bf16x8 af = *(const bf16x8*)(t_lds + ((arow * 512 + (kk * 4 + kg) * 16) ^ swz));
#pragma unroll
        for (int n = 0; n < 2; ++n) {
            const int col = w * 32 + n * 16 + r16;
            bf16x8 wf = *(const bf16x8*)(W2T + col * 256 + kk * 32 + kg * 8);
            acc2[n] = __builtin_amdgcn_mfma_f32_16x16x32_bf16(wf, af, acc2[n], 0, 0, 0);
        }
    }
    __syncthreads();

#pragma unroll
    for (int n = 0; n < 2; ++n) {
        const int c0 = w * 32 + n * 16 + kg * 4;
        const f32x4 bv = *(const f32x4*)(b2 + c0);
        uint2 p;
        p.x = (unsigned)f2b(acc2[n][0] + bv[0]) | ((unsigned)f2b(acc2[n][1] + bv[1]) << 16);
        p.y = (unsigned)f2b(acc2[n][2] + bv[2]) | ((unsigned)f2b(acc2[n][3] + bv[3]) << 16);
        *(uint2*)(smem + ((arow * 512 + c0 * 2) ^ swz)) = p;
    }
    __syncthreads();
    {
        const int flat = tid * 16;
        const int row = flat >> 9, cbyte = flat & 511;
        uint4 d = *(const uint4*)(smem + ((row * 512 + cbyte) ^ ((row & 7) << 4)));
        *(uint4*)((unsigned char*)Cb + (brow + row) * 512 + cbyte) = d;
    }
}

// ======== STEP: agg_L -> st_L (+x update) -> mn_{L+1} (or ro GEMM1 if LAST) ========
// One dispatch replaces {agg+st} and {mn'} -- xb_new never leaves LDS.
// nmsg ping-pong: reads nmsg_in, writes nmsg_out (different buffers -> no race).
// Wave geometry identical to fused_mn0 (R17-verified): 16 rows, wave w cols [w*32,+32).
template <int LAST>
__global__ __launch_bounds__(512, 2)
void step_k(const float* __restrict__ dcsr,
            const unsigned short* __restrict__ tab,
            const unsigned short* __restrict__ nmsg_in,
            const int* __restrict__ coff,
            const int* __restrict__ gsrcs,
            const unsigned short* __restrict__ S1T, const float* __restrict__ sb1,
            const unsigned short* __restrict__ S2T, const float* __restrict__ sb2,
            float* __restrict__ Xf,
            const unsigned short* __restrict__ N1T, const float* __restrict__ nb1,
            const unsigned short* __restrict__ N2T, const float* __restrict__ nb2,
            unsigned short* __restrict__ nmsg_out)
{
    __shared__ __align__(16) unsigned char smem[16384];       // R0(8K) + R1(8K)
    unsigned short* R0 = (unsigned short*)smem;
    unsigned char*  R1 = smem + 8192;

    const int tid  = threadIdx.x;
    const int lane = tid & 63;
    const int w    = tid >> 6;
    const int r16  = lane & 15;
    const int kg   = lane >> 4;
    const long brow = (long)blockIdx.x * 16;

    const int arow = r16;
    const int swz  = (arow & 7) << 4;

    // ---- phase 1: aggregation (R11/R17-verified lerp math) -> R0 ----
    {
        const int node = tid >> 5;
        const int c0   = (tid & 31) * 8;
        const int gn   = (int)brow + node;
        float s[8];
#pragma unroll
        for (int j = 0; j < 8; ++j) s[j] = 0.f;
        const int beg = coff[gn], end = coff[gn + 1];
        for (int i = beg; i < end; ++i) {
            const float d  = dcsr[i];
            const int   sr = gsrcs[i];
            const float xx = d * TSCALE;
            const int   i0 = (int)xx;
            const float f  = xx - (float)i0;
            const unsigned short* t0 = tab + (long)i0 * 256 + c0;
            ushort8 g0 = *(const ushort8*)t0;
            ushort8 g1 = *(const ushort8*)(t0 + 256);
            ushort8 nm = *(const ushort8*)(nmsg_in + ((long)sr << 8) + c0);
#pragma unroll
            for (int j = 0; j < 8; ++j) {
                float a = b2f(g0[j]);
                s[j] += (a + (b2f(g1[j]) - a) * f) * b2f(nm[j]);
            }
        }
        const int swzn = (node & 7) << 4;
#pragma unroll
        for (int j = 0; j < 2; ++j) {
            uint2 p;
            p.x = (unsigned)f2b(s[j * 4 + 0]) | ((unsigned)f2b(s[j * 4 + 1]) << 16);
            p.y = (unsigned)f2b(s[j * 4 + 2]) | ((unsigned)f2b(s[j * 4 + 3]) << 16);
            const int c = c0 + j * 4;
            *(uint2*)((unsigned char*)R0 + ((node * 512 + c * 2) ^ swzn)) = p;
        }
    }
    __syncthreads();

    // ---- phase 2: st GEMM1: R0(msum) -> R1(t), ssp ----
    {
        f32x4 acc[2];
#pragma unroll
        for (int n = 0; n < 2; ++n) acc[n] = f32x4{0.f, 0.f, 0.f, 0.f};
#pragma unroll
        for (int kk = 0; kk < 8; ++kk) {
            const int slot = (kk * 4 + kg) ^ (arow & 7);
            bf16x8 af = *(const bf16x8*)(R0 + arow * 256 + slot * 8);
#pragma unroll
            for (int n = 0; n < 2; ++n) {
                const int col = w * 32 + n * 16 + r16;
                bf16x8 wf = *(const bf16x8*)(S1T + col * 256 + kk * 32 + kg * 8);
                acc[n] = __builtin_amdgcn_mfma_f32_16x16x32_bf16(wf, af, acc[n], 0, 0, 0);
            }
        }
#pragma unroll
        for (int n = 0; n < 2; ++n) {
            const int c0 = w * 32 + n * 16 + kg * 4;
            const f32x4 bv = *(const f32x4*)(sb1 + c0);
            uint2 p;
            p.x = (unsigned)f2b(sspf(acc[n][0] + bv[0])) |
                  ((unsigned)f2b(sspf(acc[n][1] + bv[1])) << 16);
            p.y = (unsigned)f2b(sspf(acc[n][2] + bv[2])) |
                  ((unsigned)f2b(sspf(acc[n][3] + bv[3])) << 16);
            *(uint2*)(R1 + ((arow * 512 + c0 * 2) ^ swz)) = p;
        }
    }
    __syncthreads();   // t visible; all R0(msum) reads done

    // ---- phase 3: st GEMM2: R1(t) -> x update (direct) + xb_new -> R0 ----
    {
        f32x4 acc[2];
#pragma unroll
        for (int n = 0; n < 2; ++n) acc[n] = f32x4{0.f, 0.f, 0.f, 0.f};
#pragma unroll
        for (int kk = 0; kk < 8; ++kk) {
            bf16x8 af = *(const bf16x8*)(R1 + ((arow * 512 + (kk * 4 + kg) * 16) ^ swz));
#pragma unroll
            for (int n = 0; n < 2; ++n) {
                const int col = w * 32 + n * 16 + r16;
                bf16x8 wf = *(const bf16x8*)(S2T + col * 256 + kk * 32 + kg * 8);
                acc[n] = __builtin_amdgcn_mfma_f32_16x16x32_bf16(wf, af, acc[n], 0, 0, 0);
            }
        }
#pragma unroll
        for (int n = 0; n < 2; ++n) {
            const int c0 = w * 32 + n * 16 + kg * 4;
            const f32x4 bv = *(const f32x4*)(sb2 + c0);
            const long base = (brow + arow) * 256 + c0;
            f32x4 xo = *(const f32x4*)(Xf + base);
            f32x4 nx;
            nx[0] = xo[0] + acc[n][0] + bv[0];
            nx[1] = xo[1] + acc[n][1] + bv[1];
            nx[2] = xo[2] + acc[n][2] + bv[2];
            nx[3] = xo[3] + acc[n][3] + bv[3];
            *(f32x4*)(Xf + base) = nx;
            uint2 p;
            p.x = (unsigned)f2b(nx[0]) | ((unsigned)f2b(nx[1]) << 16);
            p.y = (unsigned)f2b(nx[2]) | ((unsigned)f2b(nx[3]) << 16);
            *(uint2*)((unsigned char*)R0 + ((arow * 512 + c0 * 2) ^ swz)) = p;
        }
    }
    __syncthreads();   // xb_new visible; all R1(t) reads done

    // ---- phase 4: next GEMM1 (mn' or ro1): R0(xb_new) -> R1(t2), ssp ----
    {
        f32x4 acc[2];
#pragma unroll
        for (int n = 0; n < 2; ++n) acc[n] = f32x4{0.f, 0.f, 0.f, 0.f};
#pragma unroll
        for (int kk = 0; kk < 8; ++kk) {
            const int slot = (kk * 4 + kg) ^ (arow & 7);
            bf16x8 af = *(const bf16x8*)(R0 + ((arow * 512 + slot * 16) ^ swz) / 2);
            // NOTE: R0 was written swizzled as bytes; read identically:
            af = *(const bf16x8*)((unsigned char*)R0 + ((arow * 512 + (kk * 4 + kg) * 16) ^ swz));
#pragma unroll
            for (int n = 0; n < 2; ++n) {
                const int col = w * 32 + n * 16 + r16;
                bf16x8 wf = *(const bf16x8*)(N1T + col * 256 + kk * 32 + kg * 8);
                acc[n] = __builtin_amdgcn_mfma_f32_16x16x32_bf16(wf, af, acc[n], 0, 0, 0);
            }
        }
#pragma unroll
        for (int n = 0; n < 2; ++n) {
            const int c0 = w * 32 + n * 16 + kg * 4;
            const f32x4 bv = *(const f32x4*)(nb1 + c0);
            uint2 p;
            p.x = (unsigned)f2b(sspf(acc[n][0] + bv[0])) |
                  ((unsigned)f2b(sspf(acc[n][1] + bv[1])) << 16);
            p.y = (unsigned)f2b(sspf(acc[n][2] + bv[2])) |
                  ((unsigned)f2b(sspf(acc[n][3] + bv[3])) << 16);
            *(uint2*)(R1 + ((arow * 512 + c0 * 2) ^ swz)) = p;
        }
    }
    __syncthreads();   // t2 visible; all R0(xb_new) reads done

    if (LAST) {
        // write t_ro (R1) linearly -> nmsg_out (= tmpb for k_readout)
        const int flat = tid * 16;
        const int row = flat >> 9, cbyte = flat & 511;
        uint4 d = *(const uint4*)(R1 + ((row * 512 + cbyte) ^ ((row & 7) << 4)));
        *(uint4*)((unsigned char*)nmsg_out + (brow + row) * 512 + cbyte) = d;
    } else {
        // ---- phase 5: mn' GEMM2: R1(t2) -> R0 -> linear copy to nmsg_out ----
        f32x4 acc[2];
#pragma unroll
        for (int n = 0; n < 2; ++n) acc[n] = f32x4{0.f, 0.f, 0.f, 0.f};
#pragma unroll
        for (int kk = 0; kk < 8; ++kk) {
            bf16x8 af = *(const bf16x8*)(R1 + ((arow * 512 + (kk * 4 + kg) * 16) ^ swz));
#pragma unroll
            for (int n = 0; n < 2; ++n) {
                const int col = w * 32 + n * 16 + r16;
                bf16x8 wf = *(const bf16x8*)(N2T + col * 256 + kk * 32 + kg * 8);
                acc[n] = __builtin_amdgcn_mfma_f32_16x16x32_bf16(wf, af, acc[n], 0, 0, 0);
            }
        }
#pragma unroll
        for (int n = 0; n < 2; ++n) {
            const int c0 = w * 32 + n * 16 + kg * 4;
            const f32x4 bv = *(const f32x4*)(nb2 + c0);
            uint2 p;
            p.x = (unsigned)f2b(acc[n][0] + bv[0]) | ((unsigned)f2b(acc[n][1] + bv[1]) << 16);
            p.y = (unsigned)f2b(acc[n][2] + bv[2]) | ((unsigned)f2b(acc[n][3] + bv[3]) << 16);
            *(uint2*)((unsigned char*)R0 + ((arow * 512 + c0 * 2) ^ swz)) = p;
        }
        __syncthreads();
        {
            const int flat = tid * 16;
            const int row = flat >> 9, cbyte = flat & 511;
            uint4 d = *(const uint4*)((unsigned char*)R0 + ((row * 512 + cbyte) ^ ((row & 7) << 4)));
            *(uint4*)((unsigned char*)nmsg_out + (brow + row) * 512 + cbyte) = d;
        }
    }
}

// ---------------- small kernels ----------------
__global__ void k_offsets(const int* __restrict__ num_nodes, int* __restrict__ off) {
    __shared__ int s[Bb];
    int t = threadIdx.x;
    s[t] = num_nodes[t];
    __syncthreads();
    for (int d = 1; d < Bb; d <<= 1) {
        int v = (t >= d) ? s[t - d] : 0;
        __syncthreads();
        s[t] += v;
        __syncthreads();
    }
    off[t + 1] = s[t];
    if (t == 0) off[0] = 0;
}

__global__ void k_edgeprep(const int* __restrict__ edges, const int* __restrict__ off,
                           int* __restrict__ gsrc, int* __restrict__ gdst, int* __restrict__ cnt) {
    int ge = blockIdx.x * 256 + threadIdx.x;
    if (ge >= TE) return;
    int b = ge >> 11;
    int o = off[b];
    gsrc[ge] = edges[ge * 2 + 0] + o;
    int d = edges[ge * 2 + 1] + o;
    gdst[ge] = d;
    atomicAdd(&cnt[d], 1);
}

__global__ void k_scan(const int* __restrict__ cnt, int* __restrict__ coff, int* __restrict__ pos) {
    __shared__ int part[1024];
    int t = threadIdx.x;
    int loc[8];
    int s = 0;
#pragma unroll
    for (int j = 0; j < 8; ++j) { loc[j] = cnt[t * 8 + j]; s += loc[j]; }
    part[t] = s;
    __syncthreads();
    for (int d = 1; d < 1024; d <<= 1) {
        int v = (t >= d) ? part[t - d] : 0;
        __syncthreads();
        part[t] += v;
        __syncthreads();
    }
    int base = part[t] - s;
#pragma unroll
    for (int j = 0; j < 8; ++j) {
        int idx = t * 8 + j;
        coff[idx] = base;
        pos[idx]  = base;
        base += loc[j];
    }
    if (t == 1023) coff[TN] = part[1023];
}

__global__ void k_fill(const int* __restrict__ gdst, const int* __restrict__ gsrc,
                       const float* __restrict__ ef,
                       int* __restrict__ pos, int* __restrict__ gsrcs,
                       float* __restrict__ dcsr) {
    int ge = blockIdx.x * 256 + threadIdx.x;
    if (ge >= TE) return;
    int d = gdst[ge];
    int p = atomicAdd(&pos[d], 1);
    gsrcs[p] = gsrc[ge];
    dcsr[p]  = ef[ge];
}

__global__ void k_rbfgrid(unsigned short* __restrict__ rbfg) {
    int gid = blockIdx.x * 256 + threadIdx.x;   // TABN * 64
    int i = gid >> 6, k = gid & 63;
    float v = 0.f;
    if (k < EDGE) {
        float d = (float)i / TSCALE;
        float t = d - 0.1f * (float)k;
        v = __expf(-50.f * t * t);
    }
    rbfg[gid] = f2b(v);
}

__global__ void k_embed(const int* __restrict__ nodes, const float* __restrict__ embed,
                        float* __restrict__ x, unsigned short* __restrict__ xb) {
    int gid = blockIdx.x * 256 + threadIdx.x;
    int i = gid >> 8, c = gid & 255;
    float v = embed[(nodes[i] << 8) + c];
    x[gid] = v;
    xb[gid] = f2b(v);
}

__global__ void k_wprep(const float* __restrict__ me_w1, const float* __restrict__ me_w2,
                        const float* __restrict__ mn_w1, const float* __restrict__ mn_w2,
                        const float* __restrict__ st_w1, const float* __restrict__ st_w2,
                        const float* __restrict__ ro_w1,
                        unsigned short* __restrict__ me1T, unsigned short* __restrict__ me2T,
                        unsigned short* __restrict__ mn1T, unsigned short* __restrict__ mn2T,
                        unsigned short* __restrict__ st1T, unsigned short* __restrict__ st2T,
                        unsigned short* __restrict__ ro1T) {
    int gid = blockIdx.x * 256 + threadIdx.x;
    const int S1 = Ll * 256 * EKPAD;
    if (gid < S1) {
        int i = gid / (256 * EKPAD);
        int r = gid % (256 * EKPAD);
        int n = r / EKPAD, k = r % EKPAD;
        float v = (k < EDGE) ? me_w1[(i * EDGE + k) * 256 + n] : 0.f;
        me1T[gid] = f2b(v);
        return;
    }
    gid -= S1;
    const int S2 = Ll * 256 * 256;
    const float* srcs[5] = { me_w2, mn_w1, mn_w2, st_w1, st_w2 };
    unsigned short* dsts[5] = { me2T, mn1T, mn2T, st1T, st2T };
#pragma unroll
    for (int q = 0; q < 5; ++q) {
        if (gid < S2) {
            int i = gid >> 16;
            int r = gid & 65535;
            int n = r >> 8, k = r & 255;
            dsts[q][gid] = f2b(srcs[q][(i << 16) + k * 256 + n]);
            return;
        }
        gid -= S2;
    }
    int n = gid >> 8, k = gid & 255;
    ro1T[gid] = f2b(ro_w1[k * 256 + n]);
}

__global__ void k_readout(const unsigned short* __restrict__ t, const float* __restrict__ w2,
                          const float* __restrict__ b2, const int* __restrict__ num_nodes,
                          const float* __restrict__ evw, const float* __restrict__ evb,
                          float* __restrict__ out) {
    __shared__ float red[256];
    int b = blockIdx.x, tid = threadIdx.x;
    const unsigned short* tb = t + (long)b * Nn * 256;
    float part = 0.f;
    for (int i = tid; i < Nn * 256; i += 256)
        part += b2f(tb[i]) * w2[i & 255];
    red[tid] = part;
    __syncthreads();
    for (int d = 128; d > 0; d >>= 1) {
        if (tid < d) red[tid] += red[tid + d];
        __syncthreads();
    }
    if (tid == 0) {
        float g = red[0] + (float)Nn * b2[0];
        g = g * 2.0f + (-1.5f) * (float)num_nodes[b];
        out[b * 4 + 0] = g * evw[0] + evb[0];
        out[b * 4 + 1] = spf(g * evw[1] + evb[1]);
        out[b * 4 + 2] = spf(g * evw[2] + evb[2]) + 1.f;
        out[b * 4 + 3] = spf(g * evw[3] + evb[3]);
    }
}

// ---------------- workspace layout ----------------
constexpr size_t al(size_t x) { return (x + 255) & ~(size_t)255; }
constexpr size_t O_OFF    = 0;
constexpr size_t O_GSRC   = al(O_OFF + 65 * 4);
constexpr size_t O_GDST   = al(O_GSRC + (size_t)TE * 4);
constexpr size_t O_CNT    = al(O_GDST + (size_t)TE * 4);
constexpr size_t O_COFF   = al(O_CNT + (size_t)TN * 4);
constexpr size_t O_POS    = al(O_COFF + (size_t)(TN + 1) * 4);
constexpr size_t O_GSRCS  = al(O_POS + (size_t)TN * 4);
constexpr size_t O_DCSR   = al(O_GSRCS + (size_t)TE * 4);
constexpr size_t O_RBFG   = al(O_DCSR + (size_t)TE * 4);
constexpr size_t O_TTAB   = al(O_RBFG + (size_t)TABN * EKPAD * 2);
constexpr size_t O_GTAB   = al(O_TTAB + (size_t)Ll * TABN * 256 * 2);
constexpr size_t O_ME1T   = al(O_GTAB + (size_t)Ll * TABN * 256 * 2);
constexpr size_t O_ME2T   = al(O_ME1T + (size_t)Ll * 256 * EKPAD * 2);
constexpr size_t O_MN1T   = al(O_ME2T + (size_t)Ll * 256 * 256 * 2);
constexpr size_t O_MN2T   = al(O_MN1T + (size_t)Ll * 256 * 256 * 2);
constexpr size_t O_ST1T   = al(O_MN2T + (size_t)Ll * 256 * 256 * 2);
constexpr size_t O_ST2T   = al(O_ST1T + (size_t)Ll * 256 * 256 * 2);
constexpr size_t O_RO1T   = al(O_ST2T + (size_t)Ll * 256 * 256 * 2);
constexpr size_t O_X      = al(O_RO1T + (size_t)256 * 256 * 2);
constexpr size_t O_XB     = al(O_X + (size_t)TN * 256 * 4);
constexpr size_t O_TMPB   = al(O_XB + (size_t)TN * 256 * 2);
constexpr size_t O_NMSGA  = al(O_TMPB + (size_t)TN * 256 * 2);
constexpr size_t O_NMSGB  = al(O_NMSGA + (size_t)TN * 256 * 2);
constexpr size_t WS_NEED  = al(O_NMSGB + (size_t)TN * 256 * 2);

extern "C" void kernel_launch(void* const* d_in, const int* in_sizes, int n_in,
                              void* d_out, int out_size, void* d_ws, size_t ws_size,
                              hipStream_t stream) {
    if (ws_size < WS_NEED) return;

    const int*   nodes     = (const int*)d_in[0];
    const int*   num_nodes = (const int*)d_in[1];
    const int*   edges     = (const int*)d_in[2];
    const float* efeat     = (const float*)d_in[3];
    const float* embed     = (const float*)d_in[5];
    const float* me_w1 = (const float*)d_in[6],  *me_b1 = (const float*)d_in[7];
    const float* me_w2 = (const float*)d_in[8],  *me_b2 = (const float*)d_in[9];
    const float* mn_w1 = (const float*)d_in[10], *mn_b1 = (const float*)d_in[11];
    const float* mn_w2 = (const float*)d_in[12], *mn_b2 = (const float*)d_in[13];
    const float* st_w1 = (const float*)d_in[14], *st_b1 = (const float*)d_in[15];
    const float* st_w2 = (const float*)d_in[16], *st_b2 = (const float*)d_in[17];
    const float* ro_w1 = (const float*)d_in[18], *ro_b1 = (const float*)d_in[19];
    const float* ro_w2 = (const float*)d_in[20], *ro_b2 = (const float*)d_in[21];
    const float* ev_w  = (const float*)d_in[22], *ev_b  = (const float*)d_in[23];

    char* ws = (char*)d_ws;
    int* off   = (int*)(ws + O_OFF);
    int* gsrc  = (int*)(ws + O_GSRC);
    int* gdst  = (int*)(ws + O_GDST);
    int* cnt   = (int*)(ws + O_CNT);
    int* coff  = (int*)(ws + O_COFF);
    int* pos   = (int*)(ws + O_POS);
    int* gsrcs = (int*)(ws + O_GSRCS);
    float* dcsr = (float*)(ws + O_DCSR);
    unsigned short* rbfg  = (unsigned short*)(ws + O_RBFG);
    unsigned short* ttab  = (unsigned short*)(ws + O_TTAB);
    unsigned short* gtab  = (unsigned short*)(ws + O_GTAB);
    unsigned short* me1T  = (unsigned short*)(ws + O_ME1T);
    unsigned short* me2T  = (unsigned short*)(ws + O_ME2T);
    unsigned short* mn1T  = (unsigned short*)(ws + O_MN1T);
    unsigned short* mn2T  = (unsigned short*)(ws + O_MN2T);
    unsigned short* st1T  = (unsigned short*)(ws + O_ST1T);
    unsigned short* st2T  = (unsigned short*)(ws + O_ST2T);
    unsigned short* ro1T  = (unsigned short*)(ws + O_RO1T);
    float*          x     = (float*)(ws + O_X);
    unsigned short* xb    = (unsigned short*)(ws + O_XB);
    unsigned short* tmpb  = (unsigned short*)(ws + O_TMPB);
    unsigned short* nmsgA = (unsigned short*)(ws + O_NMSGA);
    unsigned short* nmsgB = (unsigned short*)(ws + O_NMSGB);
    float* out = (float*)d_out;

    hipMemsetAsync(cnt, 0, TN * 4, stream);
    k_offsets<<<1, Bb, 0, stream>>>(num_nodes, off);
    k_edgeprep<<<TE / 256, 256, 0, stream>>>(edges, off, gsrc, gdst, cnt);
    k_scan<<<1, 1024, 0, stream>>>(cnt, coff, pos);
    k_fill<<<TE / 256, 256, 0, stream>>>(gdst, gsrc, efeat, pos, gsrcs, dcsr);
    k_rbfgrid<<<(TABN * EKPAD) / 256, 256, 0, stream>>>(rbfg);
    k_embed<<<TN, 256, 0, stream>>>(nodes, embed, x, xb);
    {
        const int total = Ll * 256 * EKPAD + 5 * Ll * 256 * 256 + 256 * 256;
        k_wprep<<<total / 256, 256, 0, stream>>>(me_w1, me_w2, mn_w1, mn_w2, st_w1, st_w2, ro_w1,
                                                 me1T, me2T, mn1T, mn2T, st1T, st2T, ro1T);
    }

    // ---- build all 6 layers' gate tables (z = layer) ----
    const dim3 gT(2, TABN / 128, Ll), blk(256);
    gemm_k<1, 0, 128><<<gT, blk, 0, stream>>>(rbfg, me1T, me_b1, ttab, nullptr, nullptr,
                                              TABN, EKPAD,
                                              0, 256 * EKPAD, 256, (long)TABN * 256);
    gemm_k<0, 0, 128><<<gT, blk, 0, stream>>>(ttab, me2T, me_b2, gtab, nullptr, nullptr,
                                              TABN, 256,
                                              (long)TABN * 256, 65536, 256, (long)TABN * 256);

    // ---- mn_0, then 6 fused STEP dispatches (nmsg ping-pong), then readout ----
    fused_mn0<<<TN / 16, 512, 0, stream>>>(xb, mn1T, mn_b1, mn2T, mn_b2, nmsgA);

    unsigned short* nin  = nmsgA;
    unsigned short* nout = nmsgB;
    for (int i = 0; i < Ll; ++i) {
        if (i < Ll - 1) {
            step_k<0><<<TN / 16, 512, 0, stream>>>(
                dcsr, gtab + (size_t)i * TABN * 256, nin, coff, gsrcs,
                st1T + i * 65536, st_b1 + i * 256, st2T + i * 65536, st_b2 + i * 256, x,
                mn1T + (i + 1) * 65536, mn_b1 + (i + 1) * 256,
                mn2T + (i + 1) * 65536, mn_b2 + (i + 1) * 256, nout);
            unsigned short* t = nin; nin = nout; nout = t;
        } else {
            step_k<1><<<TN / 16, 512, 0, stream>>>(
                dcsr, gtab + (size_t)i * TABN * 256, nin, coff, gsrcs,
                st1T + i * 65536, st_b1 + i * 256, st2T + i * 65536, st_b2 + i * 256, x,
                ro1T, ro_b1, nullptr, nullptr, tmpb);
        }
    }

    k_readout<<<Bb, 256, 0, stream>>>(tmpb, ro_w2, ro_b2, num_nodes, ev_w, ev_b, out);
}

// Round 19
// 349.449 us; speedup vs baseline: 3.3288x; 1.1712x over previous
//
#include <hip/hip_runtime.h>

#define Bb 64
#define Nn 128
#define Ee 2048
#define Hh 256
#define Ll 6
#define TN 8192
#define TE 131072
#define EDGE 50
#define EKPAD 64
#define TABN 512
#define TSCALE ((float)(TABN - 2) / 5.0f)

typedef __attribute__((ext_vector_type(4))) float f32x4;
typedef __attribute__((ext_vector_type(8))) __bf16 bf16x8;
typedef __attribute__((ext_vector_type(8))) unsigned short ushort8;

__device__ inline float b2f(unsigned short u) {
    union { unsigned u; float f; } v; v.u = ((unsigned)u) << 16; return v.f;
}
__device__ inline unsigned short f2b(float f) {
    union { float f; unsigned u; } v; v.f = f;
    unsigned r = v.u + 0x7fffu + ((v.u >> 16) & 1u);
    return (unsigned short)(r >> 16);
}
__device__ inline float spf(float x) {
    return fmaxf(x, 0.f) + __logf(1.f + __expf(-fabsf(x)));
}
__device__ inline float sspf(float x) {
    return spf(x) - 0.69314718055994530942f;
}

// ---------------- GEMM (R4-verified) + z-batch strides (table build) ----------------
template <int ACT, int OUTMODE, int TM>
__global__ __launch_bounds__(256)
void gemm_k(const unsigned short* __restrict__ A,
            const unsigned short* __restrict__ WT,
            const float* __restrict__ bias,
            unsigned short* __restrict__ Cb,
            float* __restrict__ Xf,
            unsigned short* __restrict__ Xb,
            int M, int K,
            long Az, long Wz, long bz, long Cz)
{
    constexpr int BK  = 64;
    constexpr int TNc = 128;
    constexpr int MR  = TM / 32;
    constexpr int NR  = 4;
    constexpr int SMEM_B = (TM + TNc) * BK * 2;

    __shared__ __align__(16) unsigned char smem[SMEM_B];
    unsigned short* As = (unsigned short*)smem;
    unsigned short* Bs = As + TM * BK;

    const int z = blockIdx.z;
    A += z * Az; WT += z * Wz; bias += z * bz;
    if (Cb) Cb += z * Cz;

    const int tid  = threadIdx.x;
    const int lane = tid & 63;
    const int w    = tid >> 6;
    const int wr   = w >> 1, wc = w & 1;
    const int r16  = lane & 15;
    const int kg   = lane >> 4;

    const long brow = (long)blockIdx.y * TM;
    const int  bcol = blockIdx.x * TNc;

    constexpr int ACH = TM / 8;
    constexpr int NCH = ACH + TNc / 8;
    constexpr int IPW = NCH / 4;
    const int lrow  = lane >> 3;
    const int lslot = lane & 7;

    f32x4 acc[MR][NR];
#pragma unroll
    for (int m = 0; m < MR; ++m)
#pragma unroll
        for (int n = 0; n < NR; ++n) acc[m][n] = f32x4{0.f, 0.f, 0.f, 0.f};

    for (int k0 = 0; k0 < K; k0 += BK) {
        __syncthreads();
#pragma unroll
        for (int i = 0; i < IPW; ++i) {
            const int c    = w * IPW + i;
            const bool isA = c < ACH;
            const int cc   = isA ? c : c - ACH;
            const int srow = cc * 8 + lrow;
            const int kch  = lslot ^ (srow & 7);
            const unsigned short* gp = isA
                ? A  + (brow + srow) * (long)K + k0 + kch * 8
                : WT + (bcol + srow) * (long)K + k0 + kch * 8;
            unsigned short* lp = (isA ? As : Bs) + cc * 512;
            __builtin_amdgcn_global_load_lds(
                (const __attribute__((address_space(1))) void*)gp,
                (__attribute__((address_space(3))) void*)lp, 16, 0, 0);
        }
        __syncthreads();

        bf16x8 a[MR][2], b[NR][2];
#pragma unroll
        for (int m = 0; m < MR; ++m) {
            const int row = wr * (MR * 16) + m * 16 + r16;
            const unsigned short* base = As + row * BK;
#pragma unroll
            for (int kk = 0; kk < 2; ++kk) {
                const int slot = (kk * 4 + kg) ^ (row & 7);
                a[m][kk] = *(const bf16x8*)(base + slot * 8);
            }
        }
#pragma unroll
        for (int n = 0; n < NR; ++n) {
            const int row = wc * 64 + n * 16 + r16;
            const unsigned short* base = Bs + row * BK;
#pragma unroll
            for (int kk = 0; kk < 2; ++kk) {
                const int slot = (kk * 4 + kg) ^ (row & 7);
                b[n][kk] = *(const bf16x8*)(base + slot * 8);
            }
        }
#pragma unroll
        for (int kk = 0; kk < 2; ++kk)
#pragma unroll
            for (int m = 0; m < MR; ++m)
#pragma unroll
                for (int n = 0; n < NR; ++n)
                    acc[m][n] = __builtin_amdgcn_mfma_f32_16x16x32_bf16(
                        b[n][kk], a[m][kk], acc[m][n], 0, 0, 0);
    }

    __syncthreads();

    {
#pragma unroll
        for (int m = 0; m < MR; ++m) {
            const int row = wr * (MR * 16) + m * 16 + r16;
#pragma unroll
            for (int n = 0; n < NR; ++n) {
                const int colL = wc * 64 + n * 16 + kg * 4;
                const f32x4 bv = *(const f32x4*)(bias + bcol + colL);
                float v0 = acc[m][n][0] + bv[0];
                float v1 = acc[m][n][1] + bv[1];
                float v2 = acc[m][n][2] + bv[2];
                float v3 = acc[m][n][3] + bv[3];
                if (ACT) { v0 = sspf(v0); v1 = sspf(v1); v2 = sspf(v2); v3 = sspf(v3); }
                uint2 p;
                p.x = (unsigned)f2b(v0) | ((unsigned)f2b(v1) << 16);
                p.y = (unsigned)f2b(v2) | ((unsigned)f2b(v3) << 16);
                const int off = (row * 256 + colL * 2) ^ ((row & 7) << 4);
                *(uint2*)(smem + off) = p;
            }
        }
        __syncthreads();
        constexpr int ITER = TM / 16;
#pragma unroll
        for (int q = 0; q < ITER; ++q) {
            const int flat = q * 4096 + tid * 16;
            const int row = flat >> 8, cbyte = flat & 255;
            uint4 d = *(const uint4*)(smem + ((row * 256 + cbyte) ^ ((row & 7) << 4)));
            *(uint4*)((unsigned char*)Cb + (brow + row) * 512 + bcol * 2 + cbyte) = d;
        }
    }
}

// ======== mn_0: fused node MLP, 16-row tiles, 8 waves (R17-verified) ========
__global__ __launch_bounds__(512, 2)
void fused_mn0(const unsigned short* __restrict__ Ab,
               const unsigned short* __restrict__ W1T,
               const float* __restrict__ b1,
               const unsigned short* __restrict__ W2T,
               const float* __restrict__ b2,
               unsigned short* __restrict__ Cb)
{
    __shared__ __align__(16) unsigned char smem[16384];
    unsigned short* A_lds = (unsigned short*)smem;
    unsigned char*  t_lds = smem + 8192;

    const int tid  = threadIdx.x;
    const int lane = tid & 63;
    const int w    = tid >> 6;
    const int r16  = lane & 15;
    const int kg   = lane >> 4;
    const long brow = (long)blockIdx.x * 16;

    {
        const int lrow  = lane >> 5;
        const int lslot = lane & 31;
        const int srow  = w * 2 + lrow;
        const int kch   = lslot ^ (srow & 7);
        const unsigned short* gp = Ab + (brow + srow) * 256 + kch * 8;
        __builtin_amdgcn_global_load_lds(
            (const __attribute__((address_space(1))) void*)gp,
            (__attribute__((address_space(3))) void*)(A_lds + w * 512), 16, 0, 0);
    }
    __syncthreads();

    const int arow = r16;
    const int swz  = (arow & 7) << 4;

    f32x4 acc1[2];
#pragma unroll
    for (int n = 0; n < 2; ++n) acc1[n] = f32x4{0.f, 0.f, 0.f, 0.f};
#pragma unroll
    for (int kk = 0; kk < 8; ++kk) {
        const int slot = (kk * 4 + kg) ^ (arow & 7);
        bf16x8 af = *(const bf16x8*)(A_lds + arow * 256 + slot * 8);
#pragma unroll
        for (int n = 0; n < 2; ++n) {
            const int col = w * 32 + n * 16 + r16;
            bf16x8 wf = *(const bf16x8*)(W1T + col * 256 + kk * 32 + kg * 8);
            acc1[n] = __builtin_amdgcn_mfma_f32_16x16x32_bf16(wf, af, acc1[n], 0, 0, 0);
        }
    }
#pragma unroll
    for (int n = 0; n < 2; ++n) {
        const int c0 = w * 32 + n * 16 + kg * 4;
        const f32x4 bv = *(const f32x4*)(b1 + c0);
        uint2 p;
        p.x = (unsigned)f2b(sspf(acc1[n][0] + bv[0])) |
              ((unsigned)f2b(sspf(acc1[n][1] + bv[1])) << 16);
        p.y = (unsigned)f2b(sspf(acc1[n][2] + bv[2])) |
              ((unsigned)f2b(sspf(acc1[n][3] + bv[3])) << 16);
        *(uint2*)(t_lds + ((arow * 512 + c0 * 2) ^ swz)) = p;
    }
    __syncthreads();

    f32x4 acc2[2];
#pragma unroll
    for (int n = 0; n < 2; ++n) acc2[n] = f32x4{0.f, 0.f, 0.f, 0.f};
#pragma unroll
    for (int kk = 0; kk < 8; ++kk) {
        bf16x8 af = *(const bf16x8*)(t_lds + ((arow * 512 + (kk * 4 + kg) * 16) ^ swz));
#pragma unroll
        for (int n = 0; n < 2; ++n) {
            const int col = w * 32 + n * 16 + r16;
            bf16x8 wf = *(const bf16x8*)(W2T + col * 256 + kk * 32 + kg * 8);
            acc2[n] = __builtin_amdgcn_mfma_f32_16x16x32_bf16(wf, af, acc2[n], 0, 0, 0);
        }
    }
    __syncthreads();

#pragma unroll
    for (int n = 0; n < 2; ++n) {
        const int c0 = w * 32 + n * 16 + kg * 4;
        const f32x4 bv = *(const f32x4*)(b2 + c0);
        uint2 p;
        p.x = (unsigned)f2b(acc2[n][0] + bv[0]) | ((unsigned)f2b(acc2[n][1] + bv[1]) << 16);
        p.y = (unsigned)f2b(acc2[n][2] + bv[2]) | ((unsigned)f2b(acc2[n][3] + bv[3]) << 16);
        *(uint2*)(smem + ((arow * 512 + c0 * 2) ^ swz)) = p;
    }
    __syncthreads();
    {
        const int flat = tid * 16;
        const int row = flat >> 9, cbyte = flat & 511;
        uint4 d = *(const uint4*)(smem + ((row * 512 + cbyte) ^ ((row & 7) << 4)));
        *(uint4*)((unsigned char*)Cb + (brow + row) * 512 + cbyte) = d;
    }
}

// ======== STEP (R18-verified) + XCD-aware remap + fused readout on LAST ========
// Block remap: graph = bid & 63, sub = bid >> 6  -> a graph's 8 blocks share an XCD
// (default dispatch round-robins bid%8 over XCDs) -> nmsg slice cached once per L2.
// LAST: t_ro reduced in-block against ro_w2 -> gsum[graph*8+sub] (no atomics).
template <int LAST>
__global__ __launch_bounds__(512, 2)
void step_k(const float* __restrict__ dcsr,
            const unsigned short* __restrict__ tab,
            const unsigned short* __restrict__ nmsg_in,
            const int* __restrict__ coff,
            const int* __restrict__ gsrcs,
            const unsigned short* __restrict__ S1T, const float* __restrict__ sb1,
            const unsigned short* __restrict__ S2T, const float* __restrict__ sb2,
            float* __restrict__ Xf,
            const unsigned short* __restrict__ N1T, const float* __restrict__ nb1,
            const unsigned short* __restrict__ N2T, const float* __restrict__ nb2,
            unsigned short* __restrict__ nmsg_out,
            const float* __restrict__ ro_w2, float* __restrict__ gsum)
{
    __shared__ __align__(16) unsigned char smem[16384];       // R0(8K) + R1(8K)
    unsigned short* R0 = (unsigned short*)smem;
    unsigned char*  R1 = smem + 8192;

    const int tid  = threadIdx.x;
    const int lane = tid & 63;
    const int w    = tid >> 6;
    const int r16  = lane & 15;
    const int kg   = lane >> 4;
    const int graph = blockIdx.x & 63;
    const int sub   = blockIdx.x >> 6;
    const long brow = (long)graph * Nn + sub * 16;

    const int arow = r16;
    const int swz  = (arow & 7) << 4;

    // ---- phase 1: aggregation -> R0 ----
    {
        const int node = tid >> 5;
        const int c0   = (tid & 31) * 8;
        const int gn   = (int)brow + node;
        float s[8];
#pragma unroll
        for (int j = 0; j < 8; ++j) s[j] = 0.f;
        const int beg = coff[gn], end = coff[gn + 1];
        for (int i = beg; i < end; ++i) {
            const float d  = dcsr[i];
            const int   sr = gsrcs[i];
            const float xx = d * TSCALE;
            const int   i0 = (int)xx;
            const float f  = xx - (float)i0;
            const unsigned short* t0 = tab + (long)i0 * 256 + c0;
            ushort8 g0 = *(const ushort8*)t0;
            ushort8 g1 = *(const ushort8*)(t0 + 256);
            ushort8 nm = *(const ushort8*)(nmsg_in + ((long)sr << 8) + c0);
#pragma unroll
            for (int j = 0; j < 8; ++j) {
                float a = b2f(g0[j]);
                s[j] += (a + (b2f(g1[j]) - a) * f) * b2f(nm[j]);
            }
        }
        const int swzn = (node & 7) << 4;
#pragma unroll
        for (int j = 0; j < 2; ++j) {
            uint2 p;
            p.x = (unsigned)f2b(s[j * 4 + 0]) | ((unsigned)f2b(s[j * 4 + 1]) << 16);
            p.y = (unsigned)f2b(s[j * 4 + 2]) | ((unsigned)f2b(s[j * 4 + 3]) << 16);
            const int c = c0 + j * 4;
            *(uint2*)((unsigned char*)R0 + ((node * 512 + c * 2) ^ swzn)) = p;
        }
    }
    __syncthreads();

    // ---- phase 2: st GEMM1: R0(msum) -> R1(t), ssp ----
    {
        f32x4 acc[2];
#pragma unroll
        for (int n = 0; n < 2; ++n) acc[n] = f32x4{0.f, 0.f, 0.f, 0.f};
#pragma unroll
        for (int kk = 0; kk < 8; ++kk) {
            const int slot = (kk * 4 + kg) ^ (arow & 7);
            bf16x8 af = *(const bf16x8*)(R0 + arow * 256 + slot * 8);
#pragma unroll
            for (int n = 0; n < 2; ++n) {
                const int col = w * 32 + n * 16 + r16;
                bf16x8 wf = *(const bf16x8*)(S1T + col * 256 + kk * 32 + kg * 8);
                acc[n] = __builtin_amdgcn_mfma_f32_16x16x32_bf16(wf, af, acc[n], 0, 0, 0);
            }
        }
#pragma unroll
        for (int n = 0; n < 2; ++n) {
            const int c0 = w * 32 + n * 16 + kg * 4;
            const f32x4 bv = *(const f32x4*)(sb1 + c0);
            uint2 p;
            p.x = (unsigned)f2b(sspf(acc[n][0] + bv[0])) |
                  ((unsigned)f2b(sspf(acc[n][1] + bv[1])) << 16);
            p.y = (unsigned)f2b(sspf(acc[n][2] + bv[2])) |
                  ((unsigned)f2b(sspf(acc[n][3] + bv[3])) << 16);
            *(uint2*)(R1 + ((arow * 512 + c0 * 2) ^ swz)) = p;
        }
    }
    __syncthreads();

    // ---- phase 3: st GEMM2: R1(t) -> x update + xb_new -> R0 ----
    {
        f32x4 acc[2];
#pragma unroll
        for (int n = 0; n < 2; ++n) acc[n] = f32x4{0.f, 0.f, 0.f, 0.f};
#pragma unroll
        for (int kk = 0; kk < 8; ++kk) {
            bf16x8 af = *(const bf16x8*)(R1 + ((arow * 512 + (kk * 4 + kg) * 16) ^ swz));
#pragma unroll
            for (int n = 0; n < 2; ++n) {
                const int col = w * 32 + n * 16 + r16;
                bf16x8 wf = *(const bf16x8*)(S2T + col * 256 + kk * 32 + kg * 8);
                acc[n] = __builtin_amdgcn_mfma_f32_16x16x32_bf16(wf, af, acc[n], 0, 0, 0);
            }
        }
#pragma unroll
        for (int n = 0; n < 2; ++n) {
            const int c0 = w * 32 + n * 16 + kg * 4;
            const f32x4 bv = *(const f32x4*)(sb2 + c0);
            const long base = (brow + arow) * 256 + c0;
            f32x4 xo = *(const f32x4*)(Xf + base);
            f32x4 nx;
            nx[0] = xo[0] + acc[n][0] + bv[0];
            nx[1] = xo[1] + acc[n][1] + bv[1];
            nx[2] = xo[2] + acc[n][2] + bv[2];
            nx[3] = xo[3] + acc[n][3] + bv[3];
            *(f32x4*)(Xf + base) = nx;
            uint2 p;
            p.x = (unsigned)f2b(nx[0]) | ((unsigned)f2b(nx[1]) << 16);
            p.y = (unsigned)f2b(nx[2]) | ((unsigned)f2b(nx[3]) << 16);
            *(uint2*)((unsigned char*)R0 + ((arow * 512 + c0 * 2) ^ swz)) = p;
        }
    }
    __syncthreads();

    // ---- phase 4: next GEMM1 (mn' or ro1): R0(xb_new) -> R1(t2), ssp ----
    {
        f32x4 acc[2];
#pragma unroll
        for (int n = 0; n < 2; ++n) acc[n] = f32x4{0.f, 0.f, 0.f, 0.f};
#pragma unroll
        for (int kk = 0; kk < 8; ++kk) {
            bf16x8 af = *(const bf16x8*)((unsigned char*)R0 + ((arow * 512 + (kk * 4 + kg) * 16) ^ swz));
#pragma unroll
            for (int n = 0; n < 2; ++n) {
                const int col = w * 32 + n * 16 + r16;
                bf16x8 wf = *(const bf16x8*)(N1T + col * 256 + kk * 32 + kg * 8);
                acc[n] = __builtin_amdgcn_mfma_f32_16x16x32_bf16(wf, af, acc[n], 0, 0, 0);
            }
        }
#pragma unroll
        for (int n = 0; n < 2; ++n) {
            const int c0 = w * 32 + n * 16 + kg * 4;
            const f32x4 bv = *(const f32x4*)(nb1 + c0);
            uint2 p;
            p.x = (unsigned)f2b(sspf(acc[n][0] + bv[0])) |
                  ((unsigned)f2b(sspf(acc[n][1] + bv[1])) << 16);
            p.y = (unsigned)f2b(sspf(acc[n][2] + bv[2])) |
                  ((unsigned)f2b(sspf(acc[n][3] + bv[3])) << 16);
            *(uint2*)(R1 + ((arow * 512 + c0 * 2) ^ swz)) = p;
        }
    }
    __syncthreads();

    if (LAST) {
        // fused readout: partial = sum over tile of t_ro[r][c] * ro_w2[c]
        float part = 0.f;
        {
            const int flat = tid * 16;
            const int row = flat >> 9, cbyte = flat & 511;
            ushort8 u = *(const ushort8*)(R1 + ((row * 512 + cbyte) ^ ((row & 7) << 4)));
            const int c = cbyte >> 1;
#pragma unroll
            for (int j = 0; j < 8; ++j)
                part += b2f(u[j]) * ro_w2[c + j];
        }
        float* red = (float*)R0;      // xb_new dead on last layer
        red[tid] = part;
        __syncthreads();
        for (int d = 256; d > 0; d >>= 1) {
            if (tid < d) red[tid] += red[tid + d];
            __syncthreads();
        }
        if (tid == 0) gsum[graph * 8 + sub] = red[0];
    } else {
        // ---- phase 5: mn' GEMM2: R1(t2) -> R0 -> linear copy to nmsg_out ----
        f32x4 acc[2];
#pragma unroll
        for (int n = 0; n < 2; ++n) acc[n] = f32x4{0.f, 0.f, 0.f, 0.f};
#pragma unroll
        for (int kk = 0; kk < 8; ++kk) {
            bf16x8 af = *(const bf16x8*)(R1 + ((arow * 512 + (kk * 4 + kg) * 16) ^ swz));
#pragma unroll
            for (int n = 0; n < 2; ++n) {
                const int col = w * 32 + n * 16 + r16;
                bf16x8 wf = *(const bf16x8*)(N2T + col * 256 + kk * 32 + kg * 8);
                acc[n] = __builtin_amdgcn_mfma_f32_16x16x32_bf16(wf, af, acc[n], 0, 0, 0);
            }
        }
#pragma unroll
        for (int n = 0; n < 2; ++n) {
            const int c0 = w * 32 + n * 16 + kg * 4;
            const f32x4 bv = *(const f32x4*)(nb2 + c0);
            uint2 p;
            p.x = (unsigned)f2b(acc[n][0] + bv[0]) | ((unsigned)f2b(acc[n][1] + bv[1]) << 16);
            p.y = (unsigned)f2b(acc[n][2] + bv[2]) | ((unsigned)f2b(acc[n][3] + bv[3]) << 16);
            *(uint2*)((unsigned char*)R0 + ((arow * 512 + c0 * 2) ^ swz)) = p;
        }
        __syncthreads();
        {
            const int flat = tid * 16;
            const int row = flat >> 9, cbyte = flat & 511;
            uint4 d = *(const uint4*)((unsigned char*)R0 + ((row * 512 + cbyte) ^ ((row & 7) << 4)));
            *(uint4*)((unsigned char*)nmsg_out + (brow + row) * 512 + cbyte) = d;
        }
    }
}

// final scalar tail: combine 8 partials per graph, apply ev head
__global__ void k_final(const float* __restrict__ gsum, const float* __restrict__ ro_b2,
                        const int* __restrict__ num_nodes,
                        const float* __restrict__ evw, const float* __restrict__ evb,
                        float* __restrict__ out) {
    int g = threadIdx.x;
    if (g >= Bb) return;
    float s = 0.f;
#pragma unroll
    for (int j = 0; j < 8; ++j) s += gsum[g * 8 + j];
    float gg = s + (float)Nn * ro_b2[0];
    gg = gg * 2.0f + (-1.5f) * (float)num_nodes[g];
    out[g * 4 + 0] = gg * evw[0] + evb[0];
    out[g * 4 + 1] = spf(gg * evw[1] + evb[1]);
    out[g * 4 + 2] = spf(gg * evw[2] + evb[2]) + 1.f;
    out[g * 4 + 3] = spf(gg * evw[3] + evb[3]);
}

// ---------------- small kernels ----------------
__global__ void k_offsets(const int* __restrict__ num_nodes, int* __restrict__ off) {
    __shared__ int s[Bb];
    int t = threadIdx.x;
    s[t] = num_nodes[t];
    __syncthreads();
    for (int d = 1; d < Bb; d <<= 1) {
        int v = (t >= d) ? s[t - d] : 0;
        __syncthreads();
        s[t] += v;
        __syncthreads();
    }
    off[t + 1] = s[t];
    if (t == 0) off[0] = 0;
}

__global__ void k_edgeprep(const int* __restrict__ edges, const int* __restrict__ off,
                           int* __restrict__ gsrc, int* __restrict__ gdst, int* __restrict__ cnt) {
    int ge = blockIdx.x * 256 + threadIdx.x;
    if (ge >= TE) return;
    int b = ge >> 11;
    int o = off[b];
    gsrc[ge] = edges[ge * 2 + 0] + o;
    int d = edges[ge * 2 + 1] + o;
    gdst[ge] = d;
    atomicAdd(&cnt[d], 1);
}

__global__ void k_scan(const int* __restrict__ cnt, int* __restrict__ coff, int* __restrict__ pos) {
    __shared__ int part[1024];
    int t = threadIdx.x;
    int loc[8];
    int s = 0;
#pragma unroll
    for (int j = 0; j < 8; ++j) { loc[j] = cnt[t * 8 + j]; s += loc[j]; }
    part[t] = s;
    __syncthreads();
    for (int d = 1; d < 1024; d <<= 1) {
        int v = (t >= d) ? part[t - d] : 0;
        __syncthreads();
        part[t] += v;
        __syncthreads();
    }
    int base = part[t] - s;
#pragma unroll
    for (int j = 0; j < 8; ++j) {
        int idx = t * 8 + j;
        coff[idx] = base;
        pos[idx]  = base;
        base += loc[j];
    }
    if (t == 1023) coff[TN] = part[1023];
}

__global__ void k_fill(const int* __restrict__ gdst, const int* __restrict__ gsrc,
                       const float* __restrict__ ef,
                       int* __restrict__ pos, int* __restrict__ gsrcs,
                       float* __restrict__ dcsr) {
    int ge = blockIdx.x * 256 + threadIdx.x;
    if (ge >= TE) return;
    int d = gdst[ge];
    int p = atomicAdd(&pos[d], 1);
    gsrcs[p] = gsrc[ge];
    dcsr[p]  = ef[ge];
}

__global__ void k_rbfgrid(unsigned short* __restrict__ rbfg) {
    int gid = blockIdx.x * 256 + threadIdx.x;   // TABN * 64
    int i = gid >> 6, k = gid & 63;
    float v = 0.f;
    if (k < EDGE) {
        float d = (float)i / TSCALE;
        float t = d - 0.1f * (float)k;
        v = __expf(-50.f * t * t);
    }
    rbfg[gid] = f2b(v);
}

__global__ void k_embed(const int* __restrict__ nodes, const float* __restrict__ embed,
                        float* __restrict__ x, unsigned short* __restrict__ xb) {
    int gid = blockIdx.x * 256 + threadIdx.x;
    int i = gid >> 8, c = gid & 255;
    float v = embed[(nodes[i] << 8) + c];
    x[gid] = v;
    xb[gid] = f2b(v);
}

__global__ void k_wprep(const float* __restrict__ me_w1, const float* __restrict__ me_w2,
                        const float* __restrict__ mn_w1, const float* __restrict__ mn_w2,
                        const float* __restrict__ st_w1, const float* __restrict__ st_w2,
                        const float* __restrict__ ro_w1,
                        unsigned short* __restrict__ me1T, unsigned short* __restrict__ me2T,
                        unsigned short* __restrict__ mn1T, unsigned short* __restrict__ mn2T,
                        unsigned short* __restrict__ st1T, unsigned short* __restrict__ st2T,
                        unsigned short* __restrict__ ro1T) {
    int gid = blockIdx.x * 256 + threadIdx.x;
    const int S1 = Ll * 256 * EKPAD;
    if (gid < S1) {
        int i = gid / (256 * EKPAD);
        int r = gid % (256 * EKPAD);
        int n = r / EKPAD, k = r % EKPAD;
        float v = (k < EDGE) ? me_w1[(i * EDGE + k) * 256 + n] : 0.f;
        me1T[gid] = f2b(v);
        return;
    }
    gid -= S1;
    const int S2 = Ll * 256 * 256;
    const float* srcs[5] = { me_w2, mn_w1, mn_w2, st_w1, st_w2 };
    unsigned short* dsts[5] = { me2T, mn1T, mn2T, st1T, st2T };
#pragma unroll
    for (int q = 0; q < 5; ++q) {
        if (gid < S2) {
            int i = gid >> 16;
            int r = gid & 65535;
            int n = r >> 8, k = r & 255;
            dsts[q][gid] = f2b(srcs[q][(i << 16) + k * 256 + n]);
            return;
        }
        gid -= S2;
    }
    int n = gid >> 8, k = gid & 255;
    ro1T[gid] = f2b(ro_w1[k * 256 + n]);
}

// ---------------- workspace layout ----------------
constexpr size_t al(size_t x) { return (x + 255) & ~(size_t)255; }
constexpr size_t O_OFF    = 0;
constexpr size_t O_GSRC   = al(O_OFF + 65 * 4);
constexpr size_t O_GDST   = al(O_GSRC + (size_t)TE * 4);
constexpr size_t O_CNT    = al(O_GDST + (size_t)TE * 4);
constexpr size_t O_COFF   = al(O_CNT + (size_t)TN * 4);
constexpr size_t O_POS    = al(O_COFF + (size_t)(TN + 1) * 4);
constexpr size_t O_GSRCS  = al(O_POS + (size_t)TN * 4);
constexpr size_t O_DCSR   = al(O_GSRCS + (size_t)TE * 4);
constexpr size_t O_RBFG   = al(O_DCSR + (size_t)TE * 4);
constexpr size_t O_TTAB   = al(O_RBFG + (size_t)TABN * EKPAD * 2);
constexpr size_t O_GTAB   = al(O_TTAB + (size_t)Ll * TABN * 256 * 2);
constexpr size_t O_ME1T   = al(O_GTAB + (size_t)Ll * TABN * 256 * 2);
constexpr size_t O_ME2T   = al(O_ME1T + (size_t)Ll * 256 * EKPAD * 2);
constexpr size_t O_MN1T   = al(O_ME2T + (size_t)Ll * 256 * 256 * 2);
constexpr size_t O_MN2T   = al(O_MN1T + (size_t)Ll * 256 * 256 * 2);
constexpr size_t O_ST1T   = al(O_MN2T + (size_t)Ll * 256 * 256 * 2);
constexpr size_t O_ST2T   = al(O_ST1T + (size_t)Ll * 256 * 256 * 2);
constexpr size_t O_RO1T   = al(O_ST2T + (size_t)Ll * 256 * 256 * 2);
constexpr size_t O_X      = al(O_RO1T + (size_t)256 * 256 * 2);
constexpr size_t O_XB     = al(O_X + (size_t)TN * 256 * 4);
constexpr size_t O_NMSGA  = al(O_XB + (size_t)TN * 256 * 2);
constexpr size_t O_NMSGB  = al(O_NMSGA + (size_t)TN * 256 * 2);
constexpr size_t O_GSUM   = al(O_NMSGB + (size_t)TN * 256 * 2);
constexpr size_t WS_NEED  = al(O_GSUM + (size_t)Bb * 8 * 4);

extern "C" void kernel_launch(void* const* d_in, const int* in_sizes, int n_in,
                              void* d_out, int out_size, void* d_ws, size_t ws_size,
                              hipStream_t stream) {
    if (ws_size < WS_NEED) return;

    const int*   nodes     = (const int*)d_in[0];
    const int*   num_nodes = (const int*)d_in[1];
    const int*   edges     = (const int*)d_in[2];
    const float* efeat     = (const float*)d_in[3];
    const float* embed     = (const float*)d_in[5];
    const float* me_w1 = (const float*)d_in[6],  *me_b1 = (const float*)d_in[7];
    const float* me_w2 = (const float*)d_in[8],  *me_b2 = (const float*)d_in[9];
    const float* mn_w1 = (const float*)d_in[10], *mn_b1 = (const float*)d_in[11];
    const float* mn_w2 = (const float*)d_in[12], *mn_b2 = (const float*)d_in[13];
    const float* st_w1 = (const float*)d_in[14], *st_b1 = (const float*)d_in[15];
    const float* st_w2 = (const float*)d_in[16], *st_b2 = (const float*)d_in[17];
    const float* ro_w1 = (const float*)d_in[18], *ro_b1 = (const float*)d_in[19];
    const float* ro_w2 = (const float*)d_in[20], *ro_b2 = (const float*)d_in[21];
    const float* ev_w  = (const float*)d_in[22], *ev_b  = (const float*)d_in[23];

    char* ws = (char*)d_ws;
    int* off   = (int*)(ws + O_OFF);
    int* gsrc  = (int*)(ws + O_GSRC);
    int* gdst  = (int*)(ws + O_GDST);
    int* cnt   = (int*)(ws + O_CNT);
    int* coff  = (int*)(ws + O_COFF);
    int* pos   = (int*)(ws + O_POS);
    int* gsrcs = (int*)(ws + O_GSRCS);
    float* dcsr = (float*)(ws + O_DCSR);
    unsigned short* rbfg  = (unsigned short*)(ws + O_RBFG);
    unsigned short* ttab  = (unsigned short*)(ws + O_TTAB);
    unsigned short* gtab  = (unsigned short*)(ws + O_GTAB);
    unsigned short* me1T  = (unsigned short*)(ws + O_ME1T);
    unsigned short* me2T  = (unsigned short*)(ws + O_ME2T);
    unsigned short* mn1T  = (unsigned short*)(ws + O_MN1T);
    unsigned short* mn2T  = (unsigned short*)(ws + O_MN2T);
    unsigned short* st1T  = (unsigned short*)(ws + O_ST1T);
    unsigned short* st2T  = (unsigned short*)(ws + O_ST2T);
    unsigned short* ro1T  = (unsigned short*)(ws + O_RO1T);
    float*          x     = (float*)(ws + O_X);
    unsigned short* xb    = (unsigned short*)(ws + O_XB);
    unsigned short* nmsgA = (unsigned short*)(ws + O_NMSGA);
    unsigned short* nmsgB = (unsigned short*)(ws + O_NMSGB);
    float*          gsum  = (float*)(ws + O_GSUM);
    float* out = (float*)d_out;

    hipMemsetAsync(cnt, 0, TN * 4, stream);
    k_offsets<<<1, Bb, 0, stream>>>(num_nodes, off);
    k_edgeprep<<<TE / 256, 256, 0, stream>>>(edges, off, gsrc, gdst, cnt);
    k_scan<<<1, 1024, 0, stream>>>(cnt, coff, pos);
    k_fill<<<TE / 256, 256, 0, stream>>>(gdst, gsrc, efeat, pos, gsrcs, dcsr);
    k_rbfgrid<<<(TABN * EKPAD) / 256, 256, 0, stream>>>(rbfg);
    k_embed<<<TN, 256, 0, stream>>>(nodes, embed, x, xb);
    {
        const int total = Ll * 256 * EKPAD + 5 * Ll * 256 * 256 + 256 * 256;
        k_wprep<<<total / 256, 256, 0, stream>>>(me_w1, me_w2, mn_w1, mn_w2, st_w1, st_w2, ro_w1,
                                                 me1T, me2T, mn1T, mn2T, st1T, st2T, ro1T);
    }

    // ---- build all 6 layers' gate tables (z = layer) ----
    const dim3 gT(2, TABN / 128, Ll), blk(256);
    gemm_k<1, 0, 128><<<gT, blk, 0, stream>>>(rbfg, me1T, me_b1, ttab, nullptr, nullptr,
                                              TABN, EKPAD,
                                              0, 256 * EKPAD, 256, (long)TABN * 256);
    gemm_k<0, 0, 128><<<gT, blk, 0, stream>>>(ttab, me2T, me_b2, gtab, nullptr, nullptr,
                                              TABN, 256,
                                              (long)TABN * 256, 65536, 256, (long)TABN * 256);

    // ---- mn_0, 6 fused STEP dispatches (ping-pong), final scalar tail ----
    fused_mn0<<<TN / 16, 512, 0, stream>>>(xb, mn1T, mn_b1, mn2T, mn_b2, nmsgA);

    unsigned short* nin  = nmsgA;
    unsigned short* nout = nmsgB;
    for (int i = 0; i < Ll; ++i) {
        if (i < Ll - 1) {
            step_k<0><<<TN / 16, 512, 0, stream>>>(
                dcsr, gtab + (size_t)i * TABN * 256, nin, coff, gsrcs,
                st1T + i * 65536, st_b1 + i * 256, st2T + i * 65536, st_b2 + i * 256, x,
                mn1T + (i + 1) * 65536, mn_b1 + (i + 1) * 256,
                mn2T + (i + 1) * 65536, mn_b2 + (i + 1) * 256, nout,
                nullptr, nullptr);
            unsigned short* t = nin; nin = nout; nout = t;
        } else {
            step_k<1><<<TN / 16, 512, 0, stream>>>(
                dcsr, gtab + (size_t)i * TABN * 256, nin, coff, gsrcs,
                st1T + i * 65536, st_b1 + i * 256, st2T + i * 65536, st_b2 + i * 256, x,
                ro1T, ro_b1, nullptr, nullptr, nullptr,
                ro_w2, gsum);
        }
    }

    k_final<<<1, Bb, 0, stream>>>(gsum, ro_b2, num_nodes, ev_w, ev_b, out);
}

// Round 20
// 266.876 us; speedup vs baseline: 4.3588x; 1.3094x over previous
//
#include <hip/hip_runtime.h>

#define Bb 64
#define Nn 128
#define Ee 2048
#define Hh 256
#define Ll 6
#define TN 8192
#define TE 131072
#define EDGE 50
#define EKPAD 64
#define TABN 512
#define TSCALE ((float)(TABN - 2) / 5.0f)

typedef __attribute__((ext_vector_type(4))) float f32x4;
typedef __attribute__((ext_vector_type(8))) __bf16 bf16x8;
typedef __attribute__((ext_vector_type(8))) unsigned short ushort8;

__device__ inline float b2f(unsigned short u) {
    union { unsigned u; float f; } v; v.u = ((unsigned)u) << 16; return v.f;
}
__device__ inline unsigned short f2b(float f) {
    union { float f; unsigned u; } v; v.f = f;
    unsigned r = v.u + 0x7fffu + ((v.u >> 16) & 1u);
    return (unsigned short)(r >> 16);
}
__device__ inline float spf(float x) {
    return fmaxf(x, 0.f) + __logf(1.f + __expf(-fabsf(x)));
}
__device__ inline float sspf(float x) {
    return spf(x) - 0.69314718055994530942f;
}

// ---------------- GEMM (R4-verified) + z-batch strides (table build only) ----------------
template <int ACT, int OUTMODE, int TM>
__global__ __launch_bounds__(256)
void gemm_k(const unsigned short* __restrict__ A,
            const unsigned short* __restrict__ WT,
            const float* __restrict__ bias,
            unsigned short* __restrict__ Cb,
            float* __restrict__ Xf,
            unsigned short* __restrict__ Xb,
            int M, int K,
            long Az, long Wz, long bz, long Cz)
{
    constexpr int BK  = 64;
    constexpr int TNc = 128;
    constexpr int MR  = TM / 32;
    constexpr int NR  = 4;
    constexpr int SMEM_B = (TM + TNc) * BK * 2;

    __shared__ __align__(16) unsigned char smem[SMEM_B];
    unsigned short* As = (unsigned short*)smem;
    unsigned short* Bs = As + TM * BK;

    const int z = blockIdx.z;
    A += z * Az; WT += z * Wz; bias += z * bz;
    if (Cb) Cb += z * Cz;

    const int tid  = threadIdx.x;
    const int lane = tid & 63;
    const int w    = tid >> 6;
    const int wr   = w >> 1, wc = w & 1;
    const int r16  = lane & 15;
    const int kg   = lane >> 4;

    const long brow = (long)blockIdx.y * TM;
    const int  bcol = blockIdx.x * TNc;

    constexpr int ACH = TM / 8;
    constexpr int NCH = ACH + TNc / 8;
    constexpr int IPW = NCH / 4;
    const int lrow  = lane >> 3;
    const int lslot = lane & 7;

    f32x4 acc[MR][NR];
#pragma unroll
    for (int m = 0; m < MR; ++m)
#pragma unroll
        for (int n = 0; n < NR; ++n) acc[m][n] = f32x4{0.f, 0.f, 0.f, 0.f};

    for (int k0 = 0; k0 < K; k0 += BK) {
        __syncthreads();
#pragma unroll
        for (int i = 0; i < IPW; ++i) {
            const int c    = w * IPW + i;
            const bool isA = c < ACH;
            const int cc   = isA ? c : c - ACH;
            const int srow = cc * 8 + lrow;
            const int kch  = lslot ^ (srow & 7);
            const unsigned short* gp = isA
                ? A  + (brow + srow) * (long)K + k0 + kch * 8
                : WT + (bcol + srow) * (long)K + k0 + kch * 8;
            unsigned short* lp = (isA ? As : Bs) + cc * 512;
            __builtin_amdgcn_global_load_lds(
                (const __attribute__((address_space(1))) void*)gp,
                (__attribute__((address_space(3))) void*)lp, 16, 0, 0);
        }
        __syncthreads();

        bf16x8 a[MR][2], b[NR][2];
#pragma unroll
        for (int m = 0; m < MR; ++m) {
            const int row = wr * (MR * 16) + m * 16 + r16;
            const unsigned short* base = As + row * BK;
#pragma unroll
            for (int kk = 0; kk < 2; ++kk) {
                const int slot = (kk * 4 + kg) ^ (row & 7);
                a[m][kk] = *(const bf16x8*)(base + slot * 8);
            }
        }
#pragma unroll
        for (int n = 0; n < NR; ++n) {
            const int row = wc * 64 + n * 16 + r16;
            const unsigned short* base = Bs + row * BK;
#pragma unroll
            for (int kk = 0; kk < 2; ++kk) {
                const int slot = (kk * 4 + kg) ^ (row & 7);
                b[n][kk] = *(const bf16x8*)(base + slot * 8);
            }
        }
#pragma unroll
        for (int kk = 0; kk < 2; ++kk)
#pragma unroll
            for (int m = 0; m < MR; ++m)
#pragma unroll
                for (int n = 0; n < NR; ++n)
                    acc[m][n] = __builtin_amdgcn_mfma_f32_16x16x32_bf16(
                        b[n][kk], a[m][kk], acc[m][n], 0, 0, 0);
    }

    __syncthreads();

    {
#pragma unroll
        for (int m = 0; m < MR; ++m) {
            const int row = wr * (MR * 16) + m * 16 + r16;
#pragma unroll
            for (int n = 0; n < NR; ++n) {
                const int colL = wc * 64 + n * 16 + kg * 4;
                const f32x4 bv = *(const f32x4*)(bias + bcol + colL);
                float v0 = acc[m][n][0] + bv[0];
                float v1 = acc[m][n][1] + bv[1];
                float v2 = acc[m][n][2] + bv[2];
                float v3 = acc[m][n][3] + bv[3];
                if (ACT) { v0 = sspf(v0); v1 = sspf(v1); v2 = sspf(v2); v3 = sspf(v3); }
                uint2 p;
                p.x = (unsigned)f2b(v0) | ((unsigned)f2b(v1) << 16);
                p.y = (unsigned)f2b(v2) | ((unsigned)f2b(v3) << 16);
                const int off = (row * 256 + colL * 2) ^ ((row & 7) << 4);
                *(uint2*)(smem + off) = p;
            }
        }
        __syncthreads();
        constexpr int ITER = TM / 16;
#pragma unroll
        for (int q = 0; q < ITER; ++q) {
            const int flat = q * 4096 + tid * 16;
            const int row = flat >> 8, cbyte = flat & 255;
            uint4 d = *(const uint4*)(smem + ((row * 256 + cbyte) ^ ((row & 7) << 4)));
            *(uint4*)((unsigned char*)Cb + (brow + row) * 512 + bcol * 2 + cbyte) = d;
        }
    }
}

// k-major weight read: lanes (r16,kg) cover one contiguous 1KB block per (kk,n)
__device__ inline bf16x8 wld(const unsigned short* __restrict__ W, int kk, int col, int kg) {
    return *(const bf16x8*)(W + kk * 8192 + col * 32 + kg * 8);
}

// ======== mn_0: fused node MLP, 16-row tiles, 8 waves (R17-verified, k-major W) ========
__global__ __launch_bounds__(512, 2)
void fused_mn0(const unsigned short* __restrict__ Ab,
               const unsigned short* __restrict__ W1T,
               const float* __restrict__ b1,
               const unsigned short* __restrict__ W2T,
               const float* __restrict__ b2,
               unsigned short* __restrict__ Cb)
{
    __shared__ __align__(16) unsigned char smem[16384];
    unsigned short* A_lds = (unsigned short*)smem;
    unsigned char*  t_lds = smem + 8192;

    const int tid  = threadIdx.x;
    const int lane = tid & 63;
    const int w    = tid >> 6;
    const int r16  = lane & 15;
    const int kg   = lane >> 4;
    const long brow = (long)blockIdx.x * 16;

    {
        const int lrow  = lane >> 5;
        const int lslot = lane & 31;
        const int srow  = w * 2 + lrow;
        const int kch   = lslot ^ (srow & 7);
        const unsigned short* gp = Ab + (brow + srow) * 256 + kch * 8;
        __builtin_amdgcn_global_load_lds(
            (const __attribute__((address_space(1))) void*)gp,
            (__attribute__((address_space(3))) void*)(A_lds + w * 512), 16, 0, 0);
    }
    __syncthreads();

    const int arow = r16;
    const int swz  = (arow & 7) << 4;

    f32x4 acc1[2];
#pragma unroll
    for (int n = 0; n < 2; ++n) acc1[n] = f32x4{0.f, 0.f, 0.f, 0.f};
#pragma unroll
    for (int kk = 0; kk < 8; ++kk) {
        const int slot = (kk * 4 + kg) ^ (arow & 7);
        bf16x8 af = *(const bf16x8*)(A_lds + arow * 256 + slot * 8);
#pragma unroll
        for (int n = 0; n < 2; ++n)
            acc1[n] = __builtin_amdgcn_mfma_f32_16x16x32_bf16(
                wld(W1T, kk, w * 32 + n * 16 + r16, kg), af, acc1[n], 0, 0, 0);
    }
#pragma unroll
    for (int n = 0; n < 2; ++n) {
        const int c0 = w * 32 + n * 16 + kg * 4;
        const f32x4 bv = *(const f32x4*)(b1 + c0);
        uint2 p;
        p.x = (unsigned)f2b(sspf(acc1[n][0] + bv[0])) |
              ((unsigned)f2b(sspf(acc1[n][1] + bv[1])) << 16);
        p.y = (unsigned)f2b(sspf(acc1[n][2] + bv[2])) |
              ((unsigned)f2b(sspf(acc1[n][3] + bv[3])) << 16);
        *(uint2*)(t_lds + ((arow * 512 + c0 * 2) ^ swz)) = p;
    }
    __syncthreads();

    f32x4 acc2[2];
#pragma unroll
    for (int n = 0; n < 2; ++n) acc2[n] = f32x4{0.f, 0.f, 0.f, 0.f};
#pragma unroll
    for (int kk = 0; kk < 8; ++kk) {
        bf16x8 af = *(const bf16x8*)(t_lds + ((arow * 512 + (kk * 4 + kg) * 16) ^ swz));
#pragma unroll
        for (int n = 0; n < 2; ++n)
            acc2[n] = __builtin_amdgcn_mfma_f32_16x16x32_bf16(
                wld(W2T, kk, w * 32 + n * 16 + r16, kg), af, acc2[n], 0, 0, 0);
    }
    __syncthreads();

#pragma unroll
    for (int n = 0; n < 2; ++n) {
        const int c0 = w * 32 + n * 16 + kg * 4;
        const f32x4 bv = *(const f32x4*)(b2 + c0);
        uint2 p;
        p.x = (unsigned)f2b(acc2[n][0] + bv[0]) | ((unsigned)f2b(acc2[n][1] + bv[1]) << 16);
        p.y = (unsigned)f2b(acc2[n][2] + bv[2]) | ((unsigned)f2b(acc2[n][3] + bv[3]) << 16);
        *(uint2*)(smem + ((arow * 512 + c0 * 2) ^ swz)) = p;
    }
    __syncthreads();
    {
        const int flat = tid * 16;
        const int row = flat >> 9, cbyte = flat & 511;
        uint4 d = *(const uint4*)(smem + ((row * 512 + cbyte) ^ ((row & 7) << 4)));
        *(uint4*)((unsigned char*)Cb + (brow + row) * 512 + cbyte) = d;
    }
}

// ======== STEP (R18/R19-verified) with k-major weights ========
template <int LAST>
__global__ __launch_bounds__(512, 2)
void step_k(const float* __restrict__ dcsr,
            const unsigned short* __restrict__ tab,
            const unsigned short* __restrict__ nmsg_in,
            const int* __restrict__ coff,
            const int* __restrict__ gsrcs,
            const unsigned short* __restrict__ S1T, const float* __restrict__ sb1,
            const unsigned short* __restrict__ S2T, const float* __restrict__ sb2,
            float* __restrict__ Xf,
            const unsigned short* __restrict__ N1T, const float* __restrict__ nb1,
            const unsigned short* __restrict__ N2T, const float* __restrict__ nb2,
            unsigned short* __restrict__ nmsg_out,
            const float* __restrict__ ro_w2, float* __restrict__ gsum)
{
    __shared__ __align__(16) unsigned char smem[16384];       // R0(8K) + R1(8K)
    unsigned short* R0 = (unsigned short*)smem;
    unsigned char*  R1 = smem + 8192;

    const int tid  = threadIdx.x;
    const int lane = tid & 63;
    const int w    = tid >> 6;
    const int r16  = lane & 15;
    const int kg   = lane >> 4;
    const int graph = blockIdx.x & 63;
    const int sub   = blockIdx.x >> 6;
    const long brow = (long)graph * Nn + sub * 16;

    const int arow = r16;
    const int swz  = (arow & 7) << 4;

    // ---- phase 1: aggregation -> R0 ----
    {
        const int node = tid >> 5;
        const int c0   = (tid & 31) * 8;
        const int gn   = (int)brow + node;
        float s[8];
#pragma unroll
        for (int j = 0; j < 8; ++j) s[j] = 0.f;
        const int beg = coff[gn], end = coff[gn + 1];
        for (int i = beg; i < end; ++i) {
            const float d  = dcsr[i];
            const int   sr = gsrcs[i];
            const float xx = d * TSCALE;
            const int   i0 = (int)xx;
            const float f  = xx - (float)i0;
            const unsigned short* t0 = tab + (long)i0 * 256 + c0;
            ushort8 g0 = *(const ushort8*)t0;
            ushort8 g1 = *(const ushort8*)(t0 + 256);
            ushort8 nm = *(const ushort8*)(nmsg_in + ((long)sr << 8) + c0);
#pragma unroll
            for (int j = 0; j < 8; ++j) {
                float a = b2f(g0[j]);
                s[j] += (a + (b2f(g1[j]) - a) * f) * b2f(nm[j]);
            }
        }
        const int swzn = (node & 7) << 4;
#pragma unroll
        for (int j = 0; j < 2; ++j) {
            uint2 p;
            p.x = (unsigned)f2b(s[j * 4 + 0]) | ((unsigned)f2b(s[j * 4 + 1]) << 16);
            p.y = (unsigned)f2b(s[j * 4 + 2]) | ((unsigned)f2b(s[j * 4 + 3]) << 16);
            const int c = c0 + j * 4;
            *(uint2*)((unsigned char*)R0 + ((node * 512 + c * 2) ^ swzn)) = p;
        }
    }
    __syncthreads();

    // ---- phase 2: st GEMM1: R0(msum) -> R1(t), ssp ----
    {
        f32x4 acc[2];
#pragma unroll
        for (int n = 0; n < 2; ++n) acc[n] = f32x4{0.f, 0.f, 0.f, 0.f};
#pragma unroll
        for (int kk = 0; kk < 8; ++kk) {
            const int slot = (kk * 4 + kg) ^ (arow & 7);
            bf16x8 af = *(const bf16x8*)(R0 + arow * 256 + slot * 8);
#pragma unroll
            for (int n = 0; n < 2; ++n)
                acc[n] = __builtin_amdgcn_mfma_f32_16x16x32_bf16(
                    wld(S1T, kk, w * 32 + n * 16 + r16, kg), af, acc[n], 0, 0, 0);
        }
#pragma unroll
        for (int n = 0; n < 2; ++n) {
            const int c0 = w * 32 + n * 16 + kg * 4;
            const f32x4 bv = *(const f32x4*)(sb1 + c0);
            uint2 p;
            p.x = (unsigned)f2b(sspf(acc[n][0] + bv[0])) |
                  ((unsigned)f2b(sspf(acc[n][1] + bv[1])) << 16);
            p.y = (unsigned)f2b(sspf(acc[n][2] + bv[2])) |
                  ((unsigned)f2b(sspf(acc[n][3] + bv[3])) << 16);
            *(uint2*)(R1 + ((arow * 512 + c0 * 2) ^ swz)) = p;
        }
    }
    __syncthreads();

    // ---- phase 3: st GEMM2: R1(t) -> x update + xb_new -> R0 ----
    {
        f32x4 acc[2];
#pragma unroll
        for (int n = 0; n < 2; ++n) acc[n] = f32x4{0.f, 0.f, 0.f, 0.f};
#pragma unroll
        for (int kk = 0; kk < 8; ++kk) {
            bf16x8 af = *(const bf16x8*)(R1 + ((arow * 512 + (kk * 4 + kg) * 16) ^ swz));
#pragma unroll
            for (int n = 0; n < 2; ++n)
                acc[n] = __builtin_amdgcn_mfma_f32_16x16x32_bf16(
                    wld(S2T, kk, w * 32 + n * 16 + r16, kg), af, acc[n], 0, 0, 0);
        }
#pragma unroll
        for (int n = 0; n < 2; ++n) {
            const int c0 = w * 32 + n * 16 + kg * 4;
            const f32x4 bv = *(const f32x4*)(sb2 + c0);
            const long base = (brow + arow) * 256 + c0;
            f32x4 xo = *(const f32x4*)(Xf + base);
            f32x4 nx;
            nx[0] = xo[0] + acc[n][0] + bv[0];
            nx[1] = xo[1] + acc[n][1] + bv[1];
            nx[2] = xo[2] + acc[n][2] + bv[2];
            nx[3] = xo[3] + acc[n][3] + bv[3];
            *(f32x4*)(Xf + base) = nx;
            uint2 p;
            p.x = (unsigned)f2b(nx[0]) | ((unsigned)f2b(nx[1]) << 16);
            p.y = (unsigned)f2b(nx[2]) | ((unsigned)f2b(nx[3]) << 16);
            *(uint2*)((unsigned char*)R0 + ((arow * 512 + c0 * 2) ^ swz)) = p;
        }
    }
    __syncthreads();

    // ---- phase 4: next GEMM1 (mn' or ro1): R0(xb_new) -> R1(t2), ssp ----
    {
        f32x4 acc[2];
#pragma unroll
        for (int n = 0; n < 2; ++n) acc[n] = f32x4{0.f, 0.f, 0.f, 0.f};
#pragma unroll
        for (int kk = 0; kk < 8; ++kk) {
            bf16x8 af = *(const bf16x8*)((unsigned char*)R0 + ((arow * 512 + (kk * 4 + kg) * 16) ^ swz));
#pragma unroll
            for (int n = 0; n < 2; ++n)
                acc[n] = __builtin_amdgcn_mfma_f32_16x16x32_bf16(
                    wld(N1T, kk, w * 32 + n * 16 + r16, kg), af, acc[n], 0, 0, 0);
        }
#pragma unroll
        for (int n = 0; n < 2; ++n) {
            const int c0 = w * 32 + n * 16 + kg * 4;
            const f32x4 bv = *(const f32x4*)(nb1 + c0);
            uint2 p;
            p.x = (unsigned)f2b(sspf(acc[n][0] + bv[0])) |
                  ((unsigned)f2b(sspf(acc[n][1] + bv[1])) << 16);
            p.y = (unsigned)f2b(sspf(acc[n][2] + bv[2])) |
                  ((unsigned)f2b(sspf(acc[n][3] + bv[3])) << 16);
            *(uint2*)(R1 + ((arow * 512 + c0 * 2) ^ swz)) = p;
        }
    }
    __syncthreads();

    if (LAST) {
        float part = 0.f;
        {
            const int flat = tid * 16;
            const int row = flat >> 9, cbyte = flat & 511;
            ushort8 u = *(const ushort8*)(R1 + ((row * 512 + cbyte) ^ ((row & 7) << 4)));
            const int c = cbyte >> 1;
#pragma unroll
            for (int j = 0; j < 8; ++j)
                part += b2f(u[j]) * ro_w2[c + j];
        }
        float* red = (float*)R0;
        red[tid] = part;
        __syncthreads();
        for (int d = 256; d > 0; d >>= 1) {
            if (tid < d) red[tid] += red[tid + d];
            __syncthreads();
        }
        if (tid == 0) gsum[graph * 8 + sub] = red[0];
    } else {
        f32x4 acc[2];
#pragma unroll
        for (int n = 0; n < 2; ++n) acc[n] = f32x4{0.f, 0.f, 0.f, 0.f};
#pragma unroll
        for (int kk = 0; kk < 8; ++kk) {
            bf16x8 af = *(const bf16x8*)(R1 + ((arow * 512 + (kk * 4 + kg) * 16) ^ swz));
#pragma unroll
            for (int n = 0; n < 2; ++n)
                acc[n] = __builtin_amdgcn_mfma_f32_16x16x32_bf16(
                    wld(N2T, kk, w * 32 + n * 16 + r16, kg), af, acc[n], 0, 0, 0);
        }
#pragma unroll
        for (int n = 0; n < 2; ++n) {
            const int c0 = w * 32 + n * 16 + kg * 4;
            const f32x4 bv = *(const f32x4*)(nb2 + c0);
            uint2 p;
            p.x = (unsigned)f2b(acc[n][0] + bv[0]) | ((unsigned)f2b(acc[n][1] + bv[1]) << 16);
            p.y = (unsigned)f2b(acc[n][2] + bv[2]) | ((unsigned)f2b(acc[n][3] + bv[3]) << 16);
            *(uint2*)((unsigned char*)R0 + ((arow * 512 + c0 * 2) ^ swz)) = p;
        }
        __syncthreads();
        {
            const int flat = tid * 16;
            const int row = flat >> 9, cbyte = flat & 511;
            uint4 d = *(const uint4*)((unsigned char*)R0 + ((row * 512 + cbyte) ^ ((row & 7) << 4)));
            *(uint4*)((unsigned char*)nmsg_out + (brow + row) * 512 + cbyte) = d;
        }
    }
}

// final scalar tail
__global__ void k_final(const float* __restrict__ gsum, const float* __restrict__ ro_b2,
                        const int* __restrict__ num_nodes,
                        const float* __restrict__ evw, const float* __restrict__ evb,
                        float* __restrict__ out) {
    int g = threadIdx.x;
    if (g >= Bb) return;
    float s = 0.f;
#pragma unroll
    for (int j = 0; j < 8; ++j) s += gsum[g * 8 + j];
    float gg = s + (float)Nn * ro_b2[0];
    gg = gg * 2.0f + (-1.5f) * (float)num_nodes[g];
    out[g * 4 + 0] = gg * evw[0] + evb[0];
    out[g * 4 + 1] = spf(gg * evw[1] + evb[1]);
    out[g * 4 + 2] = spf(gg * evw[2] + evb[2]) + 1.f;
    out[g * 4 + 3] = spf(gg * evw[3] + evb[3]);
}

// ---------------- small kernels ----------------
__global__ void k_offsets(const int* __restrict__ num_nodes, int* __restrict__ off) {
    __shared__ int s[Bb];
    int t = threadIdx.x;
    s[t] = num_nodes[t];
    __syncthreads();
    for (int d = 1; d < Bb; d <<= 1) {
        int v = (t >= d) ? s[t - d] : 0;
        __syncthreads();
        s[t] += v;
        __syncthreads();
    }
    off[t + 1] = s[t];
    if (t == 0) off[0] = 0;
}

__global__ void k_edgeprep(const int* __restrict__ edges, const int* __restrict__ off,
                           int* __restrict__ gsrc, int* __restrict__ gdst, int* __restrict__ cnt) {
    int ge = blockIdx.x * 256 + threadIdx.x;
    if (ge >= TE) return;
    int b = ge >> 11;
    int o = off[b];
    gsrc[ge] = edges[ge * 2 + 0] + o;
    int d = edges[ge * 2 + 1] + o;
    gdst[ge] = d;
    atomicAdd(&cnt[d], 1);
}

__global__ void k_scan(const int* __restrict__ cnt, int* __restrict__ coff, int* __restrict__ pos) {
    __shared__ int part[1024];
    int t = threadIdx.x;
    int loc[8];
    int s = 0;
#pragma unroll
    for (int j = 0; j < 8; ++j) { loc[j] = cnt[t * 8 + j]; s += loc[j]; }
    part[t] = s;
    __syncthreads();
    for (int d = 1; d < 1024; d <<= 1) {
        int v = (t >= d) ? part[t - d] : 0;
        __syncthreads();
        part[t] += v;
        __syncthreads();
    }
    int base = part[t] - s;
#pragma unroll
    for (int j = 0; j < 8; ++j) {
        int idx = t * 8 + j;
        coff[idx] = base;
        pos[idx]  = base;
        base += loc[j];
    }
    if (t == 1023) coff[TN] = part[1023];
}

__global__ void k_fill(const int* __restrict__ gdst, const int* __restrict__ gsrc,
                       const float* __restrict__ ef,
                       int* __restrict__ pos, int* __restrict__ gsrcs,
                       float* __restrict__ dcsr) {
    int ge = blockIdx.x * 256 + threadIdx.x;
    if (ge >= TE) return;
    int d = gdst[ge];
    int p = atomicAdd(&pos[d], 1);
    gsrcs[p] = gsrc[ge];
    dcsr[p]  = ef[ge];
}

__global__ void k_rbfgrid(unsigned short* __restrict__ rbfg) {
    int gid = blockIdx.x * 256 + threadIdx.x;   // TABN * 64
    int i = gid >> 6, k = gid & 63;
    float v = 0.f;
    if (k < EDGE) {
        float d = (float)i / TSCALE;
        float t = d - 0.1f * (float)k;
        v = __expf(-50.f * t * t);
    }
    rbfg[gid] = f2b(v);
}

__global__ void k_embed(const int* __restrict__ nodes, const float* __restrict__ embed,
                        float* __restrict__ x, unsigned short* __restrict__ xb) {
    int gid = blockIdx.x * 256 + threadIdx.x;
    int i = gid >> 8, c = gid & 255;
    float v = embed[(nodes[i] << 8) + c];
    x[gid] = v;
    xb[gid] = f2b(v);
}

// weight prep: me1/me2 keep N x K layout (table-build gemm_k);
// mn/st/ro packed K-MAJOR: dst[(k>>5)*8192 + n*32 + (k&31)]  (per layer)
__global__ void k_wprep(const float* __restrict__ me_w1, const float* __restrict__ me_w2,
                        const float* __restrict__ mn_w1, const float* __restrict__ mn_w2,
                        const float* __restrict__ st_w1, const float* __restrict__ st_w2,
                        const float* __restrict__ ro_w1,
                        unsigned short* __restrict__ me1T, unsigned short* __restrict__ me2T,
                        unsigned short* __restrict__ mn1T, unsigned short* __restrict__ mn2T,
                        unsigned short* __restrict__ st1T, unsigned short* __restrict__ st2T,
                        unsigned short* __restrict__ ro1T) {
    int gid = blockIdx.x * 256 + threadIdx.x;
    const int S1 = Ll * 256 * EKPAD;
    if (gid < S1) {
        int i = gid / (256 * EKPAD);
        int r = gid % (256 * EKPAD);
        int n = r / EKPAD, k = r % EKPAD;
        float v = (k < EDGE) ? me_w1[(i * EDGE + k) * 256 + n] : 0.f;
        me1T[gid] = f2b(v);
        return;
    }
    gid -= S1;
    const int S2 = Ll * 256 * 256;
    if (gid < S2) {   // me2T: old N x K layout
        int i = gid >> 16;
        int r = gid & 65535;
        int n = r >> 8, k = r & 255;
        me2T[gid] = f2b(me_w2[(i << 16) + k * 256 + n]);
        return;
    }
    gid -= S2;
    const float* srcs[4] = { mn_w1, mn_w2, st_w1, st_w2 };
    unsigned short* dsts[4] = { mn1T, mn2T, st1T, st2T };
#pragma unroll
    for (int q = 0; q < 4; ++q) {
        if (gid < S2) {   // k-major layout
            int i = gid >> 16;
            int r = gid & 65535;
            int n = r >> 8, k = r & 255;
            float v = srcs[q][(i << 16) + k * 256 + n];
            dsts[q][(i << 16) + ((k >> 5) << 13) + n * 32 + (k & 31)] = f2b(v);
            return;
        }
        gid -= S2;
    }
    // ro1T: 256x256, k-major
    int n = gid >> 8, k = gid & 255;
    ro1T[((k >> 5) << 13) + n * 32 + (k & 31)] = f2b(ro_w1[k * 256 + n]);
}

// ---------------- workspace layout ----------------
constexpr size_t al(size_t x) { return (x + 255) & ~(size_t)255; }
constexpr size_t O_OFF    = 0;
constexpr size_t O_GSRC   = al(O_OFF + 65 * 4);
constexpr size_t O_GDST   = al(O_GSRC + (size_t)TE * 4);
constexpr size_t O_CNT    = al(O_GDST + (size_t)TE * 4);
constexpr size_t O_COFF   = al(O_CNT + (size_t)TN * 4);
constexpr size_t O_POS    = al(O_COFF + (size_t)(TN + 1) * 4);
constexpr size_t O_GSRCS  = al(O_POS + (size_t)TN * 4);
constexpr size_t O_DCSR   = al(O_GSRCS + (size_t)TE * 4);
constexpr size_t O_RBFG   = al(O_DCSR + (size_t)TE * 4);
constexpr size_t O_TTAB   = al(O_RBFG + (size_t)TABN * EKPAD * 2);
constexpr size_t O_GTAB   = al(O_TTAB + (size_t)Ll * TABN * 256 * 2);
constexpr size_t O_ME1T   = al(O_GTAB + (size_t)Ll * TABN * 256 * 2);
constexpr size_t O_ME2T   = al(O_ME1T + (size_t)Ll * 256 * EKPAD * 2);
constexpr size_t O_MN1T   = al(O_ME2T + (size_t)Ll * 256 * 256 * 2);
constexpr size_t O_MN2T   = al(O_MN1T + (size_t)Ll * 256 * 256 * 2);
constexpr size_t O_ST1T   = al(O_MN2T + (size_t)Ll * 256 * 256 * 2);
constexpr size_t O_ST2T   = al(O_ST1T + (size_t)Ll * 256 * 256 * 2);
constexpr size_t O_RO1T   = al(O_ST2T + (size_t)Ll * 256 * 256 * 2);
constexpr size_t O_X      = al(O_RO1T + (size_t)256 * 256 * 2);
constexpr size_t O_XB     = al(O_X + (size_t)TN * 256 * 4);
constexpr size_t O_NMSGA  = al(O_XB + (size_t)TN * 256 * 2);
constexpr size_t O_NMSGB  = al(O_NMSGA + (size_t)TN * 256 * 2);
constexpr size_t O_GSUM   = al(O_NMSGB + (size_t)TN * 256 * 2);
constexpr size_t WS_NEED  = al(O_GSUM + (size_t)Bb * 8 * 4);

extern "C" void kernel_launch(void* const* d_in, const int* in_sizes, int n_in,
                              void* d_out, int out_size, void* d_ws, size_t ws_size,
                              hipStream_t stream) {
    if (ws_size < WS_NEED) return;

    const int*   nodes     = (const int*)d_in[0];
    const int*   num_nodes = (const int*)d_in[1];
    const int*   edges     = (const int*)d_in[2];
    const float* efeat     = (const float*)d_in[3];
    const float* embed     = (const float*)d_in[5];
    const float* me_w1 = (const float*)d_in[6],  *me_b1 = (const float*)d_in[7];
    const float* me_w2 = (const float*)d_in[8],  *me_b2 = (const float*)d_in[9];
    const float* mn_w1 = (const float*)d_in[10], *mn_b1 = (const float*)d_in[11];
    const float* mn_w2 = (const float*)d_in[12], *mn_b2 = (const float*)d_in[13];
    const float* st_w1 = (const float*)d_in[14], *st_b1 = (const float*)d_in[15];
    const float* st_w2 = (const float*)d_in[16], *st_b2 = (const float*)d_in[17];
    const float* ro_w1 = (const float*)d_in[18], *ro_b1 = (const float*)d_in[19];
    const float* ro_w2 = (const float*)d_in[20], *ro_b2 = (const float*)d_in[21];
    const float* ev_w  = (const float*)d_in[22], *ev_b  = (const float*)d_in[23];

    char* ws = (char*)d_ws;
    int* off   = (int*)(ws + O_OFF);
    int* gsrc  = (int*)(ws + O_GSRC);
    int* gdst  = (int*)(ws + O_GDST);
    int* cnt   = (int*)(ws + O_CNT);
    int* coff  = (int*)(ws + O_COFF);
    int* pos   = (int*)(ws + O_POS);
    int* gsrcs = (int*)(ws + O_GSRCS);
    float* dcsr = (float*)(ws + O_DCSR);
    unsigned short* rbfg  = (unsigned short*)(ws + O_RBFG);
    unsigned short* ttab  = (unsigned short*)(ws + O_TTAB);
    unsigned short* gtab  = (unsigned short*)(ws + O_GTAB);
    unsigned short* me1T  = (unsigned short*)(ws + O_ME1T);
    unsigned short* me2T  = (unsigned short*)(ws + O_ME2T);
    unsigned short* mn1T  = (unsigned short*)(ws + O_MN1T);
    unsigned short* mn2T  = (unsigned short*)(ws + O_MN2T);
    unsigned short* st1T  = (unsigned short*)(ws + O_ST1T);
    unsigned short* st2T  = (unsigned short*)(ws + O_ST2T);
    unsigned short* ro1T  = (unsigned short*)(ws + O_RO1T);
    float*          x     = (float*)(ws + O_X);
    unsigned short* xb    = (unsigned short*)(ws + O_XB);
    unsigned short* nmsgA = (unsigned short*)(ws + O_NMSGA);
    unsigned short* nmsgB = (unsigned short*)(ws + O_NMSGB);
    float*          gsum  = (float*)(ws + O_GSUM);
    float* out = (float*)d_out;

    hipMemsetAsync(cnt, 0, TN * 4, stream);
    k_offsets<<<1, Bb, 0, stream>>>(num_nodes, off);
    k_edgeprep<<<TE / 256, 256, 0, stream>>>(edges, off, gsrc, gdst, cnt);
    k_scan<<<1, 1024, 0, stream>>>(cnt, coff, pos);
    k_fill<<<TE / 256, 256, 0, stream>>>(gdst, gsrc, efeat, pos, gsrcs, dcsr);
    k_rbfgrid<<<(TABN * EKPAD) / 256, 256, 0, stream>>>(rbfg);
    k_embed<<<TN, 256, 0, stream>>>(nodes, embed, x, xb);
    {
        const int total = Ll * 256 * EKPAD + 5 * Ll * 256 * 256 + 256 * 256;
        k_wprep<<<total / 256, 256, 0, stream>>>(me_w1, me_w2, mn_w1, mn_w2, st_w1, st_w2, ro_w1,
                                                 me1T, me2T, mn1T, mn2T, st1T, st2T, ro1T);
    }

    // ---- build all 6 layers' gate tables (z = layer) ----
    const dim3 gT(2, TABN / 128, Ll), blk(256);
    gemm_k<1, 0, 128><<<gT, blk, 0, stream>>>(rbfg, me1T, me_b1, ttab, nullptr, nullptr,
                                              TABN, EKPAD,
                                              0, 256 * EKPAD, 256, (long)TABN * 256);
    gemm_k<0, 0, 128><<<gT, blk, 0, stream>>>(ttab, me2T, me_b2, gtab, nullptr, nullptr,
                                              TABN, 256,
                                              (long)TABN * 256, 65536, 256, (long)TABN * 256);

    // ---- mn_0, 6 fused STEP dispatches (ping-pong), final scalar tail ----
    fused_mn0<<<TN / 16, 512, 0, stream>>>(xb, mn1T, mn_b1, mn2T, mn_b2, nmsgA);

    unsigned short* nin  = nmsgA;
    unsigned short* nout = nmsgB;
    for (int i = 0; i < Ll; ++i) {
        if (i < Ll - 1) {
            step_k<0><<<TN / 16, 512, 0, stream>>>(
                dcsr, gtab + (size_t)i * TABN * 256, nin, coff, gsrcs,
                st1T + i * 65536, st_b1 + i * 256, st2T + i * 65536, st_b2 + i * 256, x,
                mn1T + (i + 1) * 65536, mn_b1 + (i + 1) * 256,
                mn2T + (i + 1) * 65536, mn_b2 + (i + 1) * 256, nout,
                nullptr, nullptr);
            unsigned short* t = nin; nin = nout; nout = t;
        } else {
            step_k<1><<<TN / 16, 512, 0, stream>>>(
                dcsr, gtab + (size_t)i * TABN * 256, nin, coff, gsrcs,
                st1T + i * 65536, st_b1 + i * 256, st2T + i * 65536, st_b2 + i * 256, x,
                ro1T, ro_b1, nullptr, nullptr, nullptr,
                ro_w2, gsum);
        }
    }

    k_final<<<1, Bb, 0, stream>>>(gsum, ro_b2, num_nodes, ev_w, ev_b, out);
}

// Round 21
// 253.792 us; speedup vs baseline: 4.5835x; 1.0516x over previous
//
#include <hip/hip_runtime.h>

#define Bb 64
#define Nn 128
#define Ee 2048
#define Hh 256
#define Ll 6
#define TN 8192
#define TE 131072
#define EDGE 50
#define EKPAD 64
#define TABN 512
#define TSCALE ((float)(TABN - 2) / 5.0f)

typedef __attribute__((ext_vector_type(4))) float f32x4;
typedef __attribute__((ext_vector_type(8))) __bf16 bf16x8;
typedef __attribute__((ext_vector_type(8))) unsigned short ushort8;

__device__ inline float b2f(unsigned short u) {
    union { unsigned u; float f; } v; v.u = ((unsigned)u) << 16; return v.f;
}
__device__ inline unsigned short f2b(float f) {
    union { float f; unsigned u; } v; v.f = f;
    unsigned r = v.u + 0x7fffu + ((v.u >> 16) & 1u);
    return (unsigned short)(r >> 16);
}
__device__ inline float spf(float x) {
    return fmaxf(x, 0.f) + __logf(1.f + __expf(-fabsf(x)));
}
__device__ inline float sspf(float x) {
    return spf(x) - 0.69314718055994530942f;
}

// ---------------- GEMM (R4-verified) + z-batch strides (table build only) ----------------
template <int ACT, int OUTMODE, int TM>
__global__ __launch_bounds__(256)
void gemm_k(const unsigned short* __restrict__ A,
            const unsigned short* __restrict__ WT,
            const float* __restrict__ bias,
            unsigned short* __restrict__ Cb,
            float* __restrict__ Xf,
            unsigned short* __restrict__ Xb,
            int M, int K,
            long Az, long Wz, long bz, long Cz)
{
    constexpr int BK  = 64;
    constexpr int TNc = 128;
    constexpr int MR  = TM / 32;
    constexpr int NR  = 4;
    constexpr int SMEM_B = (TM + TNc) * BK * 2;

    __shared__ __align__(16) unsigned char smem[SMEM_B];
    unsigned short* As = (unsigned short*)smem;
    unsigned short* Bs = As + TM * BK;

    const int z = blockIdx.z;
    A += z * Az; WT += z * Wz; bias += z * bz;
    if (Cb) Cb += z * Cz;

    const int tid  = threadIdx.x;
    const int lane = tid & 63;
    const int w    = tid >> 6;
    const int wr   = w >> 1, wc = w & 1;
    const int r16  = lane & 15;
    const int kg   = lane >> 4;

    const long brow = (long)blockIdx.y * TM;
    const int  bcol = blockIdx.x * TNc;

    constexpr int ACH = TM / 8;
    constexpr int NCH = ACH + TNc / 8;
    constexpr int IPW = NCH / 4;
    const int lrow  = lane >> 3;
    const int lslot = lane & 7;

    f32x4 acc[MR][NR];
#pragma unroll
    for (int m = 0; m < MR; ++m)
#pragma unroll
        for (int n = 0; n < NR; ++n) acc[m][n] = f32x4{0.f, 0.f, 0.f, 0.f};

    for (int k0 = 0; k0 < K; k0 += BK) {
        __syncthreads();
#pragma unroll
        for (int i = 0; i < IPW; ++i) {
            const int c    = w * IPW + i;
            const bool isA = c < ACH;
            const int cc   = isA ? c : c - ACH;
            const int srow = cc * 8 + lrow;
            const int kch  = lslot ^ (srow & 7);
            const unsigned short* gp = isA
                ? A  + (brow + srow) * (long)K + k0 + kch * 8
                : WT + (bcol + srow) * (long)K + k0 + kch * 8;
            unsigned short* lp = (isA ? As : Bs) + cc * 512;
            __builtin_amdgcn_global_load_lds(
                (const __attribute__((address_space(1))) void*)gp,
                (__attribute__((address_space(3))) void*)lp, 16, 0, 0);
        }
        __syncthreads();

        bf16x8 a[MR][2], b[NR][2];
#pragma unroll
        for (int m = 0; m < MR; ++m) {
            const int row = wr * (MR * 16) + m * 16 + r16;
            const unsigned short* base = As + row * BK;
#pragma unroll
            for (int kk = 0; kk < 2; ++kk) {
                const int slot = (kk * 4 + kg) ^ (row & 7);
                a[m][kk] = *(const bf16x8*)(base + slot * 8);
            }
        }
#pragma unroll
        for (int n = 0; n < NR; ++n) {
            const int row = wc * 64 + n * 16 + r16;
            const unsigned short* base = Bs + row * BK;
#pragma unroll
            for (int kk = 0; kk < 2; ++kk) {
                const int slot = (kk * 4 + kg) ^ (row & 7);
                b[n][kk] = *(const bf16x8*)(base + slot * 8);
            }
        }
#pragma unroll
        for (int kk = 0; kk < 2; ++kk)
#pragma unroll
            for (int m = 0; m < MR; ++m)
#pragma unroll
                for (int n = 0; n < NR; ++n)
                    acc[m][n] = __builtin_amdgcn_mfma_f32_16x16x32_bf16(
                        b[n][kk], a[m][kk], acc[m][n], 0, 0, 0);
    }

    __syncthreads();

    {
#pragma unroll
        for (int m = 0; m < MR; ++m) {
            const int row = wr * (MR * 16) + m * 16 + r16;
#pragma unroll
            for (int n = 0; n < NR; ++n) {
                const int colL = wc * 64 + n * 16 + kg * 4;
                const f32x4 bv = *(const f32x4*)(bias + bcol + colL);
                float v0 = acc[m][n][0] + bv[0];
                float v1 = acc[m][n][1] + bv[1];
                float v2 = acc[m][n][2] + bv[2];
                float v3 = acc[m][n][3] + bv[3];
                if (ACT) { v0 = sspf(v0); v1 = sspf(v1); v2 = sspf(v2); v3 = sspf(v3); }
                uint2 p;
                p.x = (unsigned)f2b(v0) | ((unsigned)f2b(v1) << 16);
                p.y = (unsigned)f2b(v2) | ((unsigned)f2b(v3) << 16);
                const int off = (row * 256 + colL * 2) ^ ((row & 7) << 4);
                *(uint2*)(smem + off) = p;
            }
        }
        __syncthreads();
        constexpr int ITER = TM / 16;
#pragma unroll
        for (int q = 0; q < ITER; ++q) {
            const int flat = q * 4096 + tid * 16;
            const int row = flat >> 8, cbyte = flat & 255;
            uint4 d = *(const uint4*)(smem + ((row * 256 + cbyte) ^ ((row & 7) << 4)));
            *(uint4*)((unsigned char*)Cb + (brow + row) * 512 + bcol * 2 + cbyte) = d;
        }
    }
}

// k-major weight read: lanes (r16,kg) cover one contiguous 1KB block per (kk,n)
__device__ inline bf16x8 wld(const unsigned short* __restrict__ W, int kk, int col, int kg) {
    return *(const bf16x8*)(W + kk * 8192 + col * 32 + kg * 8);
}

// ======== mn_0: fused node MLP, 16-row tiles, 8 waves (R17/R20-verified) ========
__global__ __launch_bounds__(512, 2)
void fused_mn0(const unsigned short* __restrict__ Ab,
               const unsigned short* __restrict__ W1T,
               const float* __restrict__ b1,
               const unsigned short* __restrict__ W2T,
               const float* __restrict__ b2,
               unsigned short* __restrict__ Cb)
{
    __shared__ __align__(16) unsigned char smem[16384];
    unsigned short* A_lds = (unsigned short*)smem;
    unsigned char*  t_lds = smem + 8192;

    const int tid  = threadIdx.x;
    const int lane = tid & 63;
    const int w    = tid >> 6;
    const int r16  = lane & 15;
    const int kg   = lane >> 4;
    const long brow = (long)blockIdx.x * 16;

    {
        const int lrow  = lane >> 5;
        const int lslot = lane & 31;
        const int srow  = w * 2 + lrow;
        const int kch   = lslot ^ (srow & 7);
        const unsigned short* gp = Ab + (brow + srow) * 256 + kch * 8;
        __builtin_amdgcn_global_load_lds(
            (const __attribute__((address_space(1))) void*)gp,
            (__attribute__((address_space(3))) void*)(A_lds + w * 512), 16, 0, 0);
    }
    __syncthreads();

    const int arow = r16;
    const int swz  = (arow & 7) << 4;

    f32x4 acc1[2];
#pragma unroll
    for (int n = 0; n < 2; ++n) acc1[n] = f32x4{0.f, 0.f, 0.f, 0.f};
#pragma unroll
    for (int kk = 0; kk < 8; ++kk) {
        const int slot = (kk * 4 + kg) ^ (arow & 7);
        bf16x8 af = *(const bf16x8*)(A_lds + arow * 256 + slot * 8);
#pragma unroll
        for (int n = 0; n < 2; ++n)
            acc1[n] = __builtin_amdgcn_mfma_f32_16x16x32_bf16(
                wld(W1T, kk, w * 32 + n * 16 + r16, kg), af, acc1[n], 0, 0, 0);
    }
#pragma unroll
    for (int n = 0; n < 2; ++n) {
        const int c0 = w * 32 + n * 16 + kg * 4;
        const f32x4 bv = *(const f32x4*)(b1 + c0);
        uint2 p;
        p.x = (unsigned)f2b(sspf(acc1[n][0] + bv[0])) |
              ((unsigned)f2b(sspf(acc1[n][1] + bv[1])) << 16);
        p.y = (unsigned)f2b(sspf(acc1[n][2] + bv[2])) |
              ((unsigned)f2b(sspf(acc1[n][3] + bv[3])) << 16);
        *(uint2*)(t_lds + ((arow * 512 + c0 * 2) ^ swz)) = p;
    }
    __syncthreads();

    f32x4 acc2[2];
#pragma unroll
    for (int n = 0; n < 2; ++n) acc2[n] = f32x4{0.f, 0.f, 0.f, 0.f};
#pragma unroll
    for (int kk = 0; kk < 8; ++kk) {
        bf16x8 af = *(const bf16x8*)(t_lds + ((arow * 512 + (kk * 4 + kg) * 16) ^ swz));
#pragma unroll
        for (int n = 0; n < 2; ++n)
            acc2[n] = __builtin_amdgcn_mfma_f32_16x16x32_bf16(
                wld(W2T, kk, w * 32 + n * 16 + r16, kg), af, acc2[n], 0, 0, 0);
    }
    __syncthreads();

#pragma unroll
    for (int n = 0; n < 2; ++n) {
        const int c0 = w * 32 + n * 16 + kg * 4;
        const f32x4 bv = *(const f32x4*)(b2 + c0);
        uint2 p;
        p.x = (unsigned)f2b(acc2[n][0] + bv[0]) | ((unsigned)f2b(acc2[n][1] + bv[1]) << 16);
        p.y = (unsigned)f2b(acc2[n][2] + bv[2]) | ((unsigned)f2b(acc2[n][3] + bv[3]) << 16);
        *(uint2*)(smem + ((arow * 512 + c0 * 2) ^ swz)) = p;
    }
    __syncthreads();
    {
        const int flat = tid * 16;
        const int row = flat >> 9, cbyte = flat & 511;
        uint4 d = *(const uint4*)(smem + ((row * 512 + cbyte) ^ ((row & 7) << 4)));
        *(uint4*)((unsigned char*)Cb + (brow + row) * 512 + cbyte) = d;
    }
}

// ======== STEP (R20-verified) + LDS-staged packed edge records ========
// erec[i] = {xx = d*TSCALE as fp32 bits, src} -- one 8B load per edge.
// Block's CSR slice (contiguous, <= 2048 recs = 16KB) staged into smem before
// the agg loop; tab/nmsg gather addresses then come from LDS (~25cy) instead of
// L2 (~200cy), halving the dependent chain.
template <int LAST>
__global__ __launch_bounds__(512, 2)
void step_k(const uint2* __restrict__ erec,
            const unsigned short* __restrict__ tab,
            const unsigned short* __restrict__ nmsg_in,
            const int* __restrict__ coff,
            const unsigned short* __restrict__ S1T, const float* __restrict__ sb1,
            const unsigned short* __restrict__ S2T, const float* __restrict__ sb2,
            float* __restrict__ Xf,
            const unsigned short* __restrict__ N1T, const float* __restrict__ nb1,
            const unsigned short* __restrict__ N2T, const float* __restrict__ nb2,
            unsigned short* __restrict__ nmsg_out,
            const float* __restrict__ ro_w2, float* __restrict__ gsum)
{
    __shared__ __align__(16) unsigned char smem[16384];       // R0(8K) + R1(8K)
    unsigned short* R0 = (unsigned short*)smem;
    unsigned char*  R1 = smem + 8192;

    const int tid  = threadIdx.x;
    const int lane = tid & 63;
    const int w    = tid >> 6;
    const int r16  = lane & 15;
    const int kg   = lane >> 4;
    const int graph = blockIdx.x & 63;
    const int sub   = blockIdx.x >> 6;
    const long brow = (long)graph * Nn + sub * 16;

    const int arow = r16;
    const int swz  = (arow & 7) << 4;

    // ---- phase 1: aggregation with LDS-staged edge records -> R0 ----
    {
        const int ebeg = coff[brow];
        const int eend = coff[brow + 16];
        const int ne   = eend - ebeg;                 // <= Ee (whole graph) = 16KB cap
        uint2* recs = (uint2*)smem;                   // full 16KB as staging
        for (int i = tid; i < ne; i += 512)
            recs[i] = erec[ebeg + i];
        __syncthreads();

        const int node = tid >> 5;
        const int c0   = (tid & 31) * 8;
        const int gn   = (int)brow + node;
        float s[8];
#pragma unroll
        for (int j = 0; j < 8; ++j) s[j] = 0.f;
        const int beg = coff[gn] - ebeg, end = coff[gn + 1] - ebeg;
        for (int i = beg; i < end; ++i) {
            const uint2 rec = recs[i];
            const float xx = __uint_as_float(rec.x);
            const int   sr = (int)rec.y;
            const int   i0 = (int)xx;
            const float f  = xx - (float)i0;
            const unsigned short* t0 = tab + (long)i0 * 256 + c0;
            ushort8 g0 = *(const ushort8*)t0;
            ushort8 g1 = *(const ushort8*)(t0 + 256);
            ushort8 nm = *(const ushort8*)(nmsg_in + ((long)sr << 8) + c0);
#pragma unroll
            for (int j = 0; j < 8; ++j) {
                float a = b2f(g0[j]);
                s[j] += (a + (b2f(g1[j]) - a) * f) * b2f(nm[j]);
            }
        }
        __syncthreads();   // all record reads done -> smem reusable as R0/R1
        const int swzn = (node & 7) << 4;
#pragma unroll
        for (int j = 0; j < 2; ++j) {
            uint2 p;
            p.x = (unsigned)f2b(s[j * 4 + 0]) | ((unsigned)f2b(s[j * 4 + 1]) << 16);
            p.y = (unsigned)f2b(s[j * 4 + 2]) | ((unsigned)f2b(s[j * 4 + 3]) << 16);
            const int c = c0 + j * 4;
            *(uint2*)((unsigned char*)R0 + ((node * 512 + c * 2) ^ swzn)) = p;
        }
    }
    __syncthreads();

    // ---- phase 2: st GEMM1: R0(msum) -> R1(t), ssp ----
    {
        f32x4 acc[2];
#pragma unroll
        for (int n = 0; n < 2; ++n) acc[n] = f32x4{0.f, 0.f, 0.f, 0.f};
#pragma unroll
        for (int kk = 0; kk < 8; ++kk) {
            const int slot = (kk * 4 + kg) ^ (arow & 7);
            bf16x8 af = *(const bf16x8*)(R0 + arow * 256 + slot * 8);
#pragma unroll
            for (int n = 0; n < 2; ++n)
                acc[n] = __builtin_amdgcn_mfma_f32_16x16x32_bf16(
                    wld(S1T, kk, w * 32 + n * 16 + r16, kg), af, acc[n], 0, 0, 0);
        }
#pragma unroll
        for (int n = 0; n < 2; ++n) {
            const int c0 = w * 32 + n * 16 + kg * 4;
            const f32x4 bv = *(const f32x4*)(sb1 + c0);
            uint2 p;
            p.x = (unsigned)f2b(sspf(acc[n][0] + bv[0])) |
                  ((unsigned)f2b(sspf(acc[n][1] + bv[1])) << 16);
            p.y = (unsigned)f2b(sspf(acc[n][2] + bv[2])) |
                  ((unsigned)f2b(sspf(acc[n][3] + bv[3])) << 16);
            *(uint2*)(R1 + ((arow * 512 + c0 * 2) ^ swz)) = p;
        }
    }
    __syncthreads();

    // ---- phase 3: st GEMM2: R1(t) -> x update + xb_new -> R0 ----
    {
        f32x4 acc[2];
#pragma unroll
        for (int n = 0; n < 2; ++n) acc[n] = f32x4{0.f, 0.f, 0.f, 0.f};
#pragma unroll
        for (int kk = 0; kk < 8; ++kk) {
            bf16x8 af = *(const bf16x8*)(R1 + ((arow * 512 + (kk * 4 + kg) * 16) ^ swz));
#pragma unroll
            for (int n = 0; n < 2; ++n)
                acc[n] = __builtin_amdgcn_mfma_f32_16x16x32_bf16(
                    wld(S2T, kk, w * 32 + n * 16 + r16, kg), af, acc[n], 0, 0, 0);
        }
#pragma unroll
        for (int n = 0; n < 2; ++n) {
            const int c0 = w * 32 + n * 16 + kg * 4;
            const f32x4 bv = *(const f32x4*)(sb2 + c0);
            const long base = (brow + arow) * 256 + c0;
            f32x4 xo = *(const f32x4*)(Xf + base);
            f32x4 nx;
            nx[0] = xo[0] + acc[n][0] + bv[0];
            nx[1] = xo[1] + acc[n][1] + bv[1];
            nx[2] = xo[2] + acc[n][2] + bv[2];
            nx[3] = xo[3] + acc[n][3] + bv[3];
            *(f32x4*)(Xf + base) = nx;
            uint2 p;
            p.x = (unsigned)f2b(nx[0]) | ((unsigned)f2b(nx[1]) << 16);
            p.y = (unsigned)f2b(nx[2]) | ((unsigned)f2b(nx[3]) << 16);
            *(uint2*)((unsigned char*)R0 + ((arow * 512 + c0 * 2) ^ swz)) = p;
        }
    }
    __syncthreads();

    // ---- phase 4: next GEMM1 (mn' or ro1): R0(xb_new) -> R1(t2), ssp ----
    {
        f32x4 acc[2];
#pragma unroll
        for (int n = 0; n < 2; ++n) acc[n] = f32x4{0.f, 0.f, 0.f, 0.f};
#pragma unroll
        for (int kk = 0; kk < 8; ++kk) {
            bf16x8 af = *(const bf16x8*)((unsigned char*)R0 + ((arow * 512 + (kk * 4 + kg) * 16) ^ swz));
#pragma unroll
            for (int n = 0; n < 2; ++n)
                acc[n] = __builtin_amdgcn_mfma_f32_16x16x32_bf16(
                    wld(N1T, kk, w * 32 + n * 16 + r16, kg), af, acc[n], 0, 0, 0);
        }
#pragma unroll
        for (int n = 0; n < 2; ++n) {
            const int c0 = w * 32 + n * 16 + kg * 4;
            const f32x4 bv = *(const f32x4*)(nb1 + c0);
            uint2 p;
            p.x = (unsigned)f2b(sspf(acc[n][0] + bv[0])) |
                  ((unsigned)f2b(sspf(acc[n][1] + bv[1])) << 16);
            p.y = (unsigned)f2b(sspf(acc[n][2] + bv[2])) |
                  ((unsigned)f2b(sspf(acc[n][3] + bv[3])) << 16);
            *(uint2*)(R1 + ((arow * 512 + c0 * 2) ^ swz)) = p;
        }
    }
    __syncthreads();

    if (LAST) {
        float part = 0.f;
        {
            const int flat = tid * 16;
            const int row = flat >> 9, cbyte = flat & 511;
            ushort8 u = *(const ushort8*)(R1 + ((row * 512 + cbyte) ^ ((row & 7) << 4)));
            const int c = cbyte >> 1;
#pragma unroll
            for (int j = 0; j < 8; ++j)
                part += b2f(u[j]) * ro_w2[c + j];
        }
        float* red = (float*)R0;
        red[tid] = part;
        __syncthreads();
        for (int d = 256; d > 0; d >>= 1) {
            if (tid < d) red[tid] += red[tid + d];
            __syncthreads();
        }
        if (tid == 0) gsum[graph * 8 + sub] = red[0];
    } else {
        f32x4 acc[2];
#pragma unroll
        for (int n = 0; n < 2; ++n) acc[n] = f32x4{0.f, 0.f, 0.f, 0.f};
#pragma unroll
        for (int kk = 0; kk < 8; ++kk) {
            bf16x8 af = *(const bf16x8*)(R1 + ((arow * 512 + (kk * 4 + kg) * 16) ^ swz));
#pragma unroll
            for (int n = 0; n < 2; ++n)
                acc[n] = __builtin_amdgcn_mfma_f32_16x16x32_bf16(
                    wld(N2T, kk, w * 32 + n * 16 + r16, kg), af, acc[n], 0, 0, 0);
        }
#pragma unroll
        for (int n = 0; n < 2; ++n) {
            const int c0 = w * 32 + n * 16 + kg * 4;
            const f32x4 bv = *(const f32x4*)(nb2 + c0);
            uint2 p;
            p.x = (unsigned)f2b(acc[n][0] + bv[0]) | ((unsigned)f2b(acc[n][1] + bv[1]) << 16);
            p.y = (unsigned)f2b(acc[n][2] + bv[2]) | ((unsigned)f2b(acc[n][3] + bv[3]) << 16);
            *(uint2*)((unsigned char*)R0 + ((arow * 512 + c0 * 2) ^ swz)) = p;
        }
        __syncthreads();
        {
            const int flat = tid * 16;
            const int row = flat >> 9, cbyte = flat & 511;
            uint4 d = *(const uint4*)((unsigned char*)R0 + ((row * 512 + cbyte) ^ ((row & 7) << 4)));
            *(uint4*)((unsigned char*)nmsg_out + (brow + row) * 512 + cbyte) = d;
        }
    }
}

// final scalar tail
__global__ void k_final(const float* __restrict__ gsum, const float* __restrict__ ro_b2,
                        const int* __restrict__ num_nodes,
                        const float* __restrict__ evw, const float* __restrict__ evb,
                        float* __restrict__ out) {
    int g = threadIdx.x;
    if (g >= Bb) return;
    float s = 0.f;
#pragma unroll
    for (int j = 0; j < 8; ++j) s += gsum[g * 8 + j];
    float gg = s + (float)Nn * ro_b2[0];
    gg = gg * 2.0f + (-1.5f) * (float)num_nodes[g];
    out[g * 4 + 0] = gg * evw[0] + evb[0];
    out[g * 4 + 1] = spf(gg * evw[1] + evb[1]);
    out[g * 4 + 2] = spf(gg * evw[2] + evb[2]) + 1.f;
    out[g * 4 + 3] = spf(gg * evw[3] + evb[3]);
}

// ---------------- small kernels ----------------
__global__ void k_offsets(const int* __restrict__ num_nodes, int* __restrict__ off) {
    __shared__ int s[Bb];
    int t = threadIdx.x;
    s[t] = num_nodes[t];
    __syncthreads();
    for (int d = 1; d < Bb; d <<= 1) {
        int v = (t >= d) ? s[t - d] : 0;
        __syncthreads();
        s[t] += v;
        __syncthreads();
    }
    off[t + 1] = s[t];
    if (t == 0) off[0] = 0;
}

__global__ void k_edgeprep(const int* __restrict__ edges, const int* __restrict__ off,
                           int* __restrict__ gsrc, int* __restrict__ gdst, int* __restrict__ cnt) {
    int ge = blockIdx.x * 256 + threadIdx.x;
    if (ge >= TE) return;
    int b = ge >> 11;
    int o = off[b];
    gsrc[ge] = edges[ge * 2 + 0] + o;
    int d = edges[ge * 2 + 1] + o;
    gdst[ge] = d;
    atomicAdd(&cnt[d], 1);
}

__global__ void k_scan(const int* __restrict__ cnt, int* __restrict__ coff, int* __restrict__ pos) {
    __shared__ int part[1024];
    int t = threadIdx.x;
    int loc[8];
    int s = 0;
#pragma unroll
    for (int j = 0; j < 8; ++j) { loc[j] = cnt[t * 8 + j]; s += loc[j]; }
    part[t] = s;
    __syncthreads();
    for (int d = 1; d < 1024; d <<= 1) {
        int v = (t >= d) ? part[t - d] : 0;
        __syncthreads();
        part[t] += v;
        __syncthreads();
    }
    int base = part[t] - s;
#pragma unroll
    for (int j = 0; j < 8; ++j) {
        int idx = t * 8 + j;
        coff[idx] = base;
        pos[idx]  = base;
        base += loc[j];
    }
    if (t == 1023) coff[TN] = part[1023];
}

// CSR fill: packed edge records {xx = d*TSCALE (fp32), src}
__global__ void k_fill(const int* __restrict__ gdst, const int* __restrict__ gsrc,
                       const float* __restrict__ ef,
                       int* __restrict__ pos, uint2* __restrict__ erec) {
    int ge = blockIdx.x * 256 + threadIdx.x;
    if (ge >= TE) return;
    int d = gdst[ge];
    int p = atomicAdd(&pos[d], 1);
    uint2 r;
    r.x = __float_as_uint(ef[ge] * TSCALE);
    r.y = (unsigned)gsrc[ge];
    erec[p] = r;
}

__global__ void k_rbfgrid(unsigned short* __restrict__ rbfg) {
    int gid = blockIdx.x * 256 + threadIdx.x;   // TABN * 64
    int i = gid >> 6, k = gid & 63;
    float v = 0.f;
    if (k < EDGE) {
        float d = (float)i / TSCALE;
        float t = d - 0.1f * (float)k;
        v = __expf(-50.f * t * t);
    }
    rbfg[gid] = f2b(v);
}

__global__ void k_embed(const int* __restrict__ nodes, const float* __restrict__ embed,
                        float* __restrict__ x, unsigned short* __restrict__ xb) {
    int gid = blockIdx.x * 256 + threadIdx.x;
    int i = gid >> 8, c = gid & 255;
    float v = embed[(nodes[i] << 8) + c];
    x[gid] = v;
    xb[gid] = f2b(v);
}

// weight prep: me1/me2 keep N x K layout (table-build gemm_k);
// mn/st/ro packed K-MAJOR: dst[(k>>5)*8192 + n*32 + (k&31)]  (per layer)
__global__ void k_wprep(const float* __restrict__ me_w1, const float* __restrict__ me_w2,
                        const float* __restrict__ mn_w1, const float* __restrict__ mn_w2,
                        const float* __restrict__ st_w1, const float* __restrict__ st_w2,
                        const float* __restrict__ ro_w1,
                        unsigned short* __restrict__ me1T, unsigned short* __restrict__ me2T,
                        unsigned short* __restrict__ mn1T, unsigned short* __restrict__ mn2T,
                        unsigned short* __restrict__ st1T, unsigned short* __restrict__ st2T,
                        unsigned short* __restrict__ ro1T) {
    int gid = blockIdx.x * 256 + threadIdx.x;
    const int S1 = Ll * 256 * EKPAD;
    if (gid < S1) {
        int i = gid / (256 * EKPAD);
        int r = gid % (256 * EKPAD);
        int n = r / EKPAD, k = r % EKPAD;
        float v = (k < EDGE) ? me_w1[(i * EDGE + k) * 256 + n] : 0.f;
        me1T[gid] = f2b(v);
        return;
    }
    gid -= S1;
    const int S2 = Ll * 256 * 256;
    if (gid < S2) {   // me2T: old N x K layout
        int i = gid >> 16;
        int r = gid & 65535;
        int n = r >> 8, k = r & 255;
        me2T[gid] = f2b(me_w2[(i << 16) + k * 256 + n]);
        return;
    }
    gid -= S2;
    const float* srcs[4] = { mn_w1, mn_w2, st_w1, st_w2 };
    unsigned short* dsts[4] = { mn1T, mn2T, st1T, st2T };
#pragma unroll
    for (int q = 0; q < 4; ++q) {
        if (gid < S2) {   // k-major layout
            int i = gid >> 16;
            int r = gid & 65535;
            int n = r >> 8, k = r & 255;
            float v = srcs[q][(i << 16) + k * 256 + n];
            dsts[q][(i << 16) + ((k >> 5) << 13) + n * 32 + (k & 31)] = f2b(v);
            return;
        }
        gid -= S2;
    }
    // ro1T: 256x256, k-major
    int n = gid >> 8, k = gid & 255;
    ro1T[((k >> 5) << 13) + n * 32 + (k & 31)] = f2b(ro_w1[k * 256 + n]);
}

// ---------------- workspace layout ----------------
constexpr size_t al(size_t x) { return (x + 255) & ~(size_t)255; }
constexpr size_t O_OFF    = 0;
constexpr size_t O_GSRC   = al(O_OFF + 65 * 4);
constexpr size_t O_GDST   = al(O_GSRC + (size_t)TE * 4);
constexpr size_t O_CNT    = al(O_GDST + (size_t)TE * 4);
constexpr size_t O_COFF   = al(O_CNT + (size_t)TN * 4);
constexpr size_t O_POS    = al(O_COFF + (size_t)(TN + 1) * 4);
constexpr size_t O_EREC   = al(O_POS + (size_t)TN * 4);
constexpr size_t O_RBFG   = al(O_EREC + (size_t)TE * 8);
constexpr size_t O_TTAB   = al(O_RBFG + (size_t)TABN * EKPAD * 2);
constexpr size_t O_GTAB   = al(O_TTAB + (size_t)Ll * TABN * 256 * 2);
constexpr size_t O_ME1T   = al(O_GTAB + (size_t)Ll * TABN * 256 * 2);
constexpr size_t O_ME2T   = al(O_ME1T + (size_t)Ll * 256 * EKPAD * 2);
constexpr size_t O_MN1T   = al(O_ME2T + (size_t)Ll * 256 * 256 * 2);
constexpr size_t O_MN2T   = al(O_MN1T + (size_t)Ll * 256 * 256 * 2);
constexpr size_t O_ST1T   = al(O_MN2T + (size_t)Ll * 256 * 256 * 2);
constexpr size_t O_ST2T   = al(O_ST1T + (size_t)Ll * 256 * 256 * 2);
constexpr size_t O_RO1T   = al(O_ST2T + (size_t)Ll * 256 * 256 * 2);
constexpr size_t O_X      = al(O_RO1T + (size_t)256 * 256 * 2);
constexpr size_t O_XB     = al(O_X + (size_t)TN * 256 * 4);
constexpr size_t O_NMSGA  = al(O_XB + (size_t)TN * 256 * 2);
constexpr size_t O_NMSGB  = al(O_NMSGA + (size_t)TN * 256 * 2);
constexpr size_t O_GSUM   = al(O_NMSGB + (size_t)TN * 256 * 2);
constexpr size_t WS_NEED  = al(O_GSUM + (size_t)Bb * 8 * 4);

extern "C" void kernel_launch(void* const* d_in, const int* in_sizes, int n_in,
                              void* d_out, int out_size, void* d_ws, size_t ws_size,
                              hipStream_t stream) {
    if (ws_size < WS_NEED) return;

    const int*   nodes     = (const int*)d_in[0];
    const int*   num_nodes = (const int*)d_in[1];
    const int*   edges     = (const int*)d_in[2];
    const float* efeat     = (const float*)d_in[3];
    const float* embed     = (const float*)d_in[5];
    const float* me_w1 = (const float*)d_in[6],  *me_b1 = (const float*)d_in[7];
    const float* me_w2 = (const float*)d_in[8],  *me_b2 = (const float*)d_in[9];
    const float* mn_w1 = (const float*)d_in[10], *mn_b1 = (const float*)d_in[11];
    const float* mn_w2 = (const float*)d_in[12], *mn_b2 = (const float*)d_in[13];
    const float* st_w1 = (const float*)d_in[14], *st_b1 = (const float*)d_in[15];
    const float* st_w2 = (const float*)d_in[16], *st_b2 = (const float*)d_in[17];
    const float* ro_w1 = (const float*)d_in[18], *ro_b1 = (const float*)d_in[19];
    const float* ro_w2 = (const float*)d_in[20], *ro_b2 = (const float*)d_in[21];
    const float* ev_w  = (const float*)d_in[22], *ev_b  = (const float*)d_in[23];

    char* ws = (char*)d_ws;
    int* off   = (int*)(ws + O_OFF);
    int* gsrc  = (int*)(ws + O_GSRC);
    int* gdst  = (int*)(ws + O_GDST);
    int* cnt   = (int*)(ws + O_CNT);
    int* coff  = (int*)(ws + O_COFF);
    int* pos   = (int*)(ws + O_POS);
    uint2* erec = (uint2*)(ws + O_EREC);
    unsigned short* rbfg  = (unsigned short*)(ws + O_RBFG);
    unsigned short* ttab  = (unsigned short*)(ws + O_TTAB);
    unsigned short* gtab  = (unsigned short*)(ws + O_GTAB);
    unsigned short* me1T  = (unsigned short*)(ws + O_ME1T);
    unsigned short* me2T  = (unsigned short*)(ws + O_ME2T);
    unsigned short* mn1T  = (unsigned short*)(ws + O_MN1T);
    unsigned short* mn2T  = (unsigned short*)(ws + O_MN2T);
    unsigned short* st1T  = (unsigned short*)(ws + O_ST1T);
    unsigned short* st2T  = (unsigned short*)(ws + O_ST2T);
    unsigned short* ro1T  = (unsigned short*)(ws + O_RO1T);
    float*          x     = (float*)(ws + O_X);
    unsigned short* xb    = (unsigned short*)(ws + O_XB);
    unsigned short* nmsgA = (unsigned short*)(ws + O_NMSGA);
    unsigned short* nmsgB = (unsigned short*)(ws + O_NMSGB);
    float*          gsum  = (float*)(ws + O_GSUM);
    float* out = (float*)d_out;

    hipMemsetAsync(cnt, 0, TN * 4, stream);
    k_offsets<<<1, Bb, 0, stream>>>(num_nodes, off);
    k_edgeprep<<<TE / 256, 256, 0, stream>>>(edges, off, gsrc, gdst, cnt);
    k_scan<<<1, 1024, 0, stream>>>(cnt, coff, pos);
    k_fill<<<TE / 256, 256, 0, stream>>>(gdst, gsrc, efeat, pos, erec);
    k_rbfgrid<<<(TABN * EKPAD) / 256, 256, 0, stream>>>(rbfg);
    k_embed<<<TN, 256, 0, stream>>>(nodes, embed, x, xb);
    {
        const int total = Ll * 256 * EKPAD + 5 * Ll * 256 * 256 + 256 * 256;
        k_wprep<<<total / 256, 256, 0, stream>>>(me_w1, me_w2, mn_w1, mn_w2, st_w1, st_w2, ro_w1,
                                                 me1T, me2T, mn1T, mn2T, st1T, st2T, ro1T);
    }

    // ---- build all 6 layers' gate tables (z = layer) ----
    const dim3 gT(2, TABN / 128, Ll), blk(256);
    gemm_k<1, 0, 128><<<gT, blk, 0, stream>>>(rbfg, me1T, me_b1, ttab, nullptr, nullptr,
                                              TABN, EKPAD,
                                              0, 256 * EKPAD, 256, (long)TABN * 256);
    gemm_k<0, 0, 128><<<gT, blk, 0, stream>>>(ttab, me2T, me_b2, gtab, nullptr, nullptr,
                                              TABN, 256,
                                              (long)TABN * 256, 65536, 256, (long)TABN * 256);

    // ---- mn_0, 6 fused STEP dispatches (ping-pong), final scalar tail ----
    fused_mn0<<<TN / 16, 512, 0, stream>>>(xb, mn1T, mn_b1, mn2T, mn_b2, nmsgA);

    unsigned short* nin  = nmsgA;
    unsigned short* nout = nmsgB;
    for (int i = 0; i < Ll; ++i) {
        if (i < Ll - 1) {
            step_k<0><<<TN / 16, 512, 0, stream>>>(
                erec, gtab + (size_t)i * TABN * 256, nin, coff,
                st1T + i * 65536, st_b1 + i * 256, st2T + i * 65536, st_b2 + i * 256, x,
                mn1T + (i + 1) * 65536, mn_b1 + (i + 1) * 256,
                mn2T + (i + 1) * 65536, mn_b2 + (i + 1) * 256, nout,
                nullptr, nullptr);
            unsigned short* t = nin; nin = nout; nout = t;
        } else {
            step_k<1><<<TN / 16, 512, 0, stream>>>(
                erec, gtab + (size_t)i * TABN * 256, nin, coff,
                st1T + i * 65536, st_b1 + i * 256, st2T + i * 65536, st_b2 + i * 256, x,
                ro1T, ro_b1, nullptr, nullptr, nullptr,
                ro_w2, gsum);
        }
    }

    k_final<<<1, Bb, 0, stream>>>(gsum, ro_b2, num_nodes, ev_w, ev_b, out);
}